// Round 11
// baseline (2616.964 us; speedup 1.0000x reference)
//
#include <hip/hip_runtime.h>
#include <stdint.h>

namespace {

constexpr int B = 8, N = 2048, KNN = 20;
constexpr int NPART = 64;

// x [B][3][N] -> feat0 [B*N][3]
__global__ void transpose_x(const float* __restrict__ x, float* __restrict__ f) {
  int i = blockIdx.x * 256 + threadIdx.x;
  if (i >= B * N * 3) return;
  int c = i % 3, n = (i / 3) % N, b = i / (3 * N);
  f[i] = x[((size_t)b * 3 + c) * N + n];
}

// [B][N][64] -> [B][64][N], 32x32 LDS tiles
__global__ void transpose64(const float* __restrict__ in, float* __restrict__ out) {
  __shared__ float t[32][33];
  int b = blockIdx.z;
  int n0 = blockIdx.x * 32, c0 = blockIdx.y * 32;
  const float* ib = in + (size_t)b * N * 64;
  float* ob = out + (size_t)b * 64 * N;
  int tx = threadIdx.x & 31, ty = threadIdx.x >> 5;  // 32 x 8
#pragma unroll
  for (int i = 0; i < 32; i += 8) t[ty + i][tx] = ib[(size_t)(n0 + ty + i) * 64 + c0 + tx];
  __syncthreads();
#pragma unroll
  for (int i = 0; i < 32; i += 8) ob[(size_t)(c0 + ty + i) * N + n0 + tx] = t[tx][ty + i];
}

// fp32 squared norms from row-major [BN][64]
__global__ void sqnormf_row(const float* __restrict__ x, float* __restrict__ sqf) {
  int bn = blockIdx.x * 4 + (threadIdx.x >> 6);
  int lane = threadIdx.x & 63;
  float v = x[(size_t)bn * 64 + lane];
  float s = v * v;
#pragma unroll
  for (int off = 32; off; off >>= 1) s += __shfl_xor(s, off, 64);
  if (lane == 0) sqf[bn] = s;
}

// fp32 squared norms from x [B][3][N]
__global__ void sqnormf3(const float* __restrict__ x, float* __restrict__ sqf) {
  int i = blockIdx.x * 256 + threadIdx.x;
  if (i >= B * N) return;
  int b = i >> 11, n = i & (N - 1);
  const float* xb = x + (size_t)b * 3 * N;
  float s = 0.f;
#pragma unroll
  for (int c = 0; c < 3; c++) {
    float v = xb[(size_t)c * N + n];
    s = fmaf(v, v, s);
  }
  sqf[i] = s;
}

// Cross-lane bitonic sort of one fp32 value per lane (ascending by lane),
// two independent streams interleaved.
__device__ __forceinline__ void lane_sort64x2(float& v0, float& v1, int lane) {
#pragma unroll
  for (int k = 2; k <= 64; k <<= 1) {
#pragma unroll
    for (int j = k >> 1; j > 0; j >>= 1) {
      float o0 = __shfl_xor(v0, j, 64);
      float o1 = __shfl_xor(v1, j, 64);
      bool keepmin = (((lane & k) == 0) == ((lane & j) == 0));
      float mn0 = fminf(v0, o0), mx0 = fmaxf(v0, o0);
      v0 = keepmin ? mn0 : mx0;
      float mn1 = fminf(v1, o1), mx1 = fmaxf(v1, o1);
      v1 = keepmin ? mn1 : mx1;
    }
  }
}

// Ballot-compaction of candidates (A[k] <= T) into buf (cap 64); returns count.
__device__ __forceinline__ int compact_cand(const float (&A)[32], float T, int lane,
                                            int* __restrict__ buf) {
  int base = 0;
#pragma unroll
  for (int k = 0; k < 32; k++) {
    bool p = (A[k] <= T);
    unsigned long long mk = __ballot(p);
    if (p) {
      int pos = base + (int)__popcll(mk & ((1ull << lane) - 1));
      if (pos < 64) buf[pos] = (k >> 2) * 256 + lane * 4 + (k & 3);
    }
    base += (int)__popcll(mk);
  }
  return base;
}

// fp32 candidate selection + fp64 exact refine for TWO queries, interleaved.
// A[32] holds dot(q, point) on entry for points pt(k) = (k>>2)*256 + lane*4 + (k&3).
template <int C>
__device__ __forceinline__ void select_refine2(float (&A0)[32], float (&A1)[32], int lane,
                                               int q0loc, int q1loc,
                                               const float* __restrict__ sqb,
                                               const float* __restrict__ rowB,
                                               const float (*qfeat)[C], int (*candBuf)[64],
                                               int* __restrict__ op0, int* __restrict__ op1) {
  const float4* sq4 = (const float4*)sqb;
#pragma unroll
  for (int j8 = 0; j8 < 8; j8++) {
    float4 sv = sq4[j8 * 64 + lane];
    A0[4 * j8 + 0] = fmaf(-2.f, A0[4 * j8 + 0], sv.x);
    A0[4 * j8 + 1] = fmaf(-2.f, A0[4 * j8 + 1], sv.y);
    A0[4 * j8 + 2] = fmaf(-2.f, A0[4 * j8 + 2], sv.z);
    A0[4 * j8 + 3] = fmaf(-2.f, A0[4 * j8 + 3], sv.w);
    A1[4 * j8 + 0] = fmaf(-2.f, A1[4 * j8 + 0], sv.x);
    A1[4 * j8 + 1] = fmaf(-2.f, A1[4 * j8 + 1], sv.y);
    A1[4 * j8 + 2] = fmaf(-2.f, A1[4 * j8 + 2], sv.z);
    A1[4 * j8 + 3] = fmaf(-2.f, A1[4 * j8 + 3], sv.w);
  }
  // Quick threshold: T = 24th smallest of the 64 per-lane minima.
  // Guarantees candidate count >= 24 (superset of fp32-top-24 >= true top-20).
  float p0 = fminf(A0[0], A0[1]), p1 = fminf(A0[2], A0[3]);
  float r0 = fminf(A1[0], A1[1]), r1 = fminf(A1[2], A1[3]);
#pragma unroll
  for (int k = 4; k < 32; k += 4) {
    p0 = fminf(p0, fminf(A0[k], A0[k + 1]));
    p1 = fminf(p1, fminf(A0[k + 2], A0[k + 3]));
    r0 = fminf(r0, fminf(A1[k], A1[k + 1]));
    r1 = fminf(r1, fminf(A1[k + 2], A1[k + 3]));
  }
  float m0 = fminf(p0, p1), m1 = fminf(r0, r1);
  lane_sort64x2(m0, m1, lane);
  float T0 = __shfl(m0, 23, 64);
  float T1 = __shfl(m1, 23, 64);
  int cnt0 = compact_cand(A0, T0, lane, candBuf[q0loc]);
  int cnt1 = compact_cand(A1, T1, lane, candBuf[q1loc]);
  cnt0 = cnt0 < 64 ? cnt0 : 64;  // truncation semantics identical to round-8 path
  cnt1 = cnt1 < 64 ? cnt1 : 64;
  // fp64 exact distances (difference formula), both gathers in flight together
  int mc0 = (lane < cnt0) ? candBuf[q0loc][lane] : 0;
  int mc1 = (lane < cnt1) ? candBuf[q1loc][lane] : 0;
  double dd0 = 0.0, dd1 = 0.0;
  if constexpr (C % 4 == 0) {
    const float4* r40 = (const float4*)(rowB + (size_t)mc0 * C);
    const float4* r41 = (const float4*)(rowB + (size_t)mc1 * C);
    const float4* q40 = (const float4*)(&qfeat[q0loc][0]);
    const float4* q41 = (const float4*)(&qfeat[q1loc][0]);
#pragma unroll 4
    for (int k = 0; k < C / 4; k++) {
      float4 rv0 = r40[k], qv0 = q40[k];
      float4 rv1 = r41[k], qv1 = q41[k];
      double e0 = (double)qv0.x - (double)rv0.x;
      dd0 = fma(e0, e0, dd0);
      double e1 = (double)qv0.y - (double)rv0.y;
      dd0 = fma(e1, e1, dd0);
      double e2 = (double)qv0.z - (double)rv0.z;
      dd0 = fma(e2, e2, dd0);
      double e3 = (double)qv0.w - (double)rv0.w;
      dd0 = fma(e3, e3, dd0);
      double f0 = (double)qv1.x - (double)rv1.x;
      dd1 = fma(f0, f0, dd1);
      double f1 = (double)qv1.y - (double)rv1.y;
      dd1 = fma(f1, f1, dd1);
      double f2 = (double)qv1.z - (double)rv1.z;
      dd1 = fma(f2, f2, dd1);
      double f3 = (double)qv1.w - (double)rv1.w;
      dd1 = fma(f3, f3, dd1);
    }
  } else {
    const float* r0p = rowB + (size_t)mc0 * C;
    const float* r1p = rowB + (size_t)mc1 * C;
#pragma unroll
    for (int c = 0; c < C; c++) {
      double e0 = (double)qfeat[q0loc][c] - (double)r0p[c];
      dd0 = fma(e0, e0, dd0);
      double e1 = (double)qfeat[q1loc][c] - (double)r1p[c];
      dd1 = fma(e1, e1, dd1);
    }
  }
  int myi0 = (lane < cnt0) ? mc0 : 0x7fffffff;
  int myi1 = (lane < cnt1) ? mc1 : 0x7fffffff;
  if (lane >= cnt0) dd0 = 1e300;
  if (lane >= cnt1) dd1 = 1e300;
  // bitonic sort of 64 (dd, idx) pairs ascending, both queries interleaved
#pragma unroll
  for (int k = 2; k <= 64; k <<= 1) {
#pragma unroll
    for (int j = k >> 1; j > 0; j >>= 1) {
      double od0 = __shfl_xor(dd0, j, 64);
      int oi0 = __shfl_xor(myi0, j, 64);
      double od1 = __shfl_xor(dd1, j, 64);
      int oi1 = __shfl_xor(myi1, j, 64);
      bool up = (lane & k) == 0;
      bool lower = (lane & j) == 0;
      bool dir = (up == lower);
      bool cmp0 = (od0 < dd0) || (od0 == dd0 && oi0 < myi0);
      if (dir ? cmp0 : !cmp0) {
        dd0 = od0;
        myi0 = oi0;
      }
      bool cmp1 = (od1 < dd1) || (od1 == dd1 && oi1 < myi1);
      if (dir ? cmp1 : !cmp1) {
        dd1 = od1;
        myi1 = oi1;
      }
    }
  }
  if (lane < KNN) {
    op0[lane] = myi0;
    op1[lane] = myi1;
  }
}

// C=3: 8 queries per 256-thread block; each wave owns 2 queries; direct global reads.
template <int C>
__global__ void __launch_bounds__(256, 4) knn_fused(const float* __restrict__ fT,
                                                    const float* __restrict__ rowF,
                                                    const float* __restrict__ sqf,
                                                    int* __restrict__ idx20) {
  __shared__ __align__(16) float qfeat[8][C];
  __shared__ int candBuf[8][64];
  int t = threadIdx.x, w = t >> 6, lane = t & 63;
  int q0 = blockIdx.x * 8;
  int b = q0 >> 11;
  for (int i = t; i < 8 * C; i += 256) qfeat[i / C][i % C] = rowF[(size_t)q0 * C + i];
  __syncthreads();
  const float* fTb = fT + (size_t)b * C * N;
  const float* rowB = rowF + (((size_t)b) << 11) * C;
  const float* sqb = sqf + (((size_t)b) << 11);
  int qa = w * 2, qbl = w * 2 + 1;
  float acc0[32], acc1[32];
#pragma unroll
  for (int j = 0; j < 32; j++) {
    acc0[j] = 0.f;
    acc1[j] = 0.f;
  }
  for (int c = 0; c < C; c++) {
    float qc0 = qfeat[qa][c], qc1 = qfeat[qbl][c];
    const float4* r4 = (const float4*)(fTb + (size_t)c * N);
#pragma unroll
    for (int j8 = 0; j8 < 8; j8++) {
      float4 v = r4[j8 * 64 + lane];
      acc0[4 * j8 + 0] = fmaf(v.x, qc0, acc0[4 * j8 + 0]);
      acc0[4 * j8 + 1] = fmaf(v.y, qc0, acc0[4 * j8 + 1]);
      acc0[4 * j8 + 2] = fmaf(v.z, qc0, acc0[4 * j8 + 2]);
      acc0[4 * j8 + 3] = fmaf(v.w, qc0, acc0[4 * j8 + 3]);
      acc1[4 * j8 + 0] = fmaf(v.x, qc1, acc1[4 * j8 + 0]);
      acc1[4 * j8 + 1] = fmaf(v.y, qc1, acc1[4 * j8 + 1]);
      acc1[4 * j8 + 2] = fmaf(v.z, qc1, acc1[4 * j8 + 2]);
      acc1[4 * j8 + 3] = fmaf(v.w, qc1, acc1[4 * j8 + 3]);
    }
  }
  select_refine2<C>(acc0, acc1, lane, qa, qbl, sqb, rowB, qfeat, candBuf,
                    idx20 + (size_t)(q0 + qa) * KNN, idx20 + (size_t)(q0 + qbl) * KNN);
}

// C=64: LDS-staged dot phase; 16 queries per block, 4 per wave.
// launch_bounds(256,4): cap VGPR at 128 (occupancy cliff) -> 4 blocks/CU,
// matching the 40KB LDS footprint exactly (160/40=4).
__global__ void __launch_bounds__(256, 4) knn_fused64(const float* __restrict__ fT,
                                                      const float* __restrict__ rowF,
                                                      const float* __restrict__ sqf,
                                                      int* __restrict__ idx20) {
  __shared__ __align__(16) float stage[2][2 * N];  // 32 KB
  __shared__ __align__(16) float qfeat[16][64];    // 4 KB
  __shared__ int candBuf[16][64];                  // 4 KB
  int t = threadIdx.x, w = t >> 6, lane = t & 63;
  int q0 = blockIdx.x * 16;
  int b = q0 >> 11;
  const float* fTb = fT + (size_t)b * 64 * N;
  const float4* src4 = (const float4*)fTb;
  for (int i = t; i < 16 * 64; i += 256) qfeat[i >> 6][i & 63] = rowF[(size_t)q0 * 64 + i];

  float4 st[4];
#pragma unroll
  for (int p = 0; p < 4; p++) st[p] = src4[t + 256 * p];
  {
    float4* d4 = (float4*)&stage[0][0];
#pragma unroll
    for (int p = 0; p < 4; p++) d4[t + 256 * p] = st[p];
  }
  __syncthreads();

  int qa = w * 4;
  float acc0[32], acc1[32], acc2[32], acc3[32];
#pragma unroll
  for (int j = 0; j < 32; j++) {
    acc0[j] = 0.f;
    acc1[j] = 0.f;
    acc2[j] = 0.f;
    acc3[j] = 0.f;
  }

  for (int chunk = 0; chunk < 32; chunk++) {
    int cur = chunk & 1;
    if (chunk < 31) {
#pragma unroll
      for (int p = 0; p < 4; p++) st[p] = src4[(chunk + 1) * 1024 + t + 256 * p];
    }
#pragma unroll
    for (int cc = 0; cc < 2; cc++) {
      int c = chunk * 2 + cc;
      float qc0 = qfeat[qa + 0][c], qc1 = qfeat[qa + 1][c];
      float qc2 = qfeat[qa + 2][c], qc3 = qfeat[qa + 3][c];
      const float4* r4 = (const float4*)&stage[cur][cc * N];
#pragma unroll
      for (int j8 = 0; j8 < 8; j8++) {
        float4 v = r4[j8 * 64 + lane];
        acc0[4 * j8 + 0] = fmaf(v.x, qc0, acc0[4 * j8 + 0]);
        acc0[4 * j8 + 1] = fmaf(v.y, qc0, acc0[4 * j8 + 1]);
        acc0[4 * j8 + 2] = fmaf(v.z, qc0, acc0[4 * j8 + 2]);
        acc0[4 * j8 + 3] = fmaf(v.w, qc0, acc0[4 * j8 + 3]);
        acc1[4 * j8 + 0] = fmaf(v.x, qc1, acc1[4 * j8 + 0]);
        acc1[4 * j8 + 1] = fmaf(v.y, qc1, acc1[4 * j8 + 1]);
        acc1[4 * j8 + 2] = fmaf(v.z, qc1, acc1[4 * j8 + 2]);
        acc1[4 * j8 + 3] = fmaf(v.w, qc1, acc1[4 * j8 + 3]);
        acc2[4 * j8 + 0] = fmaf(v.x, qc2, acc2[4 * j8 + 0]);
        acc2[4 * j8 + 1] = fmaf(v.y, qc2, acc2[4 * j8 + 1]);
        acc2[4 * j8 + 2] = fmaf(v.z, qc2, acc2[4 * j8 + 2]);
        acc2[4 * j8 + 3] = fmaf(v.w, qc2, acc2[4 * j8 + 3]);
        acc3[4 * j8 + 0] = fmaf(v.x, qc3, acc3[4 * j8 + 0]);
        acc3[4 * j8 + 1] = fmaf(v.y, qc3, acc3[4 * j8 + 1]);
        acc3[4 * j8 + 2] = fmaf(v.z, qc3, acc3[4 * j8 + 2]);
        acc3[4 * j8 + 3] = fmaf(v.w, qc3, acc3[4 * j8 + 3]);
      }
    }
    if (chunk < 31) {
      float4* d4 = (float4*)&stage[cur ^ 1][0];
#pragma unroll
      for (int p = 0; p < 4; p++) d4[t + 256 * p] = st[p];
    }
    __syncthreads();
  }
  const float* rowB = rowF + (((size_t)b) << 11) * 64;
  const float* sqb = sqf + (((size_t)b) << 11);
  select_refine2<64>(acc0, acc1, lane, qa + 0, qa + 1, sqb, rowB, qfeat, candBuf,
                     idx20 + (size_t)(q0 + qa + 0) * KNN, idx20 + (size_t)(q0 + qa + 1) * KNN);
  select_refine2<64>(acc2, acc3, lane, qa + 2, qa + 3, sqb, rowB, qfeat, candBuf,
                     idx20 + (size_t)(q0 + qa + 2) * KNN, idx20 + (size_t)(q0 + qa + 3) * KNN);
}

// EdgeConv factorization: u' = A*(Wt - Wb) + bias, v = A*Wb.
template <int K, int D>
__global__ void __launch_bounds__(256) gemm_uv(const float* __restrict__ A,
                                               const float* __restrict__ W,
                                               const float* __restrict__ bias,
                                               float* __restrict__ u, float* __restrict__ v) {
  constexpr int RG = 256 / D;
  constexpr int RPT = 64 / RG;
  __shared__ float At[64][K];
  int t = threadIdx.x;
  int n0 = blockIdx.x * 64;
  for (int i = t; i < 64 * K; i += 256) At[i / K][i % K] = A[(size_t)n0 * K + i];
  __syncthreads();
  int col = t & (D - 1), rg = t / D;
  float au[RPT], av[RPT];
  float bb = bias[col];
#pragma unroll
  for (int r = 0; r < RPT; r++) {
    au[r] = bb;
    av[r] = 0.f;
  }
  for (int c = 0; c < K; c++) {
    float wt = W[(size_t)c * D + col];
    float wb = W[(size_t)(K + c) * D + col];
    float wu = wt - wb;
#pragma unroll
    for (int r = 0; r < RPT; r++) {
      float a = At[rg * RPT + r][c];
      au[r] = fmaf(a, wu, au[r]);
      av[r] = fmaf(a, wb, av[r]);
    }
  }
#pragma unroll
  for (int r = 0; r < RPT; r++) {
    u[(size_t)(n0 + rg * RPT + r) * D + col] = au[r];
    v[(size_t)(n0 + rg * RPT + r) * D + col] = av[r];
  }
}

// h[n,j,d] = relu(u'[n,d] + v[idx[n,j],d]); max/min over j per point + fp64
// stats. 16 points per block; per-channel LDS reduce -> ONE atomic pair/block.
template <int D>
__global__ void __launch_bounds__(256) combine_max(const float* __restrict__ u,
                                                   const float* __restrict__ v,
                                                   const int* __restrict__ idx20,
                                                   float* __restrict__ hmax,
                                                   float* __restrict__ hmin,
                                                   double* __restrict__ sumP,
                                                   double* __restrict__ sqP) {
  constexpr int NG = 256 / D;   // point-groups per block
  constexpr int PPG = 16 / NG;  // points per group (serial)
  __shared__ double reds[NG][D], redq[NG][D];
  int t = threadIdx.x;
  int g = t / D, d = t & (D - 1);
  int bn0 = blockIdx.x * 16;
  int b = bn0 >> 11;
  const float* vb = v + ((size_t)b << 11) * D;
  double s = 0.0, q = 0.0;
  for (int pp = 0; pp < PPG; pp++) {
    int bn = bn0 + g * PPG + pp;
    const int* ip = idx20 + (size_t)bn * KNN;
    float up = u[(size_t)bn * D + d];
    float mx = -1e30f, mn = 1e30f;
#pragma unroll 4
    for (int j = 0; j < KNN; j++) {
      int nb = ip[j];
      float hv = up + vb[(size_t)nb * D + d];
      hv = hv > 0.f ? hv : 0.f;
      mx = fmaxf(mx, hv);
      mn = fminf(mn, hv);
      double hd = (double)hv;
      s += hd;
      q = fma(hd, hd, q);
    }
    hmax[(size_t)bn * D + d] = mx;
    hmin[(size_t)bn * D + d] = mn;
  }
  reds[g][d] = s;
  redq[g][d] = q;
  __syncthreads();
  if (g == 0) {
#pragma unroll
    for (int i = 1; i < NG; i++) {
      s += reds[i][d];
      q += redq[i][d];
    }
    int slot = blockIdx.x & (NPART - 1);
    atomicAdd(&sumP[(size_t)slot * D + d], s);
    atomicAdd(&sqP[(size_t)slot * D + d], q);
  }
}

__global__ void bn_finalize(const double* __restrict__ sumP, const double* __restrict__ sqP,
                            const float* __restrict__ g, const float* __restrict__ be,
                            float* __restrict__ scale, float* __restrict__ shift, int D,
                            int nslots, double invM) {
  int d = blockIdx.x * 256 + threadIdx.x;
  if (d >= D) return;
  double s = 0.0, q = 0.0;
  for (int i = 0; i < nslots; i++) {
    s += sumP[i * D + d];
    q += sqP[i * D + d];
  }
  double mean = s * invM;
  double var = q * invM - mean * mean;
  double sc = (double)g[d] / sqrt(var + 1e-5);
  scale[d] = (float)sc;
  shift[d] = (float)((double)be[d] - mean * sc);
}

__global__ void bn_apply_max(const float* __restrict__ hmax, const float* __restrict__ hmin,
                             const float* __restrict__ scale, const float* __restrict__ shift,
                             float* __restrict__ out, int dmask, int total) {
  int i = blockIdx.x * 256 + threadIdx.x;
  if (i >= total) return;
  int d = i & dmask;
  float sc = scale[d];
  float v = sc >= 0.f ? hmax[i] : hmin[i];
  out[i] = v * sc + shift[d];
}

// [16384,320]x[320,1024]: block = 16 rows x 1024 cols; thread = 16 rows x 4
// contiguous cols. Epilogue: per-block partials (f32), NO atomics.
__global__ void __launch_bounds__(256) final_gemm(const float* __restrict__ x1,
                                                  const float* __restrict__ x2,
                                                  const float* __restrict__ x3,
                                                  const float* __restrict__ x4,
                                                  const float* __restrict__ W5,
                                                  const float* __restrict__ b5,
                                                  float* __restrict__ partMax,
                                                  float* __restrict__ partMin,
                                                  float* __restrict__ partSum,
                                                  float* __restrict__ partSq) {
  __shared__ __align__(16) float At[16][320];  // 20 KB
  int t = threadIdx.x;
  int blk = blockIdx.x;
  int n0 = blk * 16;
  int col = t * 4;
  for (int i = t; i < 16 * 320; i += 256) {
    int r = i / 320, c = i % 320;
    int n = n0 + r;
    float vv;
    if (c < 64) vv = x1[(size_t)n * 64 + c];
    else if (c < 128) vv = x2[(size_t)n * 64 + c - 64];
    else if (c < 192) vv = x3[(size_t)n * 64 + c - 128];
    else vv = x4[(size_t)n * 128 + c - 192];
    At[r][c] = vv;
  }
  __syncthreads();
  float4 acc[16];
  float4 bb = *(const float4*)(b5 + col);
#pragma unroll
  for (int r = 0; r < 16; r++) acc[r] = bb;
  for (int c4 = 0; c4 < 80; c4++) {
    const float* wbase = W5 + (size_t)c4 * 4 * 1024 + col;
    float4 w0 = *(const float4*)(wbase);
    float4 w1 = *(const float4*)(wbase + 1024);
    float4 w2 = *(const float4*)(wbase + 2048);
    float4 w3 = *(const float4*)(wbase + 3072);
#pragma unroll
    for (int r = 0; r < 16; r++) {
      float4 a = *(const float4*)(&At[r][c4 * 4]);
      acc[r].x = fmaf(a.x, w0.x, acc[r].x);
      acc[r].y = fmaf(a.x, w0.y, acc[r].y);
      acc[r].z = fmaf(a.x, w0.z, acc[r].z);
      acc[r].w = fmaf(a.x, w0.w, acc[r].w);
      acc[r].x = fmaf(a.y, w1.x, acc[r].x);
      acc[r].y = fmaf(a.y, w1.y, acc[r].y);
      acc[r].z = fmaf(a.y, w1.z, acc[r].z);
      acc[r].w = fmaf(a.y, w1.w, acc[r].w);
      acc[r].x = fmaf(a.z, w2.x, acc[r].x);
      acc[r].y = fmaf(a.z, w2.y, acc[r].y);
      acc[r].z = fmaf(a.z, w2.z, acc[r].z);
      acc[r].w = fmaf(a.z, w2.w, acc[r].w);
      acc[r].x = fmaf(a.w, w3.x, acc[r].x);
      acc[r].y = fmaf(a.w, w3.y, acc[r].y);
      acc[r].z = fmaf(a.w, w3.z, acc[r].z);
      acc[r].w = fmaf(a.w, w3.w, acc[r].w);
    }
  }
  float mx[4] = {-1e30f, -1e30f, -1e30f, -1e30f};
  float mn[4] = {1e30f, 1e30f, 1e30f, 1e30f};
  double sv[4] = {0, 0, 0, 0}, qv[4] = {0, 0, 0, 0};
#pragma unroll
  for (int r = 0; r < 16; r++) {
    float h0 = acc[r].x > 0.f ? acc[r].x : 0.f;
    float h1 = acc[r].y > 0.f ? acc[r].y : 0.f;
    float h2 = acc[r].z > 0.f ? acc[r].z : 0.f;
    float h3 = acc[r].w > 0.f ? acc[r].w : 0.f;
    mx[0] = fmaxf(mx[0], h0);
    mn[0] = fminf(mn[0], h0);
    sv[0] += h0;
    qv[0] = fma((double)h0, (double)h0, qv[0]);
    mx[1] = fmaxf(mx[1], h1);
    mn[1] = fminf(mn[1], h1);
    sv[1] += h1;
    qv[1] = fma((double)h1, (double)h1, qv[1]);
    mx[2] = fmaxf(mx[2], h2);
    mn[2] = fminf(mn[2], h2);
    sv[2] += h2;
    qv[2] = fma((double)h2, (double)h2, qv[2]);
    mx[3] = fmaxf(mx[3], h3);
    mn[3] = fminf(mn[3], h3);
    sv[3] += h3;
    qv[3] = fma((double)h3, (double)h3, qv[3]);
  }
  size_t base = (size_t)blk * 1024;
  *(float4*)(partMax + base + col) = make_float4(mx[0], mx[1], mx[2], mx[3]);
  *(float4*)(partMin + base + col) = make_float4(mn[0], mn[1], mn[2], mn[3]);
  *(float4*)(partSum + base + col) =
      make_float4((float)sv[0], (float)sv[1], (float)sv[2], (float)sv[3]);
  *(float4*)(partSq + base + col) =
      make_float4((float)qv[0], (float)qv[1], (float)qv[2], (float)qv[3]);
}

// Reduce 128 per-block partials per (batch, channel): final max/min + f64 sums.
__global__ void __launch_bounds__(256) final_reduce(const float* __restrict__ partMax,
                                                    const float* __restrict__ partMin,
                                                    const float* __restrict__ partSum,
                                                    const float* __restrict__ partSq,
                                                    float* __restrict__ h5max,
                                                    float* __restrict__ h5min,
                                                    double* __restrict__ bsum,
                                                    double* __restrict__ bsq) {
  int bid = blockIdx.x;  // 32 blocks: b = bid>>2, ch chunk = (bid&3)*256
  int b = bid >> 2;
  int ch = ((bid & 3) << 8) + threadIdx.x;
  float mx = -1e30f, mn = 1e30f;
  double s = 0.0, q = 0.0;
  for (int j = 0; j < 128; j++) {
    size_t base = ((size_t)(b * 128 + j) << 10) + ch;
    mx = fmaxf(mx, partMax[base]);
    mn = fminf(mn, partMin[base]);
    s += (double)partSum[base];
    q += (double)partSq[base];
  }
  h5max[(size_t)b * 1024 + ch] = mx;
  h5min[(size_t)b * 1024 + ch] = mn;
  bsum[(size_t)b * 1024 + ch] = s;
  bsq[(size_t)b * 1024 + ch] = q;
}

__global__ void final_apply(const float* __restrict__ h5max, const float* __restrict__ h5min,
                            const float* __restrict__ scale, const float* __restrict__ shift,
                            float* __restrict__ out) {
  int i = blockIdx.x * 256 + threadIdx.x;
  if (i >= B * 1024) return;
  int ch = i & 1023;
  float sc = scale[ch];
  float v = sc >= 0.f ? h5max[i] : h5min[i];
  out[i] = v * sc + shift[ch];
}

}  // namespace

extern "C" void kernel_launch(void* const* d_in, const int* in_sizes, int n_in,
                              void* d_out, int out_size, void* d_ws, size_t ws_size,
                              hipStream_t stream) {
  const float* x = (const float*)d_in[0];
  const float *Wv[5], *bv[5], *gv[5], *bev[5];
  for (int i = 0; i < 5; i++) {
    Wv[i] = (const float*)d_in[1 + 4 * i];
    bv[i] = (const float*)d_in[2 + 4 * i];
    gv[i] = (const float*)d_in[3 + 4 * i];
    bev[i] = (const float*)d_in[4 + 4 * i];
  }

  char* ws = (char*)d_ws;
  size_t off = 0;
  auto alloc = [&](size_t bytes) {
    size_t r = off;
    off = (off + bytes + 255) & ~(size_t)255;
    return r;
  };
  const int BN = B * N;
  float* feat0 = (float*)(ws + alloc((size_t)BN * 3 * 4));
  int* idx = (int*)(ws + alloc((size_t)BN * KNN * 4));
  float* x1 = (float*)(ws + alloc((size_t)BN * 64 * 4));
  float* x2 = (float*)(ws + alloc((size_t)BN * 64 * 4));
  float* x3 = (float*)(ws + alloc((size_t)BN * 64 * 4));
  float* x4 = (float*)(ws + alloc((size_t)BN * 128 * 4));
  float* xT = (float*)(ws + alloc((size_t)BN * 64 * 4));
  float* ub = (float*)(ws + alloc((size_t)BN * 128 * 4));
  float* vb = (float*)(ws + alloc((size_t)BN * 128 * 4));
  float* hmax = (float*)(ws + alloc((size_t)BN * 128 * 4));  // reused as partMax/partMin
  float* hmin = (float*)(ws + alloc((size_t)BN * 128 * 4));  // reused as partSum/partSq
  float* sqf = (float*)(ws + alloc((size_t)BN * 4));
  double* sumP = (double*)(ws + alloc((size_t)NPART * 1024 * 8));
  double* sqP = (double*)(ws + alloc((size_t)NPART * 1024 * 8));
  float* scale = (float*)(ws + alloc(1024 * 4));
  float* shift = (float*)(ws + alloc(1024 * 4));
  float* h5max = (float*)(ws + alloc((size_t)B * 1024 * 4));
  float* h5min = (float*)(ws + alloc((size_t)B * 1024 * 4));

  float* partMax = hmax;
  float* partMin = hmax + 1024 * 1024;
  float* partSum = hmin;
  float* partSq = hmin + 1024 * 1024;

  const double invMk = 1.0 / ((double)BN * KNN);
  dim3 tgrid(N / 32, 64 / 32, B);

  transpose_x<<<(BN * 3 + 255) / 256, 256, 0, stream>>>(x, feat0);

  // ---- layer 1: C=3 -> D=64 (x is already [B][3][N]) ----
  sqnormf3<<<(BN + 255) / 256, 256, 0, stream>>>(x, sqf);
  knn_fused<3><<<BN / 8, 256, 0, stream>>>(x, feat0, sqf, idx);
  gemm_uv<3, 64><<<BN / 64, 256, 0, stream>>>(feat0, Wv[0], bv[0], ub, vb);
  hipMemsetAsync(sumP, 0, NPART * 64 * 8, stream);
  hipMemsetAsync(sqP, 0, NPART * 64 * 8, stream);
  combine_max<64><<<BN / 16, 256, 0, stream>>>(ub, vb, idx, hmax, hmin, sumP, sqP);
  bn_finalize<<<1, 256, 0, stream>>>(sumP, sqP, gv[0], bev[0], scale, shift, 64, NPART, invMk);
  bn_apply_max<<<(BN * 64 + 255) / 256, 256, 0, stream>>>(hmax, hmin, scale, shift, x1, 63,
                                                          BN * 64);

  // ---- layer 2: C=64 -> D=64 ----
  transpose64<<<tgrid, 256, 0, stream>>>(x1, xT);
  sqnormf_row<<<BN / 4, 256, 0, stream>>>(x1, sqf);
  knn_fused64<<<BN / 16, 256, 0, stream>>>(xT, x1, sqf, idx);
  gemm_uv<64, 64><<<BN / 64, 256, 0, stream>>>(x1, Wv[1], bv[1], ub, vb);
  hipMemsetAsync(sumP, 0, NPART * 64 * 8, stream);
  hipMemsetAsync(sqP, 0, NPART * 64 * 8, stream);
  combine_max<64><<<BN / 16, 256, 0, stream>>>(ub, vb, idx, hmax, hmin, sumP, sqP);
  bn_finalize<<<1, 256, 0, stream>>>(sumP, sqP, gv[1], bev[1], scale, shift, 64, NPART, invMk);
  bn_apply_max<<<(BN * 64 + 255) / 256, 256, 0, stream>>>(hmax, hmin, scale, shift, x2, 63,
                                                          BN * 64);

  // ---- layer 3: C=64 -> D=64 ----
  transpose64<<<tgrid, 256, 0, stream>>>(x2, xT);
  sqnormf_row<<<BN / 4, 256, 0, stream>>>(x2, sqf);
  knn_fused64<<<BN / 16, 256, 0, stream>>>(xT, x2, sqf, idx);
  gemm_uv<64, 64><<<BN / 64, 256, 0, stream>>>(x2, Wv[2], bv[2], ub, vb);
  hipMemsetAsync(sumP, 0, NPART * 64 * 8, stream);
  hipMemsetAsync(sqP, 0, NPART * 64 * 8, stream);
  combine_max<64><<<BN / 16, 256, 0, stream>>>(ub, vb, idx, hmax, hmin, sumP, sqP);
  bn_finalize<<<1, 256, 0, stream>>>(sumP, sqP, gv[2], bev[2], scale, shift, 64, NPART, invMk);
  bn_apply_max<<<(BN * 64 + 255) / 256, 256, 0, stream>>>(hmax, hmin, scale, shift, x3, 63,
                                                          BN * 64);

  // ---- layer 4: C=64 -> D=128 ----
  transpose64<<<tgrid, 256, 0, stream>>>(x3, xT);
  sqnormf_row<<<BN / 4, 256, 0, stream>>>(x3, sqf);
  knn_fused64<<<BN / 16, 256, 0, stream>>>(xT, x3, sqf, idx);
  gemm_uv<64, 128><<<BN / 64, 256, 0, stream>>>(x3, Wv[3], bv[3], ub, vb);
  hipMemsetAsync(sumP, 0, NPART * 128 * 8, stream);
  hipMemsetAsync(sqP, 0, NPART * 128 * 8, stream);
  combine_max<128><<<BN / 16, 256, 0, stream>>>(ub, vb, idx, hmax, hmin, sumP, sqP);
  bn_finalize<<<1, 256, 0, stream>>>(sumP, sqP, gv[3], bev[3], scale, shift, 128, NPART,
                                     invMk);
  bn_apply_max<<<(BN * 128 + 255) / 256, 256, 0, stream>>>(hmax, hmin, scale, shift, x4, 127,
                                                           BN * 128);

  // ---- final: [BN,320] @ [320,1024], max over n; atomic-free partials ----
  final_gemm<<<BN / 16, 256, 0, stream>>>(x1, x2, x3, x4, Wv[4], bv[4], partMax, partMin,
                                          partSum, partSq);
  final_reduce<<<32, 256, 0, stream>>>(partMax, partMin, partSum, partSq, h5max, h5min, sumP,
                                       sqP);
  bn_finalize<<<4, 256, 0, stream>>>(sumP, sqP, gv[4], bev[4], scale, shift, 1024, 8,
                                     1.0 / (double)BN);
  final_apply<<<(B * 1024 + 255) / 256, 256, 0, stream>>>(h5max, h5min, scale, shift,
                                                          (float*)d_out);
}

// Round 12
// 968.547 us; speedup vs baseline: 2.7019x; 2.7019x over previous
//
#include <hip/hip_runtime.h>
#include <stdint.h>

namespace {

constexpr int B = 8, N = 2048, KNN = 20;
constexpr int NPART = 64;

// x [B][3][N] -> feat0 [B*N][3]
__global__ void transpose_x(const float* __restrict__ x, float* __restrict__ f) {
  int i = blockIdx.x * 256 + threadIdx.x;
  if (i >= B * N * 3) return;
  int c = i % 3, n = (i / 3) % N, b = i / (3 * N);
  f[i] = x[((size_t)b * 3 + c) * N + n];
}

// [B][N][64] -> [B][64][N], 32x32 LDS tiles
__global__ void transpose64(const float* __restrict__ in, float* __restrict__ out) {
  __shared__ float t[32][33];
  int b = blockIdx.z;
  int n0 = blockIdx.x * 32, c0 = blockIdx.y * 32;
  const float* ib = in + (size_t)b * N * 64;
  float* ob = out + (size_t)b * 64 * N;
  int tx = threadIdx.x & 31, ty = threadIdx.x >> 5;  // 32 x 8
#pragma unroll
  for (int i = 0; i < 32; i += 8) t[ty + i][tx] = ib[(size_t)(n0 + ty + i) * 64 + c0 + tx];
  __syncthreads();
#pragma unroll
  for (int i = 0; i < 32; i += 8) ob[(size_t)(c0 + ty + i) * N + n0 + tx] = t[tx][ty + i];
}

// fp32 squared norms from row-major [BN][64]
__global__ void sqnormf_row(const float* __restrict__ x, float* __restrict__ sqf) {
  int bn = blockIdx.x * 4 + (threadIdx.x >> 6);
  int lane = threadIdx.x & 63;
  float v = x[(size_t)bn * 64 + lane];
  float s = v * v;
#pragma unroll
  for (int off = 32; off; off >>= 1) s += __shfl_xor(s, off, 64);
  if (lane == 0) sqf[bn] = s;
}

// fp32 squared norms from x [B][3][N]
__global__ void sqnormf3(const float* __restrict__ x, float* __restrict__ sqf) {
  int i = blockIdx.x * 256 + threadIdx.x;
  if (i >= B * N) return;
  int b = i >> 11, n = i & (N - 1);
  const float* xb = x + (size_t)b * 3 * N;
  float s = 0.f;
#pragma unroll
  for (int c = 0; c < 3; c++) {
    float v = xb[(size_t)c * N + n];
    s = fmaf(v, v, s);
  }
  sqf[i] = s;
}

// Wave-wide min, result in ALL lanes. row_ror DPP for in-row steps + shfl for cross-row.
__device__ __forceinline__ float wave_min_f32(float x) {
  int t;
  t = __builtin_amdgcn_update_dpp(__float_as_int(x), __float_as_int(x), 0x121, 0xf, 0xf, false);
  x = fminf(x, __int_as_float(t));
  t = __builtin_amdgcn_update_dpp(__float_as_int(x), __float_as_int(x), 0x122, 0xf, 0xf, false);
  x = fminf(x, __int_as_float(t));
  t = __builtin_amdgcn_update_dpp(__float_as_int(x), __float_as_int(x), 0x124, 0xf, 0xf, false);
  x = fminf(x, __int_as_float(t));
  t = __builtin_amdgcn_update_dpp(__float_as_int(x), __float_as_int(x), 0x128, 0xf, 0xf, false);
  x = fminf(x, __int_as_float(t));
  x = fminf(x, __shfl_xor(x, 16, 64));
  x = fminf(x, __shfl_xor(x, 32, 64));
  return x;
}

// fp32 candidate selection + fp64 exact refine for TWO queries, interleaved
// (round-7 exact-threshold version: 120 VGPR, best measured).
// A[32] holds dot(q, point) on entry for points pt(k) = (k>>2)*256 + lane*4 + (k&3).
template <int C>
__device__ __forceinline__ void select_refine2(float (&A0)[32], float (&A1)[32], int lane,
                                               int q0loc, int q1loc,
                                               const float* __restrict__ sqb,
                                               const float* __restrict__ rowB,
                                               const float (*qfeat)[C], int (*candBuf)[64],
                                               int* __restrict__ op0, int* __restrict__ op1) {
  const float4* sq4 = (const float4*)sqb;
#pragma unroll
  for (int j8 = 0; j8 < 8; j8++) {
    float4 sv = sq4[j8 * 64 + lane];
    A0[4 * j8 + 0] = fmaf(-2.f, A0[4 * j8 + 0], sv.x);
    A0[4 * j8 + 1] = fmaf(-2.f, A0[4 * j8 + 1], sv.y);
    A0[4 * j8 + 2] = fmaf(-2.f, A0[4 * j8 + 2], sv.z);
    A0[4 * j8 + 3] = fmaf(-2.f, A0[4 * j8 + 3], sv.w);
    A1[4 * j8 + 0] = fmaf(-2.f, A1[4 * j8 + 0], sv.x);
    A1[4 * j8 + 1] = fmaf(-2.f, A1[4 * j8 + 1], sv.y);
    A1[4 * j8 + 2] = fmaf(-2.f, A1[4 * j8 + 2], sv.z);
    A1[4 * j8 + 3] = fmaf(-2.f, A1[4 * j8 + 3], sv.w);
  }
  // per-lane branchless sorted top-8 (ascending), both queries interleaved
  float s0[8], s1[8];
#pragma unroll
  for (int i = 0; i < 8; i++) {
    s0[i] = 1e30f;
    s1[i] = 1e30f;
  }
#pragma unroll
  for (int k = 0; k < 32; k++) {
    float t0 = A0[k], t1 = A1[k];
#pragma unroll
    for (int i = 0; i < 8; i++) {
      float lo0 = fminf(s0[i], t0);
      t0 = fmaxf(s0[i], t0);
      s0[i] = lo0;
      float lo1 = fminf(s1[i], t1);
      t1 = fmaxf(s1[i], t1);
      s1[i] = lo1;
    }
  }
  // 32 wave-min pops -> threshold T at rank >= 32
  float T0 = 0.f, T1 = 0.f;
  for (int it = 0; it < 32; it++) {
    float m0 = wave_min_f32(s0[0]);
    float m1 = wave_min_f32(s1[0]);
    bool w0 = (s0[0] == m0);
    bool w1 = (s1[0] == m1);
#pragma unroll
    for (int i = 0; i < 7; i++) {
      s0[i] = w0 ? s0[i + 1] : s0[i];
      s1[i] = w1 ? s1[i + 1] : s1[i];
    }
    s0[7] = w0 ? 1e30f : s0[7];
    s1[7] = w1 ? 1e30f : s1[7];
    T0 = m0;
    T1 = m1;
  }
  // ballot-compact candidates (d <= T) into LDS
  int base0 = 0, base1 = 0;
#pragma unroll
  for (int k = 0; k < 32; k++) {
    int pt = (k >> 2) * 256 + lane * 4 + (k & 3);
    bool p0 = (A0[k] <= T0);
    unsigned long long mk0 = __ballot(p0);
    if (p0) {
      int pos = base0 + (int)__popcll(mk0 & ((1ull << lane) - 1));
      if (pos < 64) candBuf[q0loc][pos] = pt;
    }
    base0 += (int)__popcll(mk0);
    bool p1 = (A1[k] <= T1);
    unsigned long long mk1 = __ballot(p1);
    if (p1) {
      int pos = base1 + (int)__popcll(mk1 & ((1ull << lane) - 1));
      if (pos < 64) candBuf[q1loc][pos] = pt;
    }
    base1 += (int)__popcll(mk1);
  }
  int cnt0 = base0 < 64 ? base0 : 64;
  int cnt1 = base1 < 64 ? base1 : 64;
  // fp64 exact distances (difference formula), both gathers in flight together
  int mc0 = (lane < cnt0) ? candBuf[q0loc][lane] : 0;
  int mc1 = (lane < cnt1) ? candBuf[q1loc][lane] : 0;
  double dd0 = 0.0, dd1 = 0.0;
  if constexpr (C % 4 == 0) {
    const float4* r40 = (const float4*)(rowB + (size_t)mc0 * C);
    const float4* r41 = (const float4*)(rowB + (size_t)mc1 * C);
    const float4* q40 = (const float4*)(&qfeat[q0loc][0]);
    const float4* q41 = (const float4*)(&qfeat[q1loc][0]);
#pragma unroll 4
    for (int k = 0; k < C / 4; k++) {
      float4 rv0 = r40[k], qv0 = q40[k];
      float4 rv1 = r41[k], qv1 = q41[k];
      double e0 = (double)qv0.x - (double)rv0.x;
      dd0 = fma(e0, e0, dd0);
      double e1 = (double)qv0.y - (double)rv0.y;
      dd0 = fma(e1, e1, dd0);
      double e2 = (double)qv0.z - (double)rv0.z;
      dd0 = fma(e2, e2, dd0);
      double e3 = (double)qv0.w - (double)rv0.w;
      dd0 = fma(e3, e3, dd0);
      double f0 = (double)qv1.x - (double)rv1.x;
      dd1 = fma(f0, f0, dd1);
      double f1 = (double)qv1.y - (double)rv1.y;
      dd1 = fma(f1, f1, dd1);
      double f2 = (double)qv1.z - (double)rv1.z;
      dd1 = fma(f2, f2, dd1);
      double f3 = (double)qv1.w - (double)rv1.w;
      dd1 = fma(f3, f3, dd1);
    }
  } else {
    const float* r0 = rowB + (size_t)mc0 * C;
    const float* r1 = rowB + (size_t)mc1 * C;
#pragma unroll
    for (int c = 0; c < C; c++) {
      double e0 = (double)qfeat[q0loc][c] - (double)r0[c];
      dd0 = fma(e0, e0, dd0);
      double e1 = (double)qfeat[q1loc][c] - (double)r1[c];
      dd1 = fma(e1, e1, dd1);
    }
  }
  int myi0 = (lane < cnt0) ? mc0 : 0x7fffffff;
  int myi1 = (lane < cnt1) ? mc1 : 0x7fffffff;
  if (lane >= cnt0) dd0 = 1e300;
  if (lane >= cnt1) dd1 = 1e300;
  // bitonic sort of 64 (dd, idx) pairs ascending, both queries interleaved
#pragma unroll
  for (int k = 2; k <= 64; k <<= 1) {
#pragma unroll
    for (int j = k >> 1; j > 0; j >>= 1) {
      double od0 = __shfl_xor(dd0, j, 64);
      int oi0 = __shfl_xor(myi0, j, 64);
      double od1 = __shfl_xor(dd1, j, 64);
      int oi1 = __shfl_xor(myi1, j, 64);
      bool up = (lane & k) == 0;
      bool lower = (lane & j) == 0;
      bool dir = (up == lower);
      bool cmp0 = (od0 < dd0) || (od0 == dd0 && oi0 < myi0);
      if (dir ? cmp0 : !cmp0) {
        dd0 = od0;
        myi0 = oi0;
      }
      bool cmp1 = (od1 < dd1) || (od1 == dd1 && oi1 < myi1);
      if (dir ? cmp1 : !cmp1) {
        dd1 = od1;
        myi1 = oi1;
      }
    }
  }
  if (lane < KNN) {
    op0[lane] = myi0;
    op1[lane] = myi1;
  }
}

// C=3: 8 queries per 256-thread block; each wave owns 2 queries; direct global reads.
template <int C>
__global__ void __launch_bounds__(256) knn_fused(const float* __restrict__ fT,
                                                 const float* __restrict__ rowF,
                                                 const float* __restrict__ sqf,
                                                 int* __restrict__ idx20) {
  __shared__ __align__(16) float qfeat[8][C];
  __shared__ int candBuf[8][64];
  int t = threadIdx.x, w = t >> 6, lane = t & 63;
  int q0 = blockIdx.x * 8;
  int b = q0 >> 11;
  for (int i = t; i < 8 * C; i += 256) qfeat[i / C][i % C] = rowF[(size_t)q0 * C + i];
  __syncthreads();
  const float* fTb = fT + (size_t)b * C * N;
  const float* rowB = rowF + (((size_t)b) << 11) * C;
  const float* sqb = sqf + (((size_t)b) << 11);
  int qa = w * 2, qbl = w * 2 + 1;
  float acc0[32], acc1[32];
#pragma unroll
  for (int j = 0; j < 32; j++) {
    acc0[j] = 0.f;
    acc1[j] = 0.f;
  }
  for (int c = 0; c < C; c++) {
    float qc0 = qfeat[qa][c], qc1 = qfeat[qbl][c];
    const float4* r4 = (const float4*)(fTb + (size_t)c * N);
#pragma unroll
    for (int j8 = 0; j8 < 8; j8++) {
      float4 v = r4[j8 * 64 + lane];
      acc0[4 * j8 + 0] = fmaf(v.x, qc0, acc0[4 * j8 + 0]);
      acc0[4 * j8 + 1] = fmaf(v.y, qc0, acc0[4 * j8 + 1]);
      acc0[4 * j8 + 2] = fmaf(v.z, qc0, acc0[4 * j8 + 2]);
      acc0[4 * j8 + 3] = fmaf(v.w, qc0, acc0[4 * j8 + 3]);
      acc1[4 * j8 + 0] = fmaf(v.x, qc1, acc1[4 * j8 + 0]);
      acc1[4 * j8 + 1] = fmaf(v.y, qc1, acc1[4 * j8 + 1]);
      acc1[4 * j8 + 2] = fmaf(v.z, qc1, acc1[4 * j8 + 2]);
      acc1[4 * j8 + 3] = fmaf(v.w, qc1, acc1[4 * j8 + 3]);
    }
  }
  select_refine2<C>(acc0, acc1, lane, qa, qbl, sqb, rowB, qfeat, candBuf,
                    idx20 + (size_t)(q0 + qa) * KNN, idx20 + (size_t)(q0 + qbl) * KNN);
}

// C=64: LDS-staged dot phase; 16 queries per block, 4 per wave.
__global__ void __launch_bounds__(256) knn_fused64(const float* __restrict__ fT,
                                                   const float* __restrict__ rowF,
                                                   const float* __restrict__ sqf,
                                                   int* __restrict__ idx20) {
  __shared__ __align__(16) float stage[2][2 * N];  // 32 KB
  __shared__ __align__(16) float qfeat[16][64];    // 4 KB
  __shared__ int candBuf[16][64];                  // 4 KB
  int t = threadIdx.x, w = t >> 6, lane = t & 63;
  int q0 = blockIdx.x * 16;
  int b = q0 >> 11;
  const float* fTb = fT + (size_t)b * 64 * N;
  const float4* src4 = (const float4*)fTb;
  for (int i = t; i < 16 * 64; i += 256) qfeat[i >> 6][i & 63] = rowF[(size_t)q0 * 64 + i];

  float4 st[4];
#pragma unroll
  for (int p = 0; p < 4; p++) st[p] = src4[t + 256 * p];
  {
    float4* d4 = (float4*)&stage[0][0];
#pragma unroll
    for (int p = 0; p < 4; p++) d4[t + 256 * p] = st[p];
  }
  __syncthreads();

  int qa = w * 4;
  float acc0[32], acc1[32], acc2[32], acc3[32];
#pragma unroll
  for (int j = 0; j < 32; j++) {
    acc0[j] = 0.f;
    acc1[j] = 0.f;
    acc2[j] = 0.f;
    acc3[j] = 0.f;
  }

  for (int chunk = 0; chunk < 32; chunk++) {
    int cur = chunk & 1;
    if (chunk < 31) {
#pragma unroll
      for (int p = 0; p < 4; p++) st[p] = src4[(chunk + 1) * 1024 + t + 256 * p];
    }
#pragma unroll
    for (int cc = 0; cc < 2; cc++) {
      int c = chunk * 2 + cc;
      float qc0 = qfeat[qa + 0][c], qc1 = qfeat[qa + 1][c];
      float qc2 = qfeat[qa + 2][c], qc3 = qfeat[qa + 3][c];
      const float4* r4 = (const float4*)&stage[cur][cc * N];
#pragma unroll
      for (int j8 = 0; j8 < 8; j8++) {
        float4 v = r4[j8 * 64 + lane];
        acc0[4 * j8 + 0] = fmaf(v.x, qc0, acc0[4 * j8 + 0]);
        acc0[4 * j8 + 1] = fmaf(v.y, qc0, acc0[4 * j8 + 1]);
        acc0[4 * j8 + 2] = fmaf(v.z, qc0, acc0[4 * j8 + 2]);
        acc0[4 * j8 + 3] = fmaf(v.w, qc0, acc0[4 * j8 + 3]);
        acc1[4 * j8 + 0] = fmaf(v.x, qc1, acc1[4 * j8 + 0]);
        acc1[4 * j8 + 1] = fmaf(v.y, qc1, acc1[4 * j8 + 1]);
        acc1[4 * j8 + 2] = fmaf(v.z, qc1, acc1[4 * j8 + 2]);
        acc1[4 * j8 + 3] = fmaf(v.w, qc1, acc1[4 * j8 + 3]);
        acc2[4 * j8 + 0] = fmaf(v.x, qc2, acc2[4 * j8 + 0]);
        acc2[4 * j8 + 1] = fmaf(v.y, qc2, acc2[4 * j8 + 1]);
        acc2[4 * j8 + 2] = fmaf(v.z, qc2, acc2[4 * j8 + 2]);
        acc2[4 * j8 + 3] = fmaf(v.w, qc2, acc2[4 * j8 + 3]);
        acc3[4 * j8 + 0] = fmaf(v.x, qc3, acc3[4 * j8 + 0]);
        acc3[4 * j8 + 1] = fmaf(v.y, qc3, acc3[4 * j8 + 1]);
        acc3[4 * j8 + 2] = fmaf(v.z, qc3, acc3[4 * j8 + 2]);
        acc3[4 * j8 + 3] = fmaf(v.w, qc3, acc3[4 * j8 + 3]);
      }
    }
    if (chunk < 31) {
      float4* d4 = (float4*)&stage[cur ^ 1][0];
#pragma unroll
      for (int p = 0; p < 4; p++) d4[t + 256 * p] = st[p];
    }
    __syncthreads();
  }
  const float* rowB = rowF + (((size_t)b) << 11) * 64;
  const float* sqb = sqf + (((size_t)b) << 11);
  select_refine2<64>(acc0, acc1, lane, qa + 0, qa + 1, sqb, rowB, qfeat, candBuf,
                     idx20 + (size_t)(q0 + qa + 0) * KNN, idx20 + (size_t)(q0 + qa + 1) * KNN);
  select_refine2<64>(acc2, acc3, lane, qa + 2, qa + 3, sqb, rowB, qfeat, candBuf,
                     idx20 + (size_t)(q0 + qa + 2) * KNN, idx20 + (size_t)(q0 + qa + 3) * KNN);
}

// EdgeConv factorization: u' = A*(Wt - Wb) + bias, v = A*Wb.
template <int K, int D>
__global__ void __launch_bounds__(256) gemm_uv(const float* __restrict__ A,
                                               const float* __restrict__ W,
                                               const float* __restrict__ bias,
                                               float* __restrict__ u, float* __restrict__ v) {
  constexpr int RG = 256 / D;
  constexpr int RPT = 64 / RG;
  __shared__ float At[64][K];
  int t = threadIdx.x;
  int n0 = blockIdx.x * 64;
  for (int i = t; i < 64 * K; i += 256) At[i / K][i % K] = A[(size_t)n0 * K + i];
  __syncthreads();
  int col = t & (D - 1), rg = t / D;
  float au[RPT], av[RPT];
  float bb = bias[col];
#pragma unroll
  for (int r = 0; r < RPT; r++) {
    au[r] = bb;
    av[r] = 0.f;
  }
  for (int c = 0; c < K; c++) {
    float wt = W[(size_t)c * D + col];
    float wb = W[(size_t)(K + c) * D + col];
    float wu = wt - wb;
#pragma unroll
    for (int r = 0; r < RPT; r++) {
      float a = At[rg * RPT + r][c];
      au[r] = fmaf(a, wu, au[r]);
      av[r] = fmaf(a, wb, av[r]);
    }
  }
#pragma unroll
  for (int r = 0; r < RPT; r++) {
    u[(size_t)(n0 + rg * RPT + r) * D + col] = au[r];
    v[(size_t)(n0 + rg * RPT + r) * D + col] = av[r];
  }
}

// h[n,j,d] = relu(u'[n,d] + v[idx[n,j],d]); max/min over j + fp64 stats
// (round-7 version: per-thread spread atomics, PPB points per block).
template <int D>
__global__ void __launch_bounds__(256) combine_max(const float* __restrict__ u,
                                                   const float* __restrict__ v,
                                                   const int* __restrict__ idx20,
                                                   float* __restrict__ hmax,
                                                   float* __restrict__ hmin,
                                                   double* __restrict__ sumP,
                                                   double* __restrict__ sqP) {
  constexpr int PPB = 256 / D;
  int t = threadIdx.x;
  int p = t / D, d = t & (D - 1);
  int bn = blockIdx.x * PPB + p;
  int b = bn >> 11;
  const int* ip = idx20 + (size_t)bn * KNN;
  float up = u[(size_t)bn * D + d];
  const float* vb = v + ((size_t)b << 11) * D;
  float mx = -1e30f, mn = 1e30f;
  double s = 0.0, q = 0.0;
#pragma unroll 4
  for (int j = 0; j < KNN; j++) {
    int nb = ip[j];
    float hv = up + vb[(size_t)nb * D + d];
    hv = hv > 0.f ? hv : 0.f;
    mx = fmaxf(mx, hv);
    mn = fminf(mn, hv);
    double hd = (double)hv;
    s += hd;
    q = fma(hd, hd, q);
  }
  hmax[(size_t)bn * D + d] = mx;
  hmin[(size_t)bn * D + d] = mn;
  int slot = bn & (NPART - 1);
  atomicAdd(&sumP[(size_t)slot * D + d], s);
  atomicAdd(&sqP[(size_t)slot * D + d], q);
}

__global__ void bn_finalize(const double* __restrict__ sumP, const double* __restrict__ sqP,
                            const float* __restrict__ g, const float* __restrict__ be,
                            float* __restrict__ scale, float* __restrict__ shift, int D,
                            int nslots, double invM) {
  int d = blockIdx.x * 256 + threadIdx.x;
  if (d >= D) return;
  double s = 0.0, q = 0.0;
  for (int i = 0; i < nslots; i++) {
    s += sumP[i * D + d];
    q += sqP[i * D + d];
  }
  double mean = s * invM;
  double var = q * invM - mean * mean;
  double sc = (double)g[d] / sqrt(var + 1e-5);
  scale[d] = (float)sc;
  shift[d] = (float)((double)be[d] - mean * sc);
}

__global__ void bn_apply_max(const float* __restrict__ hmax, const float* __restrict__ hmin,
                             const float* __restrict__ scale, const float* __restrict__ shift,
                             float* __restrict__ out, int dmask, int total) {
  int i = blockIdx.x * 256 + threadIdx.x;
  if (i >= total) return;
  int d = i & dmask;
  float sc = scale[d];
  float v = sc >= 0.f ? hmax[i] : hmin[i];
  out[i] = v * sc + shift[d];
}

// [16384,320]x[320,1024]: block = 16 rows x 1024 cols; thread = 16 rows x 4
// contiguous cols. Epilogue: per-block partials (f32), NO atomics.
__global__ void __launch_bounds__(256) final_gemm(const float* __restrict__ x1,
                                                  const float* __restrict__ x2,
                                                  const float* __restrict__ x3,
                                                  const float* __restrict__ x4,
                                                  const float* __restrict__ W5,
                                                  const float* __restrict__ b5,
                                                  float* __restrict__ partMax,
                                                  float* __restrict__ partMin,
                                                  float* __restrict__ partSum,
                                                  float* __restrict__ partSq) {
  __shared__ __align__(16) float At[16][320];  // 20 KB
  int t = threadIdx.x;
  int blk = blockIdx.x;
  int n0 = blk * 16;
  int col = t * 4;
  for (int i = t; i < 16 * 320; i += 256) {
    int r = i / 320, c = i % 320;
    int n = n0 + r;
    float vv;
    if (c < 64) vv = x1[(size_t)n * 64 + c];
    else if (c < 128) vv = x2[(size_t)n * 64 + c - 64];
    else if (c < 192) vv = x3[(size_t)n * 64 + c - 128];
    else vv = x4[(size_t)n * 128 + c - 192];
    At[r][c] = vv;
  }
  __syncthreads();
  float4 acc[16];
  float4 bb = *(const float4*)(b5 + col);
#pragma unroll
  for (int r = 0; r < 16; r++) acc[r] = bb;
  for (int c4 = 0; c4 < 80; c4++) {
    const float* wbase = W5 + (size_t)c4 * 4 * 1024 + col;
    float4 w0 = *(const float4*)(wbase);
    float4 w1 = *(const float4*)(wbase + 1024);
    float4 w2 = *(const float4*)(wbase + 2048);
    float4 w3 = *(const float4*)(wbase + 3072);
#pragma unroll
    for (int r = 0; r < 16; r++) {
      float4 a = *(const float4*)(&At[r][c4 * 4]);
      acc[r].x = fmaf(a.x, w0.x, acc[r].x);
      acc[r].y = fmaf(a.x, w0.y, acc[r].y);
      acc[r].z = fmaf(a.x, w0.z, acc[r].z);
      acc[r].w = fmaf(a.x, w0.w, acc[r].w);
      acc[r].x = fmaf(a.y, w1.x, acc[r].x);
      acc[r].y = fmaf(a.y, w1.y, acc[r].y);
      acc[r].z = fmaf(a.y, w1.z, acc[r].z);
      acc[r].w = fmaf(a.y, w1.w, acc[r].w);
      acc[r].x = fmaf(a.z, w2.x, acc[r].x);
      acc[r].y = fmaf(a.z, w2.y, acc[r].y);
      acc[r].z = fmaf(a.z, w2.z, acc[r].z);
      acc[r].w = fmaf(a.z, w2.w, acc[r].w);
      acc[r].x = fmaf(a.w, w3.x, acc[r].x);
      acc[r].y = fmaf(a.w, w3.y, acc[r].y);
      acc[r].z = fmaf(a.w, w3.z, acc[r].z);
      acc[r].w = fmaf(a.w, w3.w, acc[r].w);
    }
  }
  float mx[4] = {-1e30f, -1e30f, -1e30f, -1e30f};
  float mn[4] = {1e30f, 1e30f, 1e30f, 1e30f};
  double sv[4] = {0, 0, 0, 0}, qv[4] = {0, 0, 0, 0};
#pragma unroll
  for (int r = 0; r < 16; r++) {
    float h0 = acc[r].x > 0.f ? acc[r].x : 0.f;
    float h1 = acc[r].y > 0.f ? acc[r].y : 0.f;
    float h2 = acc[r].z > 0.f ? acc[r].z : 0.f;
    float h3 = acc[r].w > 0.f ? acc[r].w : 0.f;
    mx[0] = fmaxf(mx[0], h0);
    mn[0] = fminf(mn[0], h0);
    sv[0] += h0;
    qv[0] = fma((double)h0, (double)h0, qv[0]);
    mx[1] = fmaxf(mx[1], h1);
    mn[1] = fminf(mn[1], h1);
    sv[1] += h1;
    qv[1] = fma((double)h1, (double)h1, qv[1]);
    mx[2] = fmaxf(mx[2], h2);
    mn[2] = fminf(mn[2], h2);
    sv[2] += h2;
    qv[2] = fma((double)h2, (double)h2, qv[2]);
    mx[3] = fmaxf(mx[3], h3);
    mn[3] = fminf(mn[3], h3);
    sv[3] += h3;
    qv[3] = fma((double)h3, (double)h3, qv[3]);
  }
  size_t base = (size_t)blk * 1024;
  *(float4*)(partMax + base + col) = make_float4(mx[0], mx[1], mx[2], mx[3]);
  *(float4*)(partMin + base + col) = make_float4(mn[0], mn[1], mn[2], mn[3]);
  *(float4*)(partSum + base + col) =
      make_float4((float)sv[0], (float)sv[1], (float)sv[2], (float)sv[3]);
  *(float4*)(partSq + base + col) =
      make_float4((float)qv[0], (float)qv[1], (float)qv[2], (float)qv[3]);
}

// Reduce 128 per-block partials per (batch, channel): final max/min + f64 sums.
__global__ void __launch_bounds__(256) final_reduce(const float* __restrict__ partMax,
                                                    const float* __restrict__ partMin,
                                                    const float* __restrict__ partSum,
                                                    const float* __restrict__ partSq,
                                                    float* __restrict__ h5max,
                                                    float* __restrict__ h5min,
                                                    double* __restrict__ bsum,
                                                    double* __restrict__ bsq) {
  int bid = blockIdx.x;  // 32 blocks: b = bid>>2, ch chunk = (bid&3)*256
  int b = bid >> 2;
  int ch = ((bid & 3) << 8) + threadIdx.x;
  float mx = -1e30f, mn = 1e30f;
  double s = 0.0, q = 0.0;
  for (int j = 0; j < 128; j++) {
    size_t base = ((size_t)(b * 128 + j) << 10) + ch;
    mx = fmaxf(mx, partMax[base]);
    mn = fminf(mn, partMin[base]);
    s += (double)partSum[base];
    q += (double)partSq[base];
  }
  h5max[(size_t)b * 1024 + ch] = mx;
  h5min[(size_t)b * 1024 + ch] = mn;
  bsum[(size_t)b * 1024 + ch] = s;
  bsq[(size_t)b * 1024 + ch] = q;
}

__global__ void final_apply(const float* __restrict__ h5max, const float* __restrict__ h5min,
                            const float* __restrict__ scale, const float* __restrict__ shift,
                            float* __restrict__ out) {
  int i = blockIdx.x * 256 + threadIdx.x;
  if (i >= B * 1024) return;
  int ch = i & 1023;
  float sc = scale[ch];
  float v = sc >= 0.f ? h5max[i] : h5min[i];
  out[i] = v * sc + shift[ch];
}

}  // namespace

extern "C" void kernel_launch(void* const* d_in, const int* in_sizes, int n_in,
                              void* d_out, int out_size, void* d_ws, size_t ws_size,
                              hipStream_t stream) {
  const float* x = (const float*)d_in[0];
  const float *Wv[5], *bv[5], *gv[5], *bev[5];
  for (int i = 0; i < 5; i++) {
    Wv[i] = (const float*)d_in[1 + 4 * i];
    bv[i] = (const float*)d_in[2 + 4 * i];
    gv[i] = (const float*)d_in[3 + 4 * i];
    bev[i] = (const float*)d_in[4 + 4 * i];
  }

  char* ws = (char*)d_ws;
  size_t off = 0;
  auto alloc = [&](size_t bytes) {
    size_t r = off;
    off = (off + bytes + 255) & ~(size_t)255;
    return r;
  };
  const int BN = B * N;
  float* feat0 = (float*)(ws + alloc((size_t)BN * 3 * 4));
  int* idx = (int*)(ws + alloc((size_t)BN * KNN * 4));
  float* x1 = (float*)(ws + alloc((size_t)BN * 64 * 4));
  float* x2 = (float*)(ws + alloc((size_t)BN * 64 * 4));
  float* x3 = (float*)(ws + alloc((size_t)BN * 64 * 4));
  float* x4 = (float*)(ws + alloc((size_t)BN * 128 * 4));
  float* xT = (float*)(ws + alloc((size_t)BN * 64 * 4));
  float* ub = (float*)(ws + alloc((size_t)BN * 128 * 4));
  float* vb = (float*)(ws + alloc((size_t)BN * 128 * 4));
  float* hmax = (float*)(ws + alloc((size_t)BN * 128 * 4));  // reused as partMax/partMin
  float* hmin = (float*)(ws + alloc((size_t)BN * 128 * 4));  // reused as partSum/partSq
  float* sqf = (float*)(ws + alloc((size_t)BN * 4));
  double* sumP = (double*)(ws + alloc((size_t)NPART * 1024 * 8));
  double* sqP = (double*)(ws + alloc((size_t)NPART * 1024 * 8));
  float* scale = (float*)(ws + alloc(1024 * 4));
  float* shift = (float*)(ws + alloc(1024 * 4));
  float* h5max = (float*)(ws + alloc((size_t)B * 1024 * 4));
  float* h5min = (float*)(ws + alloc((size_t)B * 1024 * 4));

  float* partMax = hmax;
  float* partMin = hmax + 1024 * 1024;
  float* partSum = hmin;
  float* partSq = hmin + 1024 * 1024;

  const double invMk = 1.0 / ((double)BN * KNN);
  dim3 tgrid(N / 32, 64 / 32, B);

  transpose_x<<<(BN * 3 + 255) / 256, 256, 0, stream>>>(x, feat0);

  // ---- layer 1: C=3 -> D=64 (x is already [B][3][N]) ----
  sqnormf3<<<(BN + 255) / 256, 256, 0, stream>>>(x, sqf);
  knn_fused<3><<<BN / 8, 256, 0, stream>>>(x, feat0, sqf, idx);
  gemm_uv<3, 64><<<BN / 64, 256, 0, stream>>>(feat0, Wv[0], bv[0], ub, vb);
  hipMemsetAsync(sumP, 0, NPART * 64 * 8, stream);
  hipMemsetAsync(sqP, 0, NPART * 64 * 8, stream);
  combine_max<64><<<BN / 4, 256, 0, stream>>>(ub, vb, idx, hmax, hmin, sumP, sqP);
  bn_finalize<<<1, 256, 0, stream>>>(sumP, sqP, gv[0], bev[0], scale, shift, 64, NPART, invMk);
  bn_apply_max<<<(BN * 64 + 255) / 256, 256, 0, stream>>>(hmax, hmin, scale, shift, x1, 63,
                                                          BN * 64);

  // ---- layer 2: C=64 -> D=64 ----
  transpose64<<<tgrid, 256, 0, stream>>>(x1, xT);
  sqnormf_row<<<BN / 4, 256, 0, stream>>>(x1, sqf);
  knn_fused64<<<BN / 16, 256, 0, stream>>>(xT, x1, sqf, idx);
  gemm_uv<64, 64><<<BN / 64, 256, 0, stream>>>(x1, Wv[1], bv[1], ub, vb);
  hipMemsetAsync(sumP, 0, NPART * 64 * 8, stream);
  hipMemsetAsync(sqP, 0, NPART * 64 * 8, stream);
  combine_max<64><<<BN / 4, 256, 0, stream>>>(ub, vb, idx, hmax, hmin, sumP, sqP);
  bn_finalize<<<1, 256, 0, stream>>>(sumP, sqP, gv[1], bev[1], scale, shift, 64, NPART, invMk);
  bn_apply_max<<<(BN * 64 + 255) / 256, 256, 0, stream>>>(hmax, hmin, scale, shift, x2, 63,
                                                          BN * 64);

  // ---- layer 3: C=64 -> D=64 ----
  transpose64<<<tgrid, 256, 0, stream>>>(x2, xT);
  sqnormf_row<<<BN / 4, 256, 0, stream>>>(x2, sqf);
  knn_fused64<<<BN / 16, 256, 0, stream>>>(xT, x2, sqf, idx);
  gemm_uv<64, 64><<<BN / 64, 256, 0, stream>>>(x2, Wv[2], bv[2], ub, vb);
  hipMemsetAsync(sumP, 0, NPART * 64 * 8, stream);
  hipMemsetAsync(sqP, 0, NPART * 64 * 8, stream);
  combine_max<64><<<BN / 4, 256, 0, stream>>>(ub, vb, idx, hmax, hmin, sumP, sqP);
  bn_finalize<<<1, 256, 0, stream>>>(sumP, sqP, gv[2], bev[2], scale, shift, 64, NPART, invMk);
  bn_apply_max<<<(BN * 64 + 255) / 256, 256, 0, stream>>>(hmax, hmin, scale, shift, x3, 63,
                                                          BN * 64);

  // ---- layer 4: C=64 -> D=128 ----
  transpose64<<<tgrid, 256, 0, stream>>>(x3, xT);
  sqnormf_row<<<BN / 4, 256, 0, stream>>>(x3, sqf);
  knn_fused64<<<BN / 16, 256, 0, stream>>>(xT, x3, sqf, idx);
  gemm_uv<64, 128><<<BN / 64, 256, 0, stream>>>(x3, Wv[3], bv[3], ub, vb);
  hipMemsetAsync(sumP, 0, NPART * 128 * 8, stream);
  hipMemsetAsync(sqP, 0, NPART * 128 * 8, stream);
  combine_max<128><<<BN / 2, 256, 0, stream>>>(ub, vb, idx, hmax, hmin, sumP, sqP);
  bn_finalize<<<1, 256, 0, stream>>>(sumP, sqP, gv[3], bev[3], scale, shift, 128, NPART,
                                     invMk);
  bn_apply_max<<<(BN * 128 + 255) / 256, 256, 0, stream>>>(hmax, hmin, scale, shift, x4, 127,
                                                           BN * 128);

  // ---- final: [BN,320] @ [320,1024], max over n; atomic-free partials ----
  final_gemm<<<BN / 16, 256, 0, stream>>>(x1, x2, x3, x4, Wv[4], bv[4], partMax, partMin,
                                          partSum, partSq);
  final_reduce<<<32, 256, 0, stream>>>(partMax, partMin, partSum, partSq, h5max, h5min, sumP,
                                       sqP);
  bn_finalize<<<4, 256, 0, stream>>>(sumP, sqP, gv[4], bev[4], scale, shift, 1024, 8,
                                     1.0 / (double)BN);
  final_apply<<<(B * 1024 + 255) / 256, 256, 0, stream>>>(h5max, h5min, scale, shift,
                                                          (float*)d_out);
}

// Round 13
// 886.437 us; speedup vs baseline: 2.9522x; 1.0926x over previous
//
#include <hip/hip_runtime.h>
#include <stdint.h>

namespace {

constexpr int B = 8, N = 2048, KNN = 20;
constexpr int NPART = 64;

// Fused: x [B][3][N] -> feat0 [BN][3] + fp32 sq-norms
__global__ void __launch_bounds__(256) transpose_x_norm(const float* __restrict__ x,
                                                        float* __restrict__ f,
                                                        float* __restrict__ sqf) {
  int i = blockIdx.x * 256 + threadIdx.x;
  if (i >= B * N) return;
  int b = i >> 11, n = i & (N - 1);
  const float* xb = x + (size_t)b * 3 * N;
  float v0 = xb[n], v1 = xb[N + n], v2 = xb[2 * N + n];
  float* fp = f + (size_t)i * 3;
  fp[0] = v0;
  fp[1] = v1;
  fp[2] = v2;
  sqf[i] = fmaf(v0, v0, fmaf(v1, v1, v2 * v2));
}

// Fused: [B][N][64] -> [B][64][N] transpose + per-point sq-norms.
// Block = 32 points x all 64 channels; grid (N/32, B).
__global__ void __launch_bounds__(256) transpose64_norm(const float* __restrict__ in,
                                                        float* __restrict__ out,
                                                        float* __restrict__ sqf) {
  __shared__ float tl[32][65];
  int t = threadIdx.x;
  int n0 = blockIdx.x * 32;
  int b = blockIdx.y;
  const float* ib = in + (size_t)b * N * 64;
  float* ob = out + (size_t)b * 64 * N;
  int pt = t >> 3, ch0 = (t & 7) * 8;
  const float4* src = (const float4*)(ib + (size_t)(n0 + pt) * 64 + ch0);
  float4 a0 = src[0], a1 = src[1];
  tl[pt][ch0 + 0] = a0.x;
  tl[pt][ch0 + 1] = a0.y;
  tl[pt][ch0 + 2] = a0.z;
  tl[pt][ch0 + 3] = a0.w;
  tl[pt][ch0 + 4] = a1.x;
  tl[pt][ch0 + 5] = a1.y;
  tl[pt][ch0 + 6] = a1.z;
  tl[pt][ch0 + 7] = a1.w;
  __syncthreads();
  if (t < 32) {
    float s = 0.f;
#pragma unroll 8
    for (int c = 0; c < 64; c++) {
      float v = tl[t][c];
      s = fmaf(v, v, s);
    }
    sqf[(size_t)b * N + n0 + t] = s;
  }
  int ch = t >> 2, pg = (t & 3) * 8;
  float4 w0, w1;
  w0.x = tl[pg + 0][ch];
  w0.y = tl[pg + 1][ch];
  w0.z = tl[pg + 2][ch];
  w0.w = tl[pg + 3][ch];
  w1.x = tl[pg + 4][ch];
  w1.y = tl[pg + 5][ch];
  w1.z = tl[pg + 6][ch];
  w1.w = tl[pg + 7][ch];
  *(float4*)(ob + (size_t)ch * N + n0 + pg) = w0;
  *(float4*)(ob + (size_t)ch * N + n0 + pg + 4) = w1;
}

// Wave-wide min, result in ALL lanes. row_ror DPP for in-row steps + shfl for cross-row.
__device__ __forceinline__ float wave_min_f32(float x) {
  int t;
  t = __builtin_amdgcn_update_dpp(__float_as_int(x), __float_as_int(x), 0x121, 0xf, 0xf, false);
  x = fminf(x, __int_as_float(t));
  t = __builtin_amdgcn_update_dpp(__float_as_int(x), __float_as_int(x), 0x122, 0xf, 0xf, false);
  x = fminf(x, __int_as_float(t));
  t = __builtin_amdgcn_update_dpp(__float_as_int(x), __float_as_int(x), 0x124, 0xf, 0xf, false);
  x = fminf(x, __int_as_float(t));
  t = __builtin_amdgcn_update_dpp(__float_as_int(x), __float_as_int(x), 0x128, 0xf, 0xf, false);
  x = fminf(x, __int_as_float(t));
  x = fminf(x, __shfl_xor(x, 16, 64));
  x = fminf(x, __shfl_xor(x, 32, 64));
  return x;
}

// fp32 candidate selection + fp64 exact refine for TWO queries, interleaved
// (round-7 exact-threshold version: 120 VGPR, best measured).
// A[32] holds dot(q, point) on entry for points pt(k) = (k>>2)*256 + lane*4 + (k&3).
template <int C>
__device__ __forceinline__ void select_refine2(float (&A0)[32], float (&A1)[32], int lane,
                                               int q0loc, int q1loc,
                                               const float* __restrict__ sqb,
                                               const float* __restrict__ rowB,
                                               const float (*qfeat)[C], int (*candBuf)[64],
                                               int* __restrict__ op0, int* __restrict__ op1) {
  const float4* sq4 = (const float4*)sqb;
#pragma unroll
  for (int j8 = 0; j8 < 8; j8++) {
    float4 sv = sq4[j8 * 64 + lane];
    A0[4 * j8 + 0] = fmaf(-2.f, A0[4 * j8 + 0], sv.x);
    A0[4 * j8 + 1] = fmaf(-2.f, A0[4 * j8 + 1], sv.y);
    A0[4 * j8 + 2] = fmaf(-2.f, A0[4 * j8 + 2], sv.z);
    A0[4 * j8 + 3] = fmaf(-2.f, A0[4 * j8 + 3], sv.w);
    A1[4 * j8 + 0] = fmaf(-2.f, A1[4 * j8 + 0], sv.x);
    A1[4 * j8 + 1] = fmaf(-2.f, A1[4 * j8 + 1], sv.y);
    A1[4 * j8 + 2] = fmaf(-2.f, A1[4 * j8 + 2], sv.z);
    A1[4 * j8 + 3] = fmaf(-2.f, A1[4 * j8 + 3], sv.w);
  }
  // per-lane branchless sorted top-8 (ascending), both queries interleaved
  float s0[8], s1[8];
#pragma unroll
  for (int i = 0; i < 8; i++) {
    s0[i] = 1e30f;
    s1[i] = 1e30f;
  }
#pragma unroll
  for (int k = 0; k < 32; k++) {
    float t0 = A0[k], t1 = A1[k];
#pragma unroll
    for (int i = 0; i < 8; i++) {
      float lo0 = fminf(s0[i], t0);
      t0 = fmaxf(s0[i], t0);
      s0[i] = lo0;
      float lo1 = fminf(s1[i], t1);
      t1 = fmaxf(s1[i], t1);
      s1[i] = lo1;
    }
  }
  // 32 wave-min pops -> threshold T at rank >= 32
  float T0 = 0.f, T1 = 0.f;
  for (int it = 0; it < 32; it++) {
    float m0 = wave_min_f32(s0[0]);
    float m1 = wave_min_f32(s1[0]);
    bool w0 = (s0[0] == m0);
    bool w1 = (s1[0] == m1);
#pragma unroll
    for (int i = 0; i < 7; i++) {
      s0[i] = w0 ? s0[i + 1] : s0[i];
      s1[i] = w1 ? s1[i + 1] : s1[i];
    }
    s0[7] = w0 ? 1e30f : s0[7];
    s1[7] = w1 ? 1e30f : s1[7];
    T0 = m0;
    T1 = m1;
  }
  // ballot-compact candidates (d <= T) into LDS
  int base0 = 0, base1 = 0;
#pragma unroll
  for (int k = 0; k < 32; k++) {
    int pt = (k >> 2) * 256 + lane * 4 + (k & 3);
    bool p0 = (A0[k] <= T0);
    unsigned long long mk0 = __ballot(p0);
    if (p0) {
      int pos = base0 + (int)__popcll(mk0 & ((1ull << lane) - 1));
      if (pos < 64) candBuf[q0loc][pos] = pt;
    }
    base0 += (int)__popcll(mk0);
    bool p1 = (A1[k] <= T1);
    unsigned long long mk1 = __ballot(p1);
    if (p1) {
      int pos = base1 + (int)__popcll(mk1 & ((1ull << lane) - 1));
      if (pos < 64) candBuf[q1loc][pos] = pt;
    }
    base1 += (int)__popcll(mk1);
  }
  int cnt0 = base0 < 64 ? base0 : 64;
  int cnt1 = base1 < 64 ? base1 : 64;
  // fp64 exact distances (difference formula), both gathers in flight together
  int mc0 = (lane < cnt0) ? candBuf[q0loc][lane] : 0;
  int mc1 = (lane < cnt1) ? candBuf[q1loc][lane] : 0;
  double dd0 = 0.0, dd1 = 0.0;
  if constexpr (C % 4 == 0) {
    const float4* r40 = (const float4*)(rowB + (size_t)mc0 * C);
    const float4* r41 = (const float4*)(rowB + (size_t)mc1 * C);
    const float4* q40 = (const float4*)(&qfeat[q0loc][0]);
    const float4* q41 = (const float4*)(&qfeat[q1loc][0]);
#pragma unroll 4
    for (int k = 0; k < C / 4; k++) {
      float4 rv0 = r40[k], qv0 = q40[k];
      float4 rv1 = r41[k], qv1 = q41[k];
      double e0 = (double)qv0.x - (double)rv0.x;
      dd0 = fma(e0, e0, dd0);
      double e1 = (double)qv0.y - (double)rv0.y;
      dd0 = fma(e1, e1, dd0);
      double e2 = (double)qv0.z - (double)rv0.z;
      dd0 = fma(e2, e2, dd0);
      double e3 = (double)qv0.w - (double)rv0.w;
      dd0 = fma(e3, e3, dd0);
      double f0 = (double)qv1.x - (double)rv1.x;
      dd1 = fma(f0, f0, dd1);
      double f1 = (double)qv1.y - (double)rv1.y;
      dd1 = fma(f1, f1, dd1);
      double f2 = (double)qv1.z - (double)rv1.z;
      dd1 = fma(f2, f2, dd1);
      double f3 = (double)qv1.w - (double)rv1.w;
      dd1 = fma(f3, f3, dd1);
    }
  } else {
    const float* r0 = rowB + (size_t)mc0 * C;
    const float* r1 = rowB + (size_t)mc1 * C;
#pragma unroll
    for (int c = 0; c < C; c++) {
      double e0 = (double)qfeat[q0loc][c] - (double)r0[c];
      dd0 = fma(e0, e0, dd0);
      double e1 = (double)qfeat[q1loc][c] - (double)r1[c];
      dd1 = fma(e1, e1, dd1);
    }
  }
  int myi0 = (lane < cnt0) ? mc0 : 0x7fffffff;
  int myi1 = (lane < cnt1) ? mc1 : 0x7fffffff;
  if (lane >= cnt0) dd0 = 1e300;
  if (lane >= cnt1) dd1 = 1e300;
  // bitonic sort of 64 (dd, idx) pairs ascending, both queries interleaved
#pragma unroll
  for (int k = 2; k <= 64; k <<= 1) {
#pragma unroll
    for (int j = k >> 1; j > 0; j >>= 1) {
      double od0 = __shfl_xor(dd0, j, 64);
      int oi0 = __shfl_xor(myi0, j, 64);
      double od1 = __shfl_xor(dd1, j, 64);
      int oi1 = __shfl_xor(myi1, j, 64);
      bool up = (lane & k) == 0;
      bool lower = (lane & j) == 0;
      bool dir = (up == lower);
      bool cmp0 = (od0 < dd0) || (od0 == dd0 && oi0 < myi0);
      if (dir ? cmp0 : !cmp0) {
        dd0 = od0;
        myi0 = oi0;
      }
      bool cmp1 = (od1 < dd1) || (od1 == dd1 && oi1 < myi1);
      if (dir ? cmp1 : !cmp1) {
        dd1 = od1;
        myi1 = oi1;
      }
    }
  }
  if (lane < KNN) {
    op0[lane] = myi0;
    op1[lane] = myi1;
  }
}

// C=3: 8 queries per 256-thread block; each wave owns 2 queries; direct global reads.
template <int C>
__global__ void __launch_bounds__(256) knn_fused(const float* __restrict__ fT,
                                                 const float* __restrict__ rowF,
                                                 const float* __restrict__ sqf,
                                                 int* __restrict__ idx20) {
  __shared__ __align__(16) float qfeat[8][C];
  __shared__ int candBuf[8][64];
  int t = threadIdx.x, w = t >> 6, lane = t & 63;
  int q0 = blockIdx.x * 8;
  int b = q0 >> 11;
  for (int i = t; i < 8 * C; i += 256) qfeat[i / C][i % C] = rowF[(size_t)q0 * C + i];
  __syncthreads();
  const float* fTb = fT + (size_t)b * C * N;
  const float* rowB = rowF + (((size_t)b) << 11) * C;
  const float* sqb = sqf + (((size_t)b) << 11);
  int qa = w * 2, qbl = w * 2 + 1;
  float acc0[32], acc1[32];
#pragma unroll
  for (int j = 0; j < 32; j++) {
    acc0[j] = 0.f;
    acc1[j] = 0.f;
  }
  for (int c = 0; c < C; c++) {
    float qc0 = qfeat[qa][c], qc1 = qfeat[qbl][c];
    const float4* r4 = (const float4*)(fTb + (size_t)c * N);
#pragma unroll
    for (int j8 = 0; j8 < 8; j8++) {
      float4 v = r4[j8 * 64 + lane];
      acc0[4 * j8 + 0] = fmaf(v.x, qc0, acc0[4 * j8 + 0]);
      acc0[4 * j8 + 1] = fmaf(v.y, qc0, acc0[4 * j8 + 1]);
      acc0[4 * j8 + 2] = fmaf(v.z, qc0, acc0[4 * j8 + 2]);
      acc0[4 * j8 + 3] = fmaf(v.w, qc0, acc0[4 * j8 + 3]);
      acc1[4 * j8 + 0] = fmaf(v.x, qc1, acc1[4 * j8 + 0]);
      acc1[4 * j8 + 1] = fmaf(v.y, qc1, acc1[4 * j8 + 1]);
      acc1[4 * j8 + 2] = fmaf(v.z, qc1, acc1[4 * j8 + 2]);
      acc1[4 * j8 + 3] = fmaf(v.w, qc1, acc1[4 * j8 + 3]);
    }
  }
  select_refine2<C>(acc0, acc1, lane, qa, qbl, sqb, rowB, qfeat, candBuf,
                    idx20 + (size_t)(q0 + qa) * KNN, idx20 + (size_t)(q0 + qbl) * KNN);
}

// C=64: LDS-staged dot phase; 16 queries per block, 4 per wave.
__global__ void __launch_bounds__(256) knn_fused64(const float* __restrict__ fT,
                                                   const float* __restrict__ rowF,
                                                   const float* __restrict__ sqf,
                                                   int* __restrict__ idx20) {
  __shared__ __align__(16) float stage[2][2 * N];  // 32 KB
  __shared__ __align__(16) float qfeat[16][64];    // 4 KB
  __shared__ int candBuf[16][64];                  // 4 KB
  int t = threadIdx.x, w = t >> 6, lane = t & 63;
  int q0 = blockIdx.x * 16;
  int b = q0 >> 11;
  const float* fTb = fT + (size_t)b * 64 * N;
  const float4* src4 = (const float4*)fTb;
  for (int i = t; i < 16 * 64; i += 256) qfeat[i >> 6][i & 63] = rowF[(size_t)q0 * 64 + i];

  float4 st[4];
#pragma unroll
  for (int p = 0; p < 4; p++) st[p] = src4[t + 256 * p];
  {
    float4* d4 = (float4*)&stage[0][0];
#pragma unroll
    for (int p = 0; p < 4; p++) d4[t + 256 * p] = st[p];
  }
  __syncthreads();

  int qa = w * 4;
  float acc0[32], acc1[32], acc2[32], acc3[32];
#pragma unroll
  for (int j = 0; j < 32; j++) {
    acc0[j] = 0.f;
    acc1[j] = 0.f;
    acc2[j] = 0.f;
    acc3[j] = 0.f;
  }

  for (int chunk = 0; chunk < 32; chunk++) {
    int cur = chunk & 1;
    if (chunk < 31) {
#pragma unroll
      for (int p = 0; p < 4; p++) st[p] = src4[(chunk + 1) * 1024 + t + 256 * p];
    }
#pragma unroll
    for (int cc = 0; cc < 2; cc++) {
      int c = chunk * 2 + cc;
      float qc0 = qfeat[qa + 0][c], qc1 = qfeat[qa + 1][c];
      float qc2 = qfeat[qa + 2][c], qc3 = qfeat[qa + 3][c];
      const float4* r4 = (const float4*)&stage[cur][cc * N];
#pragma unroll
      for (int j8 = 0; j8 < 8; j8++) {
        float4 v = r4[j8 * 64 + lane];
        acc0[4 * j8 + 0] = fmaf(v.x, qc0, acc0[4 * j8 + 0]);
        acc0[4 * j8 + 1] = fmaf(v.y, qc0, acc0[4 * j8 + 1]);
        acc0[4 * j8 + 2] = fmaf(v.z, qc0, acc0[4 * j8 + 2]);
        acc0[4 * j8 + 3] = fmaf(v.w, qc0, acc0[4 * j8 + 3]);
        acc1[4 * j8 + 0] = fmaf(v.x, qc1, acc1[4 * j8 + 0]);
        acc1[4 * j8 + 1] = fmaf(v.y, qc1, acc1[4 * j8 + 1]);
        acc1[4 * j8 + 2] = fmaf(v.z, qc1, acc1[4 * j8 + 2]);
        acc1[4 * j8 + 3] = fmaf(v.w, qc1, acc1[4 * j8 + 3]);
        acc2[4 * j8 + 0] = fmaf(v.x, qc2, acc2[4 * j8 + 0]);
        acc2[4 * j8 + 1] = fmaf(v.y, qc2, acc2[4 * j8 + 1]);
        acc2[4 * j8 + 2] = fmaf(v.z, qc2, acc2[4 * j8 + 2]);
        acc2[4 * j8 + 3] = fmaf(v.w, qc2, acc2[4 * j8 + 3]);
        acc3[4 * j8 + 0] = fmaf(v.x, qc3, acc3[4 * j8 + 0]);
        acc3[4 * j8 + 1] = fmaf(v.y, qc3, acc3[4 * j8 + 1]);
        acc3[4 * j8 + 2] = fmaf(v.z, qc3, acc3[4 * j8 + 2]);
        acc3[4 * j8 + 3] = fmaf(v.w, qc3, acc3[4 * j8 + 3]);
      }
    }
    if (chunk < 31) {
      float4* d4 = (float4*)&stage[cur ^ 1][0];
#pragma unroll
      for (int p = 0; p < 4; p++) d4[t + 256 * p] = st[p];
    }
    __syncthreads();
  }
  const float* rowB = rowF + (((size_t)b) << 11) * 64;
  const float* sqb = sqf + (((size_t)b) << 11);
  select_refine2<64>(acc0, acc1, lane, qa + 0, qa + 1, sqb, rowB, qfeat, candBuf,
                     idx20 + (size_t)(q0 + qa + 0) * KNN, idx20 + (size_t)(q0 + qa + 1) * KNN);
  select_refine2<64>(acc2, acc3, lane, qa + 2, qa + 3, sqb, rowB, qfeat, candBuf,
                     idx20 + (size_t)(q0 + qa + 2) * KNN, idx20 + (size_t)(q0 + qa + 3) * KNN);
}

// EdgeConv factorization: u' = A*(Wt - Wb) + bias, v = A*Wb.
template <int K, int D>
__global__ void __launch_bounds__(256) gemm_uv(const float* __restrict__ A,
                                               const float* __restrict__ W,
                                               const float* __restrict__ bias,
                                               float* __restrict__ u, float* __restrict__ v) {
  constexpr int RG = 256 / D;
  constexpr int RPT = 64 / RG;
  __shared__ float At[64][K];
  int t = threadIdx.x;
  int n0 = blockIdx.x * 64;
  for (int i = t; i < 64 * K; i += 256) At[i / K][i % K] = A[(size_t)n0 * K + i];
  __syncthreads();
  int col = t & (D - 1), rg = t / D;
  float au[RPT], av[RPT];
  float bb = bias[col];
#pragma unroll
  for (int r = 0; r < RPT; r++) {
    au[r] = bb;
    av[r] = 0.f;
  }
  for (int c = 0; c < K; c++) {
    float wt = W[(size_t)c * D + col];
    float wb = W[(size_t)(K + c) * D + col];
    float wu = wt - wb;
#pragma unroll
    for (int r = 0; r < RPT; r++) {
      float a = At[rg * RPT + r][c];
      au[r] = fmaf(a, wu, au[r]);
      av[r] = fmaf(a, wb, av[r]);
    }
  }
#pragma unroll
  for (int r = 0; r < RPT; r++) {
    u[(size_t)(n0 + rg * RPT + r) * D + col] = au[r];
    v[(size_t)(n0 + rg * RPT + r) * D + col] = av[r];
  }
}

// h[n,j,d] = relu(u'[n,d] + v[idx[n,j],d]); max/min over j + fp64 stats.
template <int D>
__global__ void __launch_bounds__(256) combine_max(const float* __restrict__ u,
                                                   const float* __restrict__ v,
                                                   const int* __restrict__ idx20,
                                                   float* __restrict__ hmax,
                                                   float* __restrict__ hmin,
                                                   double* __restrict__ sumP,
                                                   double* __restrict__ sqP) {
  constexpr int PPB = 256 / D;
  int t = threadIdx.x;
  int p = t / D, d = t & (D - 1);
  int bn = blockIdx.x * PPB + p;
  int b = bn >> 11;
  const int* ip = idx20 + (size_t)bn * KNN;
  float up = u[(size_t)bn * D + d];
  const float* vb = v + ((size_t)b << 11) * D;
  float mx = -1e30f, mn = 1e30f;
  double s = 0.0, q = 0.0;
#pragma unroll 4
  for (int j = 0; j < KNN; j++) {
    int nb = ip[j];
    float hv = up + vb[(size_t)nb * D + d];
    hv = hv > 0.f ? hv : 0.f;
    mx = fmaxf(mx, hv);
    mn = fminf(mn, hv);
    double hd = (double)hv;
    s += hd;
    q = fma(hd, hd, q);
  }
  hmax[(size_t)bn * D + d] = mx;
  hmin[(size_t)bn * D + d] = mn;
  int slot = bn & (NPART - 1);
  atomicAdd(&sumP[(size_t)slot * D + d], s);
  atomicAdd(&sqP[(size_t)slot * D + d], q);
}

// Fused bn_finalize + bn_apply: 256-block grid-stride; each block computes
// scale/shift in an LDS preamble (redundant, L2-resident), then applies.
template <int D>
__global__ void __launch_bounds__(256) bn_apply_fused(const float* __restrict__ hmax,
                                                      const float* __restrict__ hmin,
                                                      const double* __restrict__ sumP,
                                                      const double* __restrict__ sqP,
                                                      const float* __restrict__ g,
                                                      const float* __restrict__ be,
                                                      float* __restrict__ out, int total,
                                                      double invM) {
  constexpr int NG = 256 / D;
  __shared__ double redsS[256], redqS[256];
  __shared__ float scl[D], shf[D];
  int t = threadIdx.x;
  int d = t & (D - 1), grp = t / D;
  double s = 0.0, q = 0.0;
  for (int i = grp; i < NPART; i += NG) {
    s += sumP[(size_t)i * D + d];
    q += sqP[(size_t)i * D + d];
  }
  redsS[t] = s;
  redqS[t] = q;
  __syncthreads();
  if (t < D) {
#pragma unroll
    for (int i = 1; i < NG; i++) {
      s += redsS[i * D + t];
      q += redqS[i * D + t];
    }
    double mean = s * invM;
    double var = q * invM - mean * mean;
    double sc = (double)g[t] / sqrt(var + 1e-5);
    scl[t] = (float)sc;
    shf[t] = (float)((double)be[t] - mean * sc);
  }
  __syncthreads();
  float sc = scl[d], sh = shf[d];
  for (int i = blockIdx.x * 256 + t; i < total; i += 256 * 256) {
    float v = sc >= 0.f ? hmax[i] : hmin[i];
    out[i] = v * sc + sh;
  }
}

// [16384,320]x[320,1024]: block = 16 rows x 1024 cols; thread = 16 rows x 4
// contiguous cols. Epilogue: per-block partials (f32), NO atomics.
__global__ void __launch_bounds__(256) final_gemm(const float* __restrict__ x1,
                                                  const float* __restrict__ x2,
                                                  const float* __restrict__ x3,
                                                  const float* __restrict__ x4,
                                                  const float* __restrict__ W5,
                                                  const float* __restrict__ b5,
                                                  float* __restrict__ partMax,
                                                  float* __restrict__ partMin,
                                                  float* __restrict__ partSum,
                                                  float* __restrict__ partSq) {
  __shared__ __align__(16) float At[16][320];  // 20 KB
  int t = threadIdx.x;
  int blk = blockIdx.x;
  int n0 = blk * 16;
  int col = t * 4;
  for (int i = t; i < 16 * 320; i += 256) {
    int r = i / 320, c = i % 320;
    int n = n0 + r;
    float vv;
    if (c < 64) vv = x1[(size_t)n * 64 + c];
    else if (c < 128) vv = x2[(size_t)n * 64 + c - 64];
    else if (c < 192) vv = x3[(size_t)n * 64 + c - 128];
    else vv = x4[(size_t)n * 128 + c - 192];
    At[r][c] = vv;
  }
  __syncthreads();
  float4 acc[16];
  float4 bb = *(const float4*)(b5 + col);
#pragma unroll
  for (int r = 0; r < 16; r++) acc[r] = bb;
  for (int c4 = 0; c4 < 80; c4++) {
    const float* wbase = W5 + (size_t)c4 * 4 * 1024 + col;
    float4 w0 = *(const float4*)(wbase);
    float4 w1 = *(const float4*)(wbase + 1024);
    float4 w2 = *(const float4*)(wbase + 2048);
    float4 w3 = *(const float4*)(wbase + 3072);
#pragma unroll
    for (int r = 0; r < 16; r++) {
      float4 a = *(const float4*)(&At[r][c4 * 4]);
      acc[r].x = fmaf(a.x, w0.x, acc[r].x);
      acc[r].y = fmaf(a.x, w0.y, acc[r].y);
      acc[r].z = fmaf(a.x, w0.z, acc[r].z);
      acc[r].w = fmaf(a.x, w0.w, acc[r].w);
      acc[r].x = fmaf(a.y, w1.x, acc[r].x);
      acc[r].y = fmaf(a.y, w1.y, acc[r].y);
      acc[r].z = fmaf(a.y, w1.z, acc[r].z);
      acc[r].w = fmaf(a.y, w1.w, acc[r].w);
      acc[r].x = fmaf(a.z, w2.x, acc[r].x);
      acc[r].y = fmaf(a.z, w2.y, acc[r].y);
      acc[r].z = fmaf(a.z, w2.z, acc[r].z);
      acc[r].w = fmaf(a.z, w2.w, acc[r].w);
      acc[r].x = fmaf(a.w, w3.x, acc[r].x);
      acc[r].y = fmaf(a.w, w3.y, acc[r].y);
      acc[r].z = fmaf(a.w, w3.z, acc[r].z);
      acc[r].w = fmaf(a.w, w3.w, acc[r].w);
    }
  }
  float mx[4] = {-1e30f, -1e30f, -1e30f, -1e30f};
  float mn[4] = {1e30f, 1e30f, 1e30f, 1e30f};
  double sv[4] = {0, 0, 0, 0}, qv[4] = {0, 0, 0, 0};
#pragma unroll
  for (int r = 0; r < 16; r++) {
    float h0 = acc[r].x > 0.f ? acc[r].x : 0.f;
    float h1 = acc[r].y > 0.f ? acc[r].y : 0.f;
    float h2 = acc[r].z > 0.f ? acc[r].z : 0.f;
    float h3 = acc[r].w > 0.f ? acc[r].w : 0.f;
    mx[0] = fmaxf(mx[0], h0);
    mn[0] = fminf(mn[0], h0);
    sv[0] += h0;
    qv[0] = fma((double)h0, (double)h0, qv[0]);
    mx[1] = fmaxf(mx[1], h1);
    mn[1] = fminf(mn[1], h1);
    sv[1] += h1;
    qv[1] = fma((double)h1, (double)h1, qv[1]);
    mx[2] = fmaxf(mx[2], h2);
    mn[2] = fminf(mn[2], h2);
    sv[2] += h2;
    qv[2] = fma((double)h2, (double)h2, qv[2]);
    mx[3] = fmaxf(mx[3], h3);
    mn[3] = fminf(mn[3], h3);
    sv[3] += h3;
    qv[3] = fma((double)h3, (double)h3, qv[3]);
  }
  size_t base = (size_t)blk * 1024;
  *(float4*)(partMax + base + col) = make_float4(mx[0], mx[1], mx[2], mx[3]);
  *(float4*)(partMin + base + col) = make_float4(mn[0], mn[1], mn[2], mn[3]);
  *(float4*)(partSum + base + col) =
      make_float4((float)sv[0], (float)sv[1], (float)sv[2], (float)sv[3]);
  *(float4*)(partSq + base + col) =
      make_float4((float)qv[0], (float)qv[1], (float)qv[2], (float)qv[3]);
}

// Reduce 128 per-block partials per (batch, channel): final max/min + f64 sums.
__global__ void __launch_bounds__(256) final_reduce(const float* __restrict__ partMax,
                                                    const float* __restrict__ partMin,
                                                    const float* __restrict__ partSum,
                                                    const float* __restrict__ partSq,
                                                    float* __restrict__ h5max,
                                                    float* __restrict__ h5min,
                                                    double* __restrict__ bsum,
                                                    double* __restrict__ bsq) {
  int bid = blockIdx.x;  // 32 blocks: b = bid>>2, ch chunk = (bid&3)*256
  int b = bid >> 2;
  int ch = ((bid & 3) << 8) + threadIdx.x;
  float mx = -1e30f, mn = 1e30f;
  double s = 0.0, q = 0.0;
  for (int j = 0; j < 128; j++) {
    size_t base = ((size_t)(b * 128 + j) << 10) + ch;
    mx = fmaxf(mx, partMax[base]);
    mn = fminf(mn, partMin[base]);
    s += (double)partSum[base];
    q += (double)partSq[base];
  }
  h5max[(size_t)b * 1024 + ch] = mx;
  h5min[(size_t)b * 1024 + ch] = mn;
  bsum[(size_t)b * 1024 + ch] = s;
  bsq[(size_t)b * 1024 + ch] = q;
}

// Fused final bn_finalize + apply.
__global__ void __launch_bounds__(256) final_apply_fused(const float* __restrict__ h5max,
                                                         const float* __restrict__ h5min,
                                                         const double* __restrict__ bsum,
                                                         const double* __restrict__ bsq,
                                                         const float* __restrict__ g,
                                                         const float* __restrict__ be,
                                                         float* __restrict__ out,
                                                         double invM) {
  int i = blockIdx.x * 256 + threadIdx.x;
  if (i >= B * 1024) return;
  int ch = i & 1023;
  double s = 0.0, q = 0.0;
#pragma unroll
  for (int j = 0; j < 8; j++) {
    s += bsum[(size_t)j * 1024 + ch];
    q += bsq[(size_t)j * 1024 + ch];
  }
  double mean = s * invM;
  double var = q * invM - mean * mean;
  double sc = (double)g[ch] / sqrt(var + 1e-5);
  float scf = (float)sc;
  float shf = (float)((double)be[ch] - mean * sc);
  float v = scf >= 0.f ? h5max[i] : h5min[i];
  out[i] = v * scf + shf;
}

}  // namespace

extern "C" void kernel_launch(void* const* d_in, const int* in_sizes, int n_in,
                              void* d_out, int out_size, void* d_ws, size_t ws_size,
                              hipStream_t stream) {
  const float* x = (const float*)d_in[0];
  const float *Wv[5], *bv[5], *gv[5], *bev[5];
  for (int i = 0; i < 5; i++) {
    Wv[i] = (const float*)d_in[1 + 4 * i];
    bv[i] = (const float*)d_in[2 + 4 * i];
    gv[i] = (const float*)d_in[3 + 4 * i];
    bev[i] = (const float*)d_in[4 + 4 * i];
  }

  char* ws = (char*)d_ws;
  size_t off = 0;
  auto alloc = [&](size_t bytes) {
    size_t r = off;
    off = (off + bytes + 255) & ~(size_t)255;
    return r;
  };
  const int BN = B * N;
  float* feat0 = (float*)(ws + alloc((size_t)BN * 3 * 4));
  int* idx = (int*)(ws + alloc((size_t)BN * KNN * 4));
  float* x1 = (float*)(ws + alloc((size_t)BN * 64 * 4));
  float* x2 = (float*)(ws + alloc((size_t)BN * 64 * 4));
  float* x3 = (float*)(ws + alloc((size_t)BN * 64 * 4));
  float* x4 = (float*)(ws + alloc((size_t)BN * 128 * 4));
  float* xT = (float*)(ws + alloc((size_t)BN * 64 * 4));
  float* ub = (float*)(ws + alloc((size_t)BN * 128 * 4));
  float* vb = (float*)(ws + alloc((size_t)BN * 128 * 4));
  float* hmax = (float*)(ws + alloc((size_t)BN * 128 * 4));  // reused as partMax/partMin
  float* hmin = (float*)(ws + alloc((size_t)BN * 128 * 4));  // reused as partSum/partSq
  float* sqf = (float*)(ws + alloc((size_t)BN * 4));
  // per-layer BN stat regions (sum+sq interleaved per layer), zeroed once
  double* lstats = (double*)(ws + alloc((size_t)4 * 2 * NPART * 128 * 8));
  double* bsum = (double*)(ws + alloc((size_t)B * 1024 * 8));
  double* bsq = (double*)(ws + alloc((size_t)B * 1024 * 8));
  float* h5max = (float*)(ws + alloc((size_t)B * 1024 * 4));
  float* h5min = (float*)(ws + alloc((size_t)B * 1024 * 4));

  double* sumL[4], *sqL[4];
  for (int l = 0; l < 4; l++) {
    sumL[l] = lstats + (size_t)l * 2 * NPART * 128;
    sqL[l] = sumL[l] + (size_t)NPART * 128;
  }

  float* partMax = hmax;
  float* partMin = hmax + 1024 * 1024;
  float* partSum = hmin;
  float* partSq = hmin + 1024 * 1024;

  const double invMk = 1.0 / ((double)BN * KNN);
  dim3 tgrid64(N / 32, B);

  // single upfront zeroing of all per-layer stat regions
  hipMemsetAsync(lstats, 0, (size_t)4 * 2 * NPART * 128 * 8, stream);

  // ---- layer 1: C=3 -> D=64 (x is already [B][3][N]) ----
  transpose_x_norm<<<(BN + 255) / 256, 256, 0, stream>>>(x, feat0, sqf);
  knn_fused<3><<<BN / 8, 256, 0, stream>>>(x, feat0, sqf, idx);
  gemm_uv<3, 64><<<BN / 64, 256, 0, stream>>>(feat0, Wv[0], bv[0], ub, vb);
  combine_max<64><<<BN / 4, 256, 0, stream>>>(ub, vb, idx, hmax, hmin, sumL[0], sqL[0]);
  bn_apply_fused<64><<<256, 256, 0, stream>>>(hmax, hmin, sumL[0], sqL[0], gv[0], bev[0], x1,
                                              BN * 64, invMk);

  // ---- layer 2: C=64 -> D=64 ----
  transpose64_norm<<<tgrid64, 256, 0, stream>>>(x1, xT, sqf);
  knn_fused64<<<BN / 16, 256, 0, stream>>>(xT, x1, sqf, idx);
  gemm_uv<64, 64><<<BN / 64, 256, 0, stream>>>(x1, Wv[1], bv[1], ub, vb);
  combine_max<64><<<BN / 4, 256, 0, stream>>>(ub, vb, idx, hmax, hmin, sumL[1], sqL[1]);
  bn_apply_fused<64><<<256, 256, 0, stream>>>(hmax, hmin, sumL[1], sqL[1], gv[1], bev[1], x2,
                                              BN * 64, invMk);

  // ---- layer 3: C=64 -> D=64 ----
  transpose64_norm<<<tgrid64, 256, 0, stream>>>(x2, xT, sqf);
  knn_fused64<<<BN / 16, 256, 0, stream>>>(xT, x2, sqf, idx);
  gemm_uv<64, 64><<<BN / 64, 256, 0, stream>>>(x2, Wv[2], bv[2], ub, vb);
  combine_max<64><<<BN / 4, 256, 0, stream>>>(ub, vb, idx, hmax, hmin, sumL[2], sqL[2]);
  bn_apply_fused<64><<<256, 256, 0, stream>>>(hmax, hmin, sumL[2], sqL[2], gv[2], bev[2], x3,
                                              BN * 64, invMk);

  // ---- layer 4: C=64 -> D=128 ----
  transpose64_norm<<<tgrid64, 256, 0, stream>>>(x3, xT, sqf);
  knn_fused64<<<BN / 16, 256, 0, stream>>>(xT, x3, sqf, idx);
  gemm_uv<64, 128><<<BN / 64, 256, 0, stream>>>(x3, Wv[3], bv[3], ub, vb);
  combine_max<128><<<BN / 2, 256, 0, stream>>>(ub, vb, idx, hmax, hmin, sumL[3], sqL[3]);
  bn_apply_fused<128><<<256, 256, 0, stream>>>(hmax, hmin, sumL[3], sqL[3], gv[3], bev[3], x4,
                                               BN * 128, invMk);

  // ---- final: [BN,320] @ [320,1024], max over n; atomic-free partials ----
  final_gemm<<<BN / 16, 256, 0, stream>>>(x1, x2, x3, x4, Wv[4], bv[4], partMax, partMin,
                                          partSum, partSq);
  final_reduce<<<32, 256, 0, stream>>>(partMax, partMin, partSum, partSq, h5max, h5min, bsum,
                                       bsq);
  final_apply_fused<<<(B * 1024 + 255) / 256, 256, 0, stream>>>(h5max, h5min, bsum, bsq,
                                                                gv[4], bev[4], (float*)d_out,
                                                                1.0 / (double)BN);
}

// Round 14
// 838.073 us; speedup vs baseline: 3.1226x; 1.0577x over previous
//
#include <hip/hip_runtime.h>
#include <hip/hip_fp16.h>
#include <stdint.h>

namespace {

constexpr int B = 8, N = 2048, KNN = 20;
constexpr int NPART = 64;

typedef _Float16 h2_t __attribute__((ext_vector_type(2)));

__device__ __forceinline__ unsigned int pack_h2(float a, float b) {
  __half2 h = __floats2half2_rn(a, b);
  return *(unsigned int*)&h;
}

__device__ __forceinline__ float dot2f(unsigned int a, unsigned int b, float c) {
#if __has_builtin(__builtin_amdgcn_fdot2)
  h2_t ha, hb;
  *(unsigned int*)&ha = a;
  *(unsigned int*)&hb = b;
  return __builtin_amdgcn_fdot2(ha, hb, c, false);
#else
  __half2 ha = *(__half2*)&a, hb = *(__half2*)&b;
  c = fmaf(__low2float(ha), __low2float(hb), c);
  c = fmaf(__high2float(ha), __high2float(hb), c);
  return c;
#endif
}

// Fused: x [B][3][N] -> feat0 [BN][3] + fp32 sq-norms
__global__ void __launch_bounds__(256) transpose_x_norm(const float* __restrict__ x,
                                                        float* __restrict__ f,
                                                        float* __restrict__ sqf) {
  int i = blockIdx.x * 256 + threadIdx.x;
  if (i >= B * N) return;
  int b = i >> 11, n = i & (N - 1);
  const float* xb = x + (size_t)b * 3 * N;
  float v0 = xb[n], v1 = xb[N + n], v2 = xb[2 * N + n];
  float* fp = f + (size_t)i * 3;
  fp[0] = v0;
  fp[1] = v1;
  fp[2] = v2;
  sqf[i] = fmaf(v0, v0, fmaf(v1, v1, v2 * v2));
}

// Fused: [B][N][64] -> fp16-packed channel-pair layout [B][32][N] (half2 as uint)
// + per-point fp32 sq-norms. Block = 32 points x 64 ch; grid (N/32, B).
__global__ void __launch_bounds__(256) transpose64h_norm(const float* __restrict__ in,
                                                         unsigned int* __restrict__ outH,
                                                         float* __restrict__ sqf) {
  __shared__ float tl[32][65];
  int t = threadIdx.x;
  int n0 = blockIdx.x * 32;
  int b = blockIdx.y;
  const float* ib = in + (size_t)b * N * 64;
  unsigned int* ob = outH + (size_t)b * 32 * N;
  int pt = t >> 3, ch0 = (t & 7) * 8;
  const float4* src = (const float4*)(ib + (size_t)(n0 + pt) * 64 + ch0);
  float4 a0 = src[0], a1 = src[1];
  tl[pt][ch0 + 0] = a0.x;
  tl[pt][ch0 + 1] = a0.y;
  tl[pt][ch0 + 2] = a0.z;
  tl[pt][ch0 + 3] = a0.w;
  tl[pt][ch0 + 4] = a1.x;
  tl[pt][ch0 + 5] = a1.y;
  tl[pt][ch0 + 6] = a1.z;
  tl[pt][ch0 + 7] = a1.w;
  __syncthreads();
  if (t < 32) {
    float s = 0.f;
#pragma unroll 8
    for (int c = 0; c < 64; c++) {
      float v = tl[t][c];
      s = fmaf(v, v, s);
    }
    sqf[(size_t)b * N + n0 + t] = s;
  }
  int p = t >> 3, j0 = (t & 7) * 4;  // pair p, 4 points
  uint4 w;
  w.x = pack_h2(tl[j0 + 0][2 * p], tl[j0 + 0][2 * p + 1]);
  w.y = pack_h2(tl[j0 + 1][2 * p], tl[j0 + 1][2 * p + 1]);
  w.z = pack_h2(tl[j0 + 2][2 * p], tl[j0 + 2][2 * p + 1]);
  w.w = pack_h2(tl[j0 + 3][2 * p], tl[j0 + 3][2 * p + 1]);
  *(uint4*)(ob + (size_t)p * N + n0 + j0) = w;
}

// Wave-wide min, result in ALL lanes.
__device__ __forceinline__ float wave_min_f32(float x) {
  int t;
  t = __builtin_amdgcn_update_dpp(__float_as_int(x), __float_as_int(x), 0x121, 0xf, 0xf, false);
  x = fminf(x, __int_as_float(t));
  t = __builtin_amdgcn_update_dpp(__float_as_int(x), __float_as_int(x), 0x122, 0xf, 0xf, false);
  x = fminf(x, __int_as_float(t));
  t = __builtin_amdgcn_update_dpp(__float_as_int(x), __float_as_int(x), 0x124, 0xf, 0xf, false);
  x = fminf(x, __int_as_float(t));
  t = __builtin_amdgcn_update_dpp(__float_as_int(x), __float_as_int(x), 0x128, 0xf, 0xf, false);
  x = fminf(x, __int_as_float(t));
  x = fminf(x, __shfl_xor(x, 16, 64));
  x = fminf(x, __shfl_xor(x, 32, 64));
  return x;
}

// fp32 candidate selection + fp64 exact refine for TWO queries, interleaved.
// A[32] holds dot(q, point) on entry for points pt(k) = (k>>2)*256 + lane*4 + (k&3).
template <int C>
__device__ __forceinline__ void select_refine2(float (&A0)[32], float (&A1)[32], int lane,
                                               int q0loc, int q1loc,
                                               const float* __restrict__ sqb,
                                               const float* __restrict__ rowB,
                                               const float (*qfeat)[C], int (*candBuf)[64],
                                               int* __restrict__ op0, int* __restrict__ op1) {
  const float4* sq4 = (const float4*)sqb;
#pragma unroll
  for (int j8 = 0; j8 < 8; j8++) {
    float4 sv = sq4[j8 * 64 + lane];
    A0[4 * j8 + 0] = fmaf(-2.f, A0[4 * j8 + 0], sv.x);
    A0[4 * j8 + 1] = fmaf(-2.f, A0[4 * j8 + 1], sv.y);
    A0[4 * j8 + 2] = fmaf(-2.f, A0[4 * j8 + 2], sv.z);
    A0[4 * j8 + 3] = fmaf(-2.f, A0[4 * j8 + 3], sv.w);
    A1[4 * j8 + 0] = fmaf(-2.f, A1[4 * j8 + 0], sv.x);
    A1[4 * j8 + 1] = fmaf(-2.f, A1[4 * j8 + 1], sv.y);
    A1[4 * j8 + 2] = fmaf(-2.f, A1[4 * j8 + 2], sv.z);
    A1[4 * j8 + 3] = fmaf(-2.f, A1[4 * j8 + 3], sv.w);
  }
  float s0[8], s1[8];
#pragma unroll
  for (int i = 0; i < 8; i++) {
    s0[i] = 1e30f;
    s1[i] = 1e30f;
  }
#pragma unroll
  for (int k = 0; k < 32; k++) {
    float t0 = A0[k], t1 = A1[k];
#pragma unroll
    for (int i = 0; i < 8; i++) {
      float lo0 = fminf(s0[i], t0);
      t0 = fmaxf(s0[i], t0);
      s0[i] = lo0;
      float lo1 = fminf(s1[i], t1);
      t1 = fmaxf(s1[i], t1);
      s1[i] = lo1;
    }
  }
  float T0 = 0.f, T1 = 0.f;
  for (int it = 0; it < 32; it++) {
    float m0 = wave_min_f32(s0[0]);
    float m1 = wave_min_f32(s1[0]);
    bool w0 = (s0[0] == m0);
    bool w1 = (s1[0] == m1);
#pragma unroll
    for (int i = 0; i < 7; i++) {
      s0[i] = w0 ? s0[i + 1] : s0[i];
      s1[i] = w1 ? s1[i + 1] : s1[i];
    }
    s0[7] = w0 ? 1e30f : s0[7];
    s1[7] = w1 ? 1e30f : s1[7];
    T0 = m0;
    T1 = m1;
  }
  int base0 = 0, base1 = 0;
#pragma unroll
  for (int k = 0; k < 32; k++) {
    int pt = (k >> 2) * 256 + lane * 4 + (k & 3);
    bool p0 = (A0[k] <= T0);
    unsigned long long mk0 = __ballot(p0);
    if (p0) {
      int pos = base0 + (int)__popcll(mk0 & ((1ull << lane) - 1));
      if (pos < 64) candBuf[q0loc][pos] = pt;
    }
    base0 += (int)__popcll(mk0);
    bool p1 = (A1[k] <= T1);
    unsigned long long mk1 = __ballot(p1);
    if (p1) {
      int pos = base1 + (int)__popcll(mk1 & ((1ull << lane) - 1));
      if (pos < 64) candBuf[q1loc][pos] = pt;
    }
    base1 += (int)__popcll(mk1);
  }
  int cnt0 = base0 < 64 ? base0 : 64;
  int cnt1 = base1 < 64 ? base1 : 64;
  int mc0 = (lane < cnt0) ? candBuf[q0loc][lane] : 0;
  int mc1 = (lane < cnt1) ? candBuf[q1loc][lane] : 0;
  double dd0 = 0.0, dd1 = 0.0;
  if constexpr (C % 4 == 0) {
    const float4* r40 = (const float4*)(rowB + (size_t)mc0 * C);
    const float4* r41 = (const float4*)(rowB + (size_t)mc1 * C);
    const float4* q40 = (const float4*)(&qfeat[q0loc][0]);
    const float4* q41 = (const float4*)(&qfeat[q1loc][0]);
#pragma unroll 4
    for (int k = 0; k < C / 4; k++) {
      float4 rv0 = r40[k], qv0 = q40[k];
      float4 rv1 = r41[k], qv1 = q41[k];
      double e0 = (double)qv0.x - (double)rv0.x;
      dd0 = fma(e0, e0, dd0);
      double e1 = (double)qv0.y - (double)rv0.y;
      dd0 = fma(e1, e1, dd0);
      double e2 = (double)qv0.z - (double)rv0.z;
      dd0 = fma(e2, e2, dd0);
      double e3 = (double)qv0.w - (double)rv0.w;
      dd0 = fma(e3, e3, dd0);
      double f0 = (double)qv1.x - (double)rv1.x;
      dd1 = fma(f0, f0, dd1);
      double f1 = (double)qv1.y - (double)rv1.y;
      dd1 = fma(f1, f1, dd1);
      double f2 = (double)qv1.z - (double)rv1.z;
      dd1 = fma(f2, f2, dd1);
      double f3 = (double)qv1.w - (double)rv1.w;
      dd1 = fma(f3, f3, dd1);
    }
  } else {
    const float* r0 = rowB + (size_t)mc0 * C;
    const float* r1 = rowB + (size_t)mc1 * C;
#pragma unroll
    for (int c = 0; c < C; c++) {
      double e0 = (double)qfeat[q0loc][c] - (double)r0[c];
      dd0 = fma(e0, e0, dd0);
      double e1 = (double)qfeat[q1loc][c] - (double)r1[c];
      dd1 = fma(e1, e1, dd1);
    }
  }
  int myi0 = (lane < cnt0) ? mc0 : 0x7fffffff;
  int myi1 = (lane < cnt1) ? mc1 : 0x7fffffff;
  if (lane >= cnt0) dd0 = 1e300;
  if (lane >= cnt1) dd1 = 1e300;
#pragma unroll
  for (int k = 2; k <= 64; k <<= 1) {
#pragma unroll
    for (int j = k >> 1; j > 0; j >>= 1) {
      double od0 = __shfl_xor(dd0, j, 64);
      int oi0 = __shfl_xor(myi0, j, 64);
      double od1 = __shfl_xor(dd1, j, 64);
      int oi1 = __shfl_xor(myi1, j, 64);
      bool up = (lane & k) == 0;
      bool lower = (lane & j) == 0;
      bool dir = (up == lower);
      bool cmp0 = (od0 < dd0) || (od0 == dd0 && oi0 < myi0);
      if (dir ? cmp0 : !cmp0) {
        dd0 = od0;
        myi0 = oi0;
      }
      bool cmp1 = (od1 < dd1) || (od1 == dd1 && oi1 < myi1);
      if (dir ? cmp1 : !cmp1) {
        dd1 = od1;
        myi1 = oi1;
      }
    }
  }
  if (lane < KNN) {
    op0[lane] = myi0;
    op1[lane] = myi1;
  }
}

// C=3: 8 queries per 256-thread block; each wave owns 2 queries; direct global reads.
template <int C>
__global__ void __launch_bounds__(256) knn_fused(const float* __restrict__ fT,
                                                 const float* __restrict__ rowF,
                                                 const float* __restrict__ sqf,
                                                 int* __restrict__ idx20) {
  __shared__ __align__(16) float qfeat[8][C];
  __shared__ int candBuf[8][64];
  int t = threadIdx.x, w = t >> 6, lane = t & 63;
  int q0 = blockIdx.x * 8;
  int b = q0 >> 11;
  for (int i = t; i < 8 * C; i += 256) qfeat[i / C][i % C] = rowF[(size_t)q0 * C + i];
  __syncthreads();
  const float* fTb = fT + (size_t)b * C * N;
  const float* rowB = rowF + (((size_t)b) << 11) * C;
  const float* sqb = sqf + (((size_t)b) << 11);
  int qa = w * 2, qbl = w * 2 + 1;
  float acc0[32], acc1[32];
#pragma unroll
  for (int j = 0; j < 32; j++) {
    acc0[j] = 0.f;
    acc1[j] = 0.f;
  }
  for (int c = 0; c < C; c++) {
    float qc0 = qfeat[qa][c], qc1 = qfeat[qbl][c];
    const float4* r4 = (const float4*)(fTb + (size_t)c * N);
#pragma unroll
    for (int j8 = 0; j8 < 8; j8++) {
      float4 v = r4[j8 * 64 + lane];
      acc0[4 * j8 + 0] = fmaf(v.x, qc0, acc0[4 * j8 + 0]);
      acc0[4 * j8 + 1] = fmaf(v.y, qc0, acc0[4 * j8 + 1]);
      acc0[4 * j8 + 2] = fmaf(v.z, qc0, acc0[4 * j8 + 2]);
      acc0[4 * j8 + 3] = fmaf(v.w, qc0, acc0[4 * j8 + 3]);
      acc1[4 * j8 + 0] = fmaf(v.x, qc1, acc1[4 * j8 + 0]);
      acc1[4 * j8 + 1] = fmaf(v.y, qc1, acc1[4 * j8 + 1]);
      acc1[4 * j8 + 2] = fmaf(v.z, qc1, acc1[4 * j8 + 2]);
      acc1[4 * j8 + 3] = fmaf(v.w, qc1, acc1[4 * j8 + 3]);
    }
  }
  select_refine2<C>(acc0, acc1, lane, qa, qbl, sqb, rowB, qfeat, candBuf,
                    idx20 + (size_t)(q0 + qa) * KNN, idx20 + (size_t)(q0 + qbl) * KNN);
}

// C=64 fp16 dot phase: features packed as channel-pair half2 [B][32][N].
// 16 queries per block, 4 per wave; one channel-pair (8 KB) staged per chunk,
// double-buffered, issue-early/write-late (structure identical to proven fp32).
__global__ void __launch_bounds__(256) knn_fused64h(const unsigned int* __restrict__ fH,
                                                    const float* __restrict__ rowF,
                                                    const float* __restrict__ sqf,
                                                    int* __restrict__ idx20) {
  __shared__ __align__(16) unsigned int stage[2][N];  // 16 KB
  __shared__ __align__(16) float qfeat[16][64];       // 4 KB (for fp64 refine)
  __shared__ unsigned int qh[16][32];                 // 2 KB packed query pairs
  __shared__ int candBuf[16][64];                     // 4 KB
  int t = threadIdx.x, w = t >> 6, lane = t & 63;
  int q0 = blockIdx.x * 16;
  int b = q0 >> 11;
  const unsigned int* fHb = fH + (size_t)b * 32 * N;
  const uint4* src4 = (const uint4*)fHb;  // pair p = uint4 [p*512 .. p*512+511]
  for (int i = t; i < 16 * 64; i += 256) qfeat[i >> 6][i & 63] = rowF[(size_t)q0 * 64 + i];
  for (int i = t; i < 16 * 32; i += 256) {
    int q = i >> 5, p = i & 31;
    const float* qp = rowF + (size_t)(q0 + q) * 64 + 2 * p;
    qh[q][p] = pack_h2(qp[0], qp[1]);
  }

  uint4 st[2];
  st[0] = src4[t];
  st[1] = src4[t + 256];
  {
    uint4* d4 = (uint4*)&stage[0][0];
    d4[t] = st[0];
    d4[t + 256] = st[1];
  }
  __syncthreads();

  int qa = w * 4;
  float acc0[32], acc1[32], acc2[32], acc3[32];
#pragma unroll
  for (int j = 0; j < 32; j++) {
    acc0[j] = 0.f;
    acc1[j] = 0.f;
    acc2[j] = 0.f;
    acc3[j] = 0.f;
  }

  for (int chunk = 0; chunk < 32; chunk++) {
    int cur = chunk & 1;
    if (chunk < 31) {  // issue next pair's loads early
      st[0] = src4[(chunk + 1) * 512 + t];
      st[1] = src4[(chunk + 1) * 512 + t + 256];
    }
    unsigned int qh0 = qh[qa + 0][chunk], qh1 = qh[qa + 1][chunk];
    unsigned int qh2 = qh[qa + 2][chunk], qh3 = qh[qa + 3][chunk];
    const uint4* r4 = (const uint4*)&stage[cur][0];
#pragma unroll
    for (int j8 = 0; j8 < 8; j8++) {
      uint4 v = r4[j8 * 64 + lane];
      acc0[4 * j8 + 0] = dot2f(v.x, qh0, acc0[4 * j8 + 0]);
      acc0[4 * j8 + 1] = dot2f(v.y, qh0, acc0[4 * j8 + 1]);
      acc0[4 * j8 + 2] = dot2f(v.z, qh0, acc0[4 * j8 + 2]);
      acc0[4 * j8 + 3] = dot2f(v.w, qh0, acc0[4 * j8 + 3]);
      acc1[4 * j8 + 0] = dot2f(v.x, qh1, acc1[4 * j8 + 0]);
      acc1[4 * j8 + 1] = dot2f(v.y, qh1, acc1[4 * j8 + 1]);
      acc1[4 * j8 + 2] = dot2f(v.z, qh1, acc1[4 * j8 + 2]);
      acc1[4 * j8 + 3] = dot2f(v.w, qh1, acc1[4 * j8 + 3]);
      acc2[4 * j8 + 0] = dot2f(v.x, qh2, acc2[4 * j8 + 0]);
      acc2[4 * j8 + 1] = dot2f(v.y, qh2, acc2[4 * j8 + 1]);
      acc2[4 * j8 + 2] = dot2f(v.z, qh2, acc2[4 * j8 + 2]);
      acc2[4 * j8 + 3] = dot2f(v.w, qh2, acc2[4 * j8 + 3]);
      acc3[4 * j8 + 0] = dot2f(v.x, qh3, acc3[4 * j8 + 0]);
      acc3[4 * j8 + 1] = dot2f(v.y, qh3, acc3[4 * j8 + 1]);
      acc3[4 * j8 + 2] = dot2f(v.z, qh3, acc3[4 * j8 + 2]);
      acc3[4 * j8 + 3] = dot2f(v.w, qh3, acc3[4 * j8 + 3]);
    }
    if (chunk < 31) {  // write-late into the other buffer
      uint4* d4 = (uint4*)&stage[cur ^ 1][0];
      d4[t] = st[0];
      d4[t + 256] = st[1];
    }
    __syncthreads();
  }
  const float* rowB = rowF + (((size_t)b) << 11) * 64;
  const float* sqb = sqf + (((size_t)b) << 11);
  select_refine2<64>(acc0, acc1, lane, qa + 0, qa + 1, sqb, rowB, qfeat, candBuf,
                     idx20 + (size_t)(q0 + qa + 0) * KNN, idx20 + (size_t)(q0 + qa + 1) * KNN);
  select_refine2<64>(acc2, acc3, lane, qa + 2, qa + 3, sqb, rowB, qfeat, candBuf,
                     idx20 + (size_t)(q0 + qa + 2) * KNN, idx20 + (size_t)(q0 + qa + 3) * KNN);
}

// EdgeConv factorization: u' = A*(Wt - Wb) + bias, v = A*Wb.
template <int K, int D>
__global__ void __launch_bounds__(256) gemm_uv(const float* __restrict__ A,
                                               const float* __restrict__ W,
                                               const float* __restrict__ bias,
                                               float* __restrict__ u, float* __restrict__ v) {
  constexpr int RG = 256 / D;
  constexpr int RPT = 64 / RG;
  __shared__ float At[64][K];
  int t = threadIdx.x;
  int n0 = blockIdx.x * 64;
  for (int i = t; i < 64 * K; i += 256) At[i / K][i % K] = A[(size_t)n0 * K + i];
  __syncthreads();
  int col = t & (D - 1), rg = t / D;
  float au[RPT], av[RPT];
  float bb = bias[col];
#pragma unroll
  for (int r = 0; r < RPT; r++) {
    au[r] = bb;
    av[r] = 0.f;
  }
  for (int c = 0; c < K; c++) {
    float wt = W[(size_t)c * D + col];
    float wb = W[(size_t)(K + c) * D + col];
    float wu = wt - wb;
#pragma unroll
    for (int r = 0; r < RPT; r++) {
      float a = At[rg * RPT + r][c];
      au[r] = fmaf(a, wu, au[r]);
      av[r] = fmaf(a, wb, av[r]);
    }
  }
#pragma unroll
  for (int r = 0; r < RPT; r++) {
    u[(size_t)(n0 + rg * RPT + r) * D + col] = au[r];
    v[(size_t)(n0 + rg * RPT + r) * D + col] = av[r];
  }
}

// h[n,j,d] = relu(u'[n,d] + v[idx[n,j],d]); max/min over j + fp64 stats.
template <int D>
__global__ void __launch_bounds__(256) combine_max(const float* __restrict__ u,
                                                   const float* __restrict__ v,
                                                   const int* __restrict__ idx20,
                                                   float* __restrict__ hmax,
                                                   float* __restrict__ hmin,
                                                   double* __restrict__ sumP,
                                                   double* __restrict__ sqP) {
  constexpr int PPB = 256 / D;
  int t = threadIdx.x;
  int p = t / D, d = t & (D - 1);
  int bn = blockIdx.x * PPB + p;
  int b = bn >> 11;
  const int* ip = idx20 + (size_t)bn * KNN;
  float up = u[(size_t)bn * D + d];
  const float* vb = v + ((size_t)b << 11) * D;
  float mx = -1e30f, mn = 1e30f;
  double s = 0.0, q = 0.0;
#pragma unroll 4
  for (int j = 0; j < KNN; j++) {
    int nb = ip[j];
    float hv = up + vb[(size_t)nb * D + d];
    hv = hv > 0.f ? hv : 0.f;
    mx = fmaxf(mx, hv);
    mn = fminf(mn, hv);
    double hd = (double)hv;
    s += hd;
    q = fma(hd, hd, q);
  }
  hmax[(size_t)bn * D + d] = mx;
  hmin[(size_t)bn * D + d] = mn;
  int slot = bn & (NPART - 1);
  atomicAdd(&sumP[(size_t)slot * D + d], s);
  atomicAdd(&sqP[(size_t)slot * D + d], q);
}

// Fused bn_finalize + bn_apply.
template <int D>
__global__ void __launch_bounds__(256) bn_apply_fused(const float* __restrict__ hmax,
                                                      const float* __restrict__ hmin,
                                                      const double* __restrict__ sumP,
                                                      const double* __restrict__ sqP,
                                                      const float* __restrict__ g,
                                                      const float* __restrict__ be,
                                                      float* __restrict__ out, int total,
                                                      double invM) {
  constexpr int NG = 256 / D;
  __shared__ double redsS[256], redqS[256];
  __shared__ float scl[D], shf[D];
  int t = threadIdx.x;
  int d = t & (D - 1), grp = t / D;
  double s = 0.0, q = 0.0;
  for (int i = grp; i < NPART; i += NG) {
    s += sumP[(size_t)i * D + d];
    q += sqP[(size_t)i * D + d];
  }
  redsS[t] = s;
  redqS[t] = q;
  __syncthreads();
  if (t < D) {
#pragma unroll
    for (int i = 1; i < NG; i++) {
      s += redsS[i * D + t];
      q += redqS[i * D + t];
    }
    double mean = s * invM;
    double var = q * invM - mean * mean;
    double sc = (double)g[t] / sqrt(var + 1e-5);
    scl[t] = (float)sc;
    shf[t] = (float)((double)be[t] - mean * sc);
  }
  __syncthreads();
  float sc = scl[d], sh = shf[d];
  for (int i = blockIdx.x * 256 + t; i < total; i += 256 * 256) {
    float v = sc >= 0.f ? hmax[i] : hmin[i];
    out[i] = v * sc + sh;
  }
}

// [16384,320]x[320,1024]: block = 16 rows x 1024 cols; per-block partials.
__global__ void __launch_bounds__(256) final_gemm(const float* __restrict__ x1,
                                                  const float* __restrict__ x2,
                                                  const float* __restrict__ x3,
                                                  const float* __restrict__ x4,
                                                  const float* __restrict__ W5,
                                                  const float* __restrict__ b5,
                                                  float* __restrict__ partMax,
                                                  float* __restrict__ partMin,
                                                  float* __restrict__ partSum,
                                                  float* __restrict__ partSq) {
  __shared__ __align__(16) float At[16][320];  // 20 KB
  int t = threadIdx.x;
  int blk = blockIdx.x;
  int n0 = blk * 16;
  int col = t * 4;
  for (int i = t; i < 16 * 320; i += 256) {
    int r = i / 320, c = i % 320;
    int n = n0 + r;
    float vv;
    if (c < 64) vv = x1[(size_t)n * 64 + c];
    else if (c < 128) vv = x2[(size_t)n * 64 + c - 64];
    else if (c < 192) vv = x3[(size_t)n * 64 + c - 128];
    else vv = x4[(size_t)n * 128 + c - 192];
    At[r][c] = vv;
  }
  __syncthreads();
  float4 acc[16];
  float4 bb = *(const float4*)(b5 + col);
#pragma unroll
  for (int r = 0; r < 16; r++) acc[r] = bb;
  for (int c4 = 0; c4 < 80; c4++) {
    const float* wbase = W5 + (size_t)c4 * 4 * 1024 + col;
    float4 w0 = *(const float4*)(wbase);
    float4 w1 = *(const float4*)(wbase + 1024);
    float4 w2 = *(const float4*)(wbase + 2048);
    float4 w3 = *(const float4*)(wbase + 3072);
#pragma unroll
    for (int r = 0; r < 16; r++) {
      float4 a = *(const float4*)(&At[r][c4 * 4]);
      acc[r].x = fmaf(a.x, w0.x, acc[r].x);
      acc[r].y = fmaf(a.x, w0.y, acc[r].y);
      acc[r].z = fmaf(a.x, w0.z, acc[r].z);
      acc[r].w = fmaf(a.x, w0.w, acc[r].w);
      acc[r].x = fmaf(a.y, w1.x, acc[r].x);
      acc[r].y = fmaf(a.y, w1.y, acc[r].y);
      acc[r].z = fmaf(a.y, w1.z, acc[r].z);
      acc[r].w = fmaf(a.y, w1.w, acc[r].w);
      acc[r].x = fmaf(a.z, w2.x, acc[r].x);
      acc[r].y = fmaf(a.z, w2.y, acc[r].y);
      acc[r].z = fmaf(a.z, w2.z, acc[r].z);
      acc[r].w = fmaf(a.z, w2.w, acc[r].w);
      acc[r].x = fmaf(a.w, w3.x, acc[r].x);
      acc[r].y = fmaf(a.w, w3.y, acc[r].y);
      acc[r].z = fmaf(a.w, w3.z, acc[r].z);
      acc[r].w = fmaf(a.w, w3.w, acc[r].w);
    }
  }
  float mx[4] = {-1e30f, -1e30f, -1e30f, -1e30f};
  float mn[4] = {1e30f, 1e30f, 1e30f, 1e30f};
  double sv[4] = {0, 0, 0, 0}, qv[4] = {0, 0, 0, 0};
#pragma unroll
  for (int r = 0; r < 16; r++) {
    float h0 = acc[r].x > 0.f ? acc[r].x : 0.f;
    float h1 = acc[r].y > 0.f ? acc[r].y : 0.f;
    float h2 = acc[r].z > 0.f ? acc[r].z : 0.f;
    float h3 = acc[r].w > 0.f ? acc[r].w : 0.f;
    mx[0] = fmaxf(mx[0], h0);
    mn[0] = fminf(mn[0], h0);
    sv[0] += h0;
    qv[0] = fma((double)h0, (double)h0, qv[0]);
    mx[1] = fmaxf(mx[1], h1);
    mn[1] = fminf(mn[1], h1);
    sv[1] += h1;
    qv[1] = fma((double)h1, (double)h1, qv[1]);
    mx[2] = fmaxf(mx[2], h2);
    mn[2] = fminf(mn[2], h2);
    sv[2] += h2;
    qv[2] = fma((double)h2, (double)h2, qv[2]);
    mx[3] = fmaxf(mx[3], h3);
    mn[3] = fminf(mn[3], h3);
    sv[3] += h3;
    qv[3] = fma((double)h3, (double)h3, qv[3]);
  }
  size_t base = (size_t)blk * 1024;
  *(float4*)(partMax + base + col) = make_float4(mx[0], mx[1], mx[2], mx[3]);
  *(float4*)(partMin + base + col) = make_float4(mn[0], mn[1], mn[2], mn[3]);
  *(float4*)(partSum + base + col) =
      make_float4((float)sv[0], (float)sv[1], (float)sv[2], (float)sv[3]);
  *(float4*)(partSq + base + col) =
      make_float4((float)qv[0], (float)qv[1], (float)qv[2], (float)qv[3]);
}

// Reduce 128 per-block partials per (batch, channel).
__global__ void __launch_bounds__(256) final_reduce(const float* __restrict__ partMax,
                                                    const float* __restrict__ partMin,
                                                    const float* __restrict__ partSum,
                                                    const float* __restrict__ partSq,
                                                    float* __restrict__ h5max,
                                                    float* __restrict__ h5min,
                                                    double* __restrict__ bsum,
                                                    double* __restrict__ bsq) {
  int bid = blockIdx.x;
  int b = bid >> 2;
  int ch = ((bid & 3) << 8) + threadIdx.x;
  float mx = -1e30f, mn = 1e30f;
  double s = 0.0, q = 0.0;
  for (int j = 0; j < 128; j++) {
    size_t base = ((size_t)(b * 128 + j) << 10) + ch;
    mx = fmaxf(mx, partMax[base]);
    mn = fminf(mn, partMin[base]);
    s += (double)partSum[base];
    q += (double)partSq[base];
  }
  h5max[(size_t)b * 1024 + ch] = mx;
  h5min[(size_t)b * 1024 + ch] = mn;
  bsum[(size_t)b * 1024 + ch] = s;
  bsq[(size_t)b * 1024 + ch] = q;
}

// Fused final bn_finalize + apply.
__global__ void __launch_bounds__(256) final_apply_fused(const float* __restrict__ h5max,
                                                         const float* __restrict__ h5min,
                                                         const double* __restrict__ bsum,
                                                         const double* __restrict__ bsq,
                                                         const float* __restrict__ g,
                                                         const float* __restrict__ be,
                                                         float* __restrict__ out,
                                                         double invM) {
  int i = blockIdx.x * 256 + threadIdx.x;
  if (i >= B * 1024) return;
  int ch = i & 1023;
  double s = 0.0, q = 0.0;
#pragma unroll
  for (int j = 0; j < 8; j++) {
    s += bsum[(size_t)j * 1024 + ch];
    q += bsq[(size_t)j * 1024 + ch];
  }
  double mean = s * invM;
  double var = q * invM - mean * mean;
  double sc = (double)g[ch] / sqrt(var + 1e-5);
  float scf = (float)sc;
  float shf = (float)((double)be[ch] - mean * sc);
  float v = scf >= 0.f ? h5max[i] : h5min[i];
  out[i] = v * scf + shf;
}

}  // namespace

extern "C" void kernel_launch(void* const* d_in, const int* in_sizes, int n_in,
                              void* d_out, int out_size, void* d_ws, size_t ws_size,
                              hipStream_t stream) {
  const float* x = (const float*)d_in[0];
  const float *Wv[5], *bv[5], *gv[5], *bev[5];
  for (int i = 0; i < 5; i++) {
    Wv[i] = (const float*)d_in[1 + 4 * i];
    bv[i] = (const float*)d_in[2 + 4 * i];
    gv[i] = (const float*)d_in[3 + 4 * i];
    bev[i] = (const float*)d_in[4 + 4 * i];
  }

  char* ws = (char*)d_ws;
  size_t off = 0;
  auto alloc = [&](size_t bytes) {
    size_t r = off;
    off = (off + bytes + 255) & ~(size_t)255;
    return r;
  };
  const int BN = B * N;
  float* feat0 = (float*)(ws + alloc((size_t)BN * 3 * 4));
  int* idx = (int*)(ws + alloc((size_t)BN * KNN * 4));
  float* x1 = (float*)(ws + alloc((size_t)BN * 64 * 4));
  float* x2 = (float*)(ws + alloc((size_t)BN * 64 * 4));
  float* x3 = (float*)(ws + alloc((size_t)BN * 64 * 4));
  float* x4 = (float*)(ws + alloc((size_t)BN * 128 * 4));
  unsigned int* fH = (unsigned int*)(ws + alloc((size_t)BN * 32 * 4));  // fp16 pairs
  float* ub = (float*)(ws + alloc((size_t)BN * 128 * 4));
  float* vb = (float*)(ws + alloc((size_t)BN * 128 * 4));
  float* hmax = (float*)(ws + alloc((size_t)BN * 128 * 4));  // reused as partMax/partMin
  float* hmin = (float*)(ws + alloc((size_t)BN * 128 * 4));  // reused as partSum/partSq
  float* sqf = (float*)(ws + alloc((size_t)BN * 4));
  double* lstats = (double*)(ws + alloc((size_t)4 * 2 * NPART * 128 * 8));
  double* bsum = (double*)(ws + alloc((size_t)B * 1024 * 8));
  double* bsq = (double*)(ws + alloc((size_t)B * 1024 * 8));
  float* h5max = (float*)(ws + alloc((size_t)B * 1024 * 4));
  float* h5min = (float*)(ws + alloc((size_t)B * 1024 * 4));

  double* sumL[4], *sqL[4];
  for (int l = 0; l < 4; l++) {
    sumL[l] = lstats + (size_t)l * 2 * NPART * 128;
    sqL[l] = sumL[l] + (size_t)NPART * 128;
  }

  float* partMax = hmax;
  float* partMin = hmax + 1024 * 1024;
  float* partSum = hmin;
  float* partSq = hmin + 1024 * 1024;

  const double invMk = 1.0 / ((double)BN * KNN);
  dim3 tgrid64(N / 32, B);

  hipMemsetAsync(lstats, 0, (size_t)4 * 2 * NPART * 128 * 8, stream);

  // ---- layer 1: C=3 -> D=64 (x is already [B][3][N]) ----
  transpose_x_norm<<<(BN + 255) / 256, 256, 0, stream>>>(x, feat0, sqf);
  knn_fused<3><<<BN / 8, 256, 0, stream>>>(x, feat0, sqf, idx);
  gemm_uv<3, 64><<<BN / 64, 256, 0, stream>>>(feat0, Wv[0], bv[0], ub, vb);
  combine_max<64><<<BN / 4, 256, 0, stream>>>(ub, vb, idx, hmax, hmin, sumL[0], sqL[0]);
  bn_apply_fused<64><<<256, 256, 0, stream>>>(hmax, hmin, sumL[0], sqL[0], gv[0], bev[0], x1,
                                              BN * 64, invMk);

  // ---- layer 2: C=64 -> D=64 ----
  transpose64h_norm<<<tgrid64, 256, 0, stream>>>(x1, fH, sqf);
  knn_fused64h<<<BN / 16, 256, 0, stream>>>(fH, x1, sqf, idx);
  gemm_uv<64, 64><<<BN / 64, 256, 0, stream>>>(x1, Wv[1], bv[1], ub, vb);
  combine_max<64><<<BN / 4, 256, 0, stream>>>(ub, vb, idx, hmax, hmin, sumL[1], sqL[1]);
  bn_apply_fused<64><<<256, 256, 0, stream>>>(hmax, hmin, sumL[1], sqL[1], gv[1], bev[1], x2,
                                              BN * 64, invMk);

  // ---- layer 3: C=64 -> D=64 ----
  transpose64h_norm<<<tgrid64, 256, 0, stream>>>(x2, fH, sqf);
  knn_fused64h<<<BN / 16, 256, 0, stream>>>(fH, x2, sqf, idx);
  gemm_uv<64, 64><<<BN / 64, 256, 0, stream>>>(x2, Wv[2], bv[2], ub, vb);
  combine_max<64><<<BN / 4, 256, 0, stream>>>(ub, vb, idx, hmax, hmin, sumL[2], sqL[2]);
  bn_apply_fused<64><<<256, 256, 0, stream>>>(hmax, hmin, sumL[2], sqL[2], gv[2], bev[2], x3,
                                              BN * 64, invMk);

  // ---- layer 4: C=64 -> D=128 ----
  transpose64h_norm<<<tgrid64, 256, 0, stream>>>(x3, fH, sqf);
  knn_fused64h<<<BN / 16, 256, 0, stream>>>(fH, x3, sqf, idx);
  gemm_uv<64, 128><<<BN / 64, 256, 0, stream>>>(x3, Wv[3], bv[3], ub, vb);
  combine_max<128><<<BN / 2, 256, 0, stream>>>(ub, vb, idx, hmax, hmin, sumL[3], sqL[3]);
  bn_apply_fused<128><<<256, 256, 0, stream>>>(hmax, hmin, sumL[3], sqL[3], gv[3], bev[3], x4,
                                               BN * 128, invMk);

  // ---- final: [BN,320] @ [320,1024], max over n; atomic-free partials ----
  final_gemm<<<BN / 16, 256, 0, stream>>>(x1, x2, x3, x4, Wv[4], bv[4], partMax, partMin,
                                          partSum, partSq);
  final_reduce<<<32, 256, 0, stream>>>(partMax, partMin, partSum, partSq, h5max, h5min, bsum,
                                       bsq);
  final_apply_fused<<<(B * 1024 + 255) / 256, 256, 0, stream>>>(h5max, h5min, bsum, bsq,
                                                                gv[4], bev[4], (float*)d_out,
                                                                1.0 / (double)BN);
}

// Round 15
// 707.703 us; speedup vs baseline: 3.6978x; 1.1842x over previous
//
#include <hip/hip_runtime.h>
#include <hip/hip_fp16.h>
#include <stdint.h>

namespace {

constexpr int B = 8, N = 2048, KNN = 20;
constexpr int NPART = 64;

typedef _Float16 h2_t __attribute__((ext_vector_type(2)));

__device__ __forceinline__ unsigned int pack_h2(float a, float b) {
  __half2 h = __floats2half2_rn(a, b);
  return *(unsigned int*)&h;
}

__device__ __forceinline__ float dot2f(unsigned int a, unsigned int b, float c) {
#if __has_builtin(__builtin_amdgcn_fdot2)
  h2_t ha, hb;
  *(unsigned int*)&ha = a;
  *(unsigned int*)&hb = b;
  return __builtin_amdgcn_fdot2(ha, hb, c, false);
#else
  __half2 ha = *(__half2*)&a, hb = *(__half2*)&b;
  c = fmaf(__low2float(ha), __low2float(hb), c);
  c = fmaf(__high2float(ha), __high2float(hb), c);
  return c;
#endif
}

// Fused: x [B][3][N] -> feat0 [BN][3] + fp32 sq-norms
__global__ void __launch_bounds__(256) transpose_x_norm(const float* __restrict__ x,
                                                        float* __restrict__ f,
                                                        float* __restrict__ sqf) {
  int i = blockIdx.x * 256 + threadIdx.x;
  if (i >= B * N) return;
  int b = i >> 11, n = i & (N - 1);
  const float* xb = x + (size_t)b * 3 * N;
  float v0 = xb[n], v1 = xb[N + n], v2 = xb[2 * N + n];
  float* fp = f + (size_t)i * 3;
  fp[0] = v0;
  fp[1] = v1;
  fp[2] = v2;
  sqf[i] = fmaf(v0, v0, fmaf(v1, v1, v2 * v2));
}

// Fused: [B][N][64] -> fp16-packed channel-pair layout [B][32][N] (half2 as uint)
// + per-point fp32 sq-norms. Block = 32 points x 64 ch; grid (N/32, B).
__global__ void __launch_bounds__(256) transpose64h_norm(const float* __restrict__ in,
                                                         unsigned int* __restrict__ outH,
                                                         float* __restrict__ sqf) {
  __shared__ float tl[32][65];
  int t = threadIdx.x;
  int n0 = blockIdx.x * 32;
  int b = blockIdx.y;
  const float* ib = in + (size_t)b * N * 64;
  unsigned int* ob = outH + (size_t)b * 32 * N;
  int pt = t >> 3, ch0 = (t & 7) * 8;
  const float4* src = (const float4*)(ib + (size_t)(n0 + pt) * 64 + ch0);
  float4 a0 = src[0], a1 = src[1];
  tl[pt][ch0 + 0] = a0.x;
  tl[pt][ch0 + 1] = a0.y;
  tl[pt][ch0 + 2] = a0.z;
  tl[pt][ch0 + 3] = a0.w;
  tl[pt][ch0 + 4] = a1.x;
  tl[pt][ch0 + 5] = a1.y;
  tl[pt][ch0 + 6] = a1.z;
  tl[pt][ch0 + 7] = a1.w;
  __syncthreads();
  if (t < 32) {
    float s = 0.f;
#pragma unroll 8
    for (int c = 0; c < 64; c++) {
      float v = tl[t][c];
      s = fmaf(v, v, s);
    }
    sqf[(size_t)b * N + n0 + t] = s;
  }
  int p = t >> 3, j0 = (t & 7) * 4;  // pair p, 4 points
  uint4 w;
  w.x = pack_h2(tl[j0 + 0][2 * p], tl[j0 + 0][2 * p + 1]);
  w.y = pack_h2(tl[j0 + 1][2 * p], tl[j0 + 1][2 * p + 1]);
  w.z = pack_h2(tl[j0 + 2][2 * p], tl[j0 + 2][2 * p + 1]);
  w.w = pack_h2(tl[j0 + 3][2 * p], tl[j0 + 3][2 * p + 1]);
  *(uint4*)(ob + (size_t)p * N + n0 + j0) = w;
}

// Cross-lane bitonic sort of one fp32 value per lane (ascending by lane),
// two independent streams interleaved.
__device__ __forceinline__ void lane_sort64x2(float& v0, float& v1, int lane) {
#pragma unroll
  for (int k = 2; k <= 64; k <<= 1) {
#pragma unroll
    for (int j = k >> 1; j > 0; j >>= 1) {
      float o0 = __shfl_xor(v0, j, 64);
      float o1 = __shfl_xor(v1, j, 64);
      bool keepmin = (((lane & k) == 0) == ((lane & j) == 0));
      float mn0 = fminf(v0, o0), mx0 = fmaxf(v0, o0);
      v0 = keepmin ? mn0 : mx0;
      float mn1 = fminf(v1, o1), mx1 = fmaxf(v1, o1);
      v1 = keepmin ? mn1 : mx1;
    }
  }
}

// Ballot-compaction of candidates (A[k] <= T) into buf (cap 64); returns count.
__device__ __forceinline__ int compact_cand(const float (&A)[32], float T, int lane,
                                            int* __restrict__ buf) {
  int base = 0;
#pragma unroll
  for (int k = 0; k < 32; k++) {
    bool p = (A[k] <= T);
    unsigned long long mk = __ballot(p);
    if (p) {
      int pos = base + (int)__popcll(mk & ((1ull << lane) - 1));
      if (pos < 64) buf[pos] = (k >> 2) * 256 + lane * 4 + (k & 3);
    }
    base += (int)__popcll(mk);
  }
  return base;
}

// fp32 candidate selection + fp64 exact refine for TWO queries, interleaved.
// Cheap threshold (validated r9/r10): T = 24th smallest of 64 per-lane minima
// => candidate count >= 24 superset of fp32-top-24 >= true top-20; truncation
// at 64 identical to prior passing rounds. fp64 refine + bitonic unchanged.
// A[32] holds dot(q, point) on entry for points pt(k) = (k>>2)*256 + lane*4 + (k&3).
template <int C>
__device__ __forceinline__ void select_refine2(float (&A0)[32], float (&A1)[32], int lane,
                                               int q0loc, int q1loc,
                                               const float* __restrict__ sqb,
                                               const float* __restrict__ rowB,
                                               const float (*qfeat)[C], int (*candBuf)[64],
                                               int* __restrict__ op0, int* __restrict__ op1) {
  const float4* sq4 = (const float4*)sqb;
#pragma unroll
  for (int j8 = 0; j8 < 8; j8++) {
    float4 sv = sq4[j8 * 64 + lane];
    A0[4 * j8 + 0] = fmaf(-2.f, A0[4 * j8 + 0], sv.x);
    A0[4 * j8 + 1] = fmaf(-2.f, A0[4 * j8 + 1], sv.y);
    A0[4 * j8 + 2] = fmaf(-2.f, A0[4 * j8 + 2], sv.z);
    A0[4 * j8 + 3] = fmaf(-2.f, A0[4 * j8 + 3], sv.w);
    A1[4 * j8 + 0] = fmaf(-2.f, A1[4 * j8 + 0], sv.x);
    A1[4 * j8 + 1] = fmaf(-2.f, A1[4 * j8 + 1], sv.y);
    A1[4 * j8 + 2] = fmaf(-2.f, A1[4 * j8 + 2], sv.z);
    A1[4 * j8 + 3] = fmaf(-2.f, A1[4 * j8 + 3], sv.w);
  }
  // register-frugal per-lane min via 4 fmin chains per stream
  float p0 = fminf(A0[0], A0[1]), p1 = fminf(A0[2], A0[3]);
  float r0 = fminf(A1[0], A1[1]), r1 = fminf(A1[2], A1[3]);
#pragma unroll
  for (int k = 4; k < 32; k += 4) {
    p0 = fminf(p0, fminf(A0[k], A0[k + 1]));
    p1 = fminf(p1, fminf(A0[k + 2], A0[k + 3]));
    r0 = fminf(r0, fminf(A1[k], A1[k + 1]));
    r1 = fminf(r1, fminf(A1[k + 2], A1[k + 3]));
  }
  float m0 = fminf(p0, p1), m1 = fminf(r0, r1);
  lane_sort64x2(m0, m1, lane);
  float T0 = __shfl(m0, 23, 64);
  float T1 = __shfl(m1, 23, 64);
  int cnt0 = compact_cand(A0, T0, lane, candBuf[q0loc]);
  int cnt1 = compact_cand(A1, T1, lane, candBuf[q1loc]);
  cnt0 = cnt0 < 64 ? cnt0 : 64;
  cnt1 = cnt1 < 64 ? cnt1 : 64;
  // fp64 exact distances (difference formula), both gathers in flight together
  int mc0 = (lane < cnt0) ? candBuf[q0loc][lane] : 0;
  int mc1 = (lane < cnt1) ? candBuf[q1loc][lane] : 0;
  double dd0 = 0.0, dd1 = 0.0;
  if constexpr (C % 4 == 0) {
    const float4* r40 = (const float4*)(rowB + (size_t)mc0 * C);
    const float4* r41 = (const float4*)(rowB + (size_t)mc1 * C);
    const float4* q40 = (const float4*)(&qfeat[q0loc][0]);
    const float4* q41 = (const float4*)(&qfeat[q1loc][0]);
#pragma unroll 4
    for (int k = 0; k < C / 4; k++) {
      float4 rv0 = r40[k], qv0 = q40[k];
      float4 rv1 = r41[k], qv1 = q41[k];
      double e0 = (double)qv0.x - (double)rv0.x;
      dd0 = fma(e0, e0, dd0);
      double e1 = (double)qv0.y - (double)rv0.y;
      dd0 = fma(e1, e1, dd0);
      double e2 = (double)qv0.z - (double)rv0.z;
      dd0 = fma(e2, e2, dd0);
      double e3 = (double)qv0.w - (double)rv0.w;
      dd0 = fma(e3, e3, dd0);
      double f0 = (double)qv1.x - (double)rv1.x;
      dd1 = fma(f0, f0, dd1);
      double f1 = (double)qv1.y - (double)rv1.y;
      dd1 = fma(f1, f1, dd1);
      double f2 = (double)qv1.z - (double)rv1.z;
      dd1 = fma(f2, f2, dd1);
      double f3 = (double)qv1.w - (double)rv1.w;
      dd1 = fma(f3, f3, dd1);
    }
  } else {
    const float* r0p = rowB + (size_t)mc0 * C;
    const float* r1p = rowB + (size_t)mc1 * C;
#pragma unroll
    for (int c = 0; c < C; c++) {
      double e0 = (double)qfeat[q0loc][c] - (double)r0p[c];
      dd0 = fma(e0, e0, dd0);
      double e1 = (double)qfeat[q1loc][c] - (double)r1p[c];
      dd1 = fma(e1, e1, dd1);
    }
  }
  int myi0 = (lane < cnt0) ? mc0 : 0x7fffffff;
  int myi1 = (lane < cnt1) ? mc1 : 0x7fffffff;
  if (lane >= cnt0) dd0 = 1e300;
  if (lane >= cnt1) dd1 = 1e300;
  // bitonic sort of 64 (dd, idx) pairs ascending, both queries interleaved
#pragma unroll
  for (int k = 2; k <= 64; k <<= 1) {
#pragma unroll
    for (int j = k >> 1; j > 0; j >>= 1) {
      double od0 = __shfl_xor(dd0, j, 64);
      int oi0 = __shfl_xor(myi0, j, 64);
      double od1 = __shfl_xor(dd1, j, 64);
      int oi1 = __shfl_xor(myi1, j, 64);
      bool up = (lane & k) == 0;
      bool lower = (lane & j) == 0;
      bool dir = (up == lower);
      bool cmp0 = (od0 < dd0) || (od0 == dd0 && oi0 < myi0);
      if (dir ? cmp0 : !cmp0) {
        dd0 = od0;
        myi0 = oi0;
      }
      bool cmp1 = (od1 < dd1) || (od1 == dd1 && oi1 < myi1);
      if (dir ? cmp1 : !cmp1) {
        dd1 = od1;
        myi1 = oi1;
      }
    }
  }
  if (lane < KNN) {
    op0[lane] = myi0;
    op1[lane] = myi1;
  }
}

// C=3: 8 queries per 256-thread block; each wave owns 2 queries; direct global reads.
template <int C>
__global__ void __launch_bounds__(256) knn_fused(const float* __restrict__ fT,
                                                 const float* __restrict__ rowF,
                                                 const float* __restrict__ sqf,
                                                 int* __restrict__ idx20) {
  __shared__ __align__(16) float qfeat[8][C];
  __shared__ int candBuf[8][64];
  int t = threadIdx.x, w = t >> 6, lane = t & 63;
  int q0 = blockIdx.x * 8;
  int b = q0 >> 11;
  for (int i = t; i < 8 * C; i += 256) qfeat[i / C][i % C] = rowF[(size_t)q0 * C + i];
  __syncthreads();
  const float* fTb = fT + (size_t)b * C * N;
  const float* rowB = rowF + (((size_t)b) << 11) * C;
  const float* sqb = sqf + (((size_t)b) << 11);
  int qa = w * 2, qbl = w * 2 + 1;
  float acc0[32], acc1[32];
#pragma unroll
  for (int j = 0; j < 32; j++) {
    acc0[j] = 0.f;
    acc1[j] = 0.f;
  }
  for (int c = 0; c < C; c++) {
    float qc0 = qfeat[qa][c], qc1 = qfeat[qbl][c];
    const float4* r4 = (const float4*)(fTb + (size_t)c * N);
#pragma unroll
    for (int j8 = 0; j8 < 8; j8++) {
      float4 v = r4[j8 * 64 + lane];
      acc0[4 * j8 + 0] = fmaf(v.x, qc0, acc0[4 * j8 + 0]);
      acc0[4 * j8 + 1] = fmaf(v.y, qc0, acc0[4 * j8 + 1]);
      acc0[4 * j8 + 2] = fmaf(v.z, qc0, acc0[4 * j8 + 2]);
      acc0[4 * j8 + 3] = fmaf(v.w, qc0, acc0[4 * j8 + 3]);
      acc1[4 * j8 + 0] = fmaf(v.x, qc1, acc1[4 * j8 + 0]);
      acc1[4 * j8 + 1] = fmaf(v.y, qc1, acc1[4 * j8 + 1]);
      acc1[4 * j8 + 2] = fmaf(v.z, qc1, acc1[4 * j8 + 2]);
      acc1[4 * j8 + 3] = fmaf(v.w, qc1, acc1[4 * j8 + 3]);
    }
  }
  select_refine2<C>(acc0, acc1, lane, qa, qbl, sqb, rowB, qfeat, candBuf,
                    idx20 + (size_t)(q0 + qa) * KNN, idx20 + (size_t)(q0 + qbl) * KNN);
}

// C=64 fp16 dot phase: features packed as channel-pair half2 [B][32][N].
// 16 queries per block, 4 per wave; one channel-pair (8 KB) staged per chunk,
// double-buffered, issue-early/write-late.
__global__ void __launch_bounds__(256) knn_fused64h(const unsigned int* __restrict__ fH,
                                                    const float* __restrict__ rowF,
                                                    const float* __restrict__ sqf,
                                                    int* __restrict__ idx20) {
  __shared__ __align__(16) unsigned int stage[2][N];  // 16 KB
  __shared__ __align__(16) float qfeat[16][64];       // 4 KB (for fp64 refine)
  __shared__ unsigned int qh[16][32];                 // 2 KB packed query pairs
  __shared__ int candBuf[16][64];                     // 4 KB
  int t = threadIdx.x, w = t >> 6, lane = t & 63;
  int q0 = blockIdx.x * 16;
  int b = q0 >> 11;
  const unsigned int* fHb = fH + (size_t)b * 32 * N;
  const uint4* src4 = (const uint4*)fHb;  // pair p = uint4 [p*512 .. p*512+511]
  for (int i = t; i < 16 * 64; i += 256) qfeat[i >> 6][i & 63] = rowF[(size_t)q0 * 64 + i];
  for (int i = t; i < 16 * 32; i += 256) {
    int q = i >> 5, p = i & 31;
    const float* qp = rowF + (size_t)(q0 + q) * 64 + 2 * p;
    qh[q][p] = pack_h2(qp[0], qp[1]);
  }

  uint4 st[2];
  st[0] = src4[t];
  st[1] = src4[t + 256];
  {
    uint4* d4 = (uint4*)&stage[0][0];
    d4[t] = st[0];
    d4[t + 256] = st[1];
  }
  __syncthreads();

  int qa = w * 4;
  float acc0[32], acc1[32], acc2[32], acc3[32];
#pragma unroll
  for (int j = 0; j < 32; j++) {
    acc0[j] = 0.f;
    acc1[j] = 0.f;
    acc2[j] = 0.f;
    acc3[j] = 0.f;
  }

  for (int chunk = 0; chunk < 32; chunk++) {
    int cur = chunk & 1;
    if (chunk < 31) {  // issue next pair's loads early
      st[0] = src4[(chunk + 1) * 512 + t];
      st[1] = src4[(chunk + 1) * 512 + t + 256];
    }
    unsigned int qh0 = qh[qa + 0][chunk], qh1 = qh[qa + 1][chunk];
    unsigned int qh2 = qh[qa + 2][chunk], qh3 = qh[qa + 3][chunk];
    const uint4* r4 = (const uint4*)&stage[cur][0];
#pragma unroll
    for (int j8 = 0; j8 < 8; j8++) {
      uint4 v = r4[j8 * 64 + lane];
      acc0[4 * j8 + 0] = dot2f(v.x, qh0, acc0[4 * j8 + 0]);
      acc0[4 * j8 + 1] = dot2f(v.y, qh0, acc0[4 * j8 + 1]);
      acc0[4 * j8 + 2] = dot2f(v.z, qh0, acc0[4 * j8 + 2]);
      acc0[4 * j8 + 3] = dot2f(v.w, qh0, acc0[4 * j8 + 3]);
      acc1[4 * j8 + 0] = dot2f(v.x, qh1, acc1[4 * j8 + 0]);
      acc1[4 * j8 + 1] = dot2f(v.y, qh1, acc1[4 * j8 + 1]);
      acc1[4 * j8 + 2] = dot2f(v.z, qh1, acc1[4 * j8 + 2]);
      acc1[4 * j8 + 3] = dot2f(v.w, qh1, acc1[4 * j8 + 3]);
      acc2[4 * j8 + 0] = dot2f(v.x, qh2, acc2[4 * j8 + 0]);
      acc2[4 * j8 + 1] = dot2f(v.y, qh2, acc2[4 * j8 + 1]);
      acc2[4 * j8 + 2] = dot2f(v.z, qh2, acc2[4 * j8 + 2]);
      acc2[4 * j8 + 3] = dot2f(v.w, qh2, acc2[4 * j8 + 3]);
      acc3[4 * j8 + 0] = dot2f(v.x, qh3, acc3[4 * j8 + 0]);
      acc3[4 * j8 + 1] = dot2f(v.y, qh3, acc3[4 * j8 + 1]);
      acc3[4 * j8 + 2] = dot2f(v.z, qh3, acc3[4 * j8 + 2]);
      acc3[4 * j8 + 3] = dot2f(v.w, qh3, acc3[4 * j8 + 3]);
    }
    if (chunk < 31) {  // write-late into the other buffer
      uint4* d4 = (uint4*)&stage[cur ^ 1][0];
      d4[t] = st[0];
      d4[t + 256] = st[1];
    }
    __syncthreads();
  }
  const float* rowB = rowF + (((size_t)b) << 11) * 64;
  const float* sqb = sqf + (((size_t)b) << 11);
  select_refine2<64>(acc0, acc1, lane, qa + 0, qa + 1, sqb, rowB, qfeat, candBuf,
                     idx20 + (size_t)(q0 + qa + 0) * KNN, idx20 + (size_t)(q0 + qa + 1) * KNN);
  select_refine2<64>(acc2, acc3, lane, qa + 2, qa + 3, sqb, rowB, qfeat, candBuf,
                     idx20 + (size_t)(q0 + qa + 2) * KNN, idx20 + (size_t)(q0 + qa + 3) * KNN);
}

// EdgeConv factorization: u' = A*(Wt - Wb) + bias, v = A*Wb.
template <int K, int D>
__global__ void __launch_bounds__(256) gemm_uv(const float* __restrict__ A,
                                               const float* __restrict__ W,
                                               const float* __restrict__ bias,
                                               float* __restrict__ u, float* __restrict__ v) {
  constexpr int RG = 256 / D;
  constexpr int RPT = 64 / RG;
  __shared__ float At[64][K];
  int t = threadIdx.x;
  int n0 = blockIdx.x * 64;
  for (int i = t; i < 64 * K; i += 256) At[i / K][i % K] = A[(size_t)n0 * K + i];
  __syncthreads();
  int col = t & (D - 1), rg = t / D;
  float au[RPT], av[RPT];
  float bb = bias[col];
#pragma unroll
  for (int r = 0; r < RPT; r++) {
    au[r] = bb;
    av[r] = 0.f;
  }
  for (int c = 0; c < K; c++) {
    float wt = W[(size_t)c * D + col];
    float wb = W[(size_t)(K + c) * D + col];
    float wu = wt - wb;
#pragma unroll
    for (int r = 0; r < RPT; r++) {
      float a = At[rg * RPT + r][c];
      au[r] = fmaf(a, wu, au[r]);
      av[r] = fmaf(a, wb, av[r]);
    }
  }
#pragma unroll
  for (int r = 0; r < RPT; r++) {
    u[(size_t)(n0 + rg * RPT + r) * D + col] = au[r];
    v[(size_t)(n0 + rg * RPT + r) * D + col] = av[r];
  }
}

// h[n,j,d] = relu(u'[n,d] + v[idx[n,j],d]); max/min over j + fp64 stats.
template <int D>
__global__ void __launch_bounds__(256) combine_max(const float* __restrict__ u,
                                                   const float* __restrict__ v,
                                                   const int* __restrict__ idx20,
                                                   float* __restrict__ hmax,
                                                   float* __restrict__ hmin,
                                                   double* __restrict__ sumP,
                                                   double* __restrict__ sqP) {
  constexpr int PPB = 256 / D;
  int t = threadIdx.x;
  int p = t / D, d = t & (D - 1);
  int bn = blockIdx.x * PPB + p;
  int b = bn >> 11;
  const int* ip = idx20 + (size_t)bn * KNN;
  float up = u[(size_t)bn * D + d];
  const float* vb = v + ((size_t)b << 11) * D;
  float mx = -1e30f, mn = 1e30f;
  double s = 0.0, q = 0.0;
#pragma unroll 4
  for (int j = 0; j < KNN; j++) {
    int nb = ip[j];
    float hv = up + vb[(size_t)nb * D + d];
    hv = hv > 0.f ? hv : 0.f;
    mx = fmaxf(mx, hv);
    mn = fminf(mn, hv);
    double hd = (double)hv;
    s += hd;
    q = fma(hd, hd, q);
  }
  hmax[(size_t)bn * D + d] = mx;
  hmin[(size_t)bn * D + d] = mn;
  int slot = bn & (NPART - 1);
  atomicAdd(&sumP[(size_t)slot * D + d], s);
  atomicAdd(&sqP[(size_t)slot * D + d], q);
}

// Fused bn_finalize + bn_apply.
template <int D>
__global__ void __launch_bounds__(256) bn_apply_fused(const float* __restrict__ hmax,
                                                      const float* __restrict__ hmin,
                                                      const double* __restrict__ sumP,
                                                      const double* __restrict__ sqP,
                                                      const float* __restrict__ g,
                                                      const float* __restrict__ be,
                                                      float* __restrict__ out, int total,
                                                      double invM) {
  constexpr int NG = 256 / D;
  __shared__ double redsS[256], redqS[256];
  __shared__ float scl[D], shf[D];
  int t = threadIdx.x;
  int d = t & (D - 1), grp = t / D;
  double s = 0.0, q = 0.0;
  for (int i = grp; i < NPART; i += NG) {
    s += sumP[(size_t)i * D + d];
    q += sqP[(size_t)i * D + d];
  }
  redsS[t] = s;
  redqS[t] = q;
  __syncthreads();
  if (t < D) {
#pragma unroll
    for (int i = 1; i < NG; i++) {
      s += redsS[i * D + t];
      q += redqS[i * D + t];
    }
    double mean = s * invM;
    double var = q * invM - mean * mean;
    double sc = (double)g[t] / sqrt(var + 1e-5);
    scl[t] = (float)sc;
    shf[t] = (float)((double)be[t] - mean * sc);
  }
  __syncthreads();
  float sc = scl[d], sh = shf[d];
  for (int i = blockIdx.x * 256 + t; i < total; i += 256 * 256) {
    float v = sc >= 0.f ? hmax[i] : hmin[i];
    out[i] = v * sc + sh;
  }
}

// [16384,320]x[320,1024]: block = 16 rows x 1024 cols; per-block partials.
__global__ void __launch_bounds__(256) final_gemm(const float* __restrict__ x1,
                                                  const float* __restrict__ x2,
                                                  const float* __restrict__ x3,
                                                  const float* __restrict__ x4,
                                                  const float* __restrict__ W5,
                                                  const float* __restrict__ b5,
                                                  float* __restrict__ partMax,
                                                  float* __restrict__ partMin,
                                                  float* __restrict__ partSum,
                                                  float* __restrict__ partSq) {
  __shared__ __align__(16) float At[16][320];  // 20 KB
  int t = threadIdx.x;
  int blk = blockIdx.x;
  int n0 = blk * 16;
  int col = t * 4;
  for (int i = t; i < 16 * 320; i += 256) {
    int r = i / 320, c = i % 320;
    int n = n0 + r;
    float vv;
    if (c < 64) vv = x1[(size_t)n * 64 + c];
    else if (c < 128) vv = x2[(size_t)n * 64 + c - 64];
    else if (c < 192) vv = x3[(size_t)n * 64 + c - 128];
    else vv = x4[(size_t)n * 128 + c - 192];
    At[r][c] = vv;
  }
  __syncthreads();
  float4 acc[16];
  float4 bb = *(const float4*)(b5 + col);
#pragma unroll
  for (int r = 0; r < 16; r++) acc[r] = bb;
  for (int c4 = 0; c4 < 80; c4++) {
    const float* wbase = W5 + (size_t)c4 * 4 * 1024 + col;
    float4 w0 = *(const float4*)(wbase);
    float4 w1 = *(const float4*)(wbase + 1024);
    float4 w2 = *(const float4*)(wbase + 2048);
    float4 w3 = *(const float4*)(wbase + 3072);
#pragma unroll
    for (int r = 0; r < 16; r++) {
      float4 a = *(const float4*)(&At[r][c4 * 4]);
      acc[r].x = fmaf(a.x, w0.x, acc[r].x);
      acc[r].y = fmaf(a.x, w0.y, acc[r].y);
      acc[r].z = fmaf(a.x, w0.z, acc[r].z);
      acc[r].w = fmaf(a.x, w0.w, acc[r].w);
      acc[r].x = fmaf(a.y, w1.x, acc[r].x);
      acc[r].y = fmaf(a.y, w1.y, acc[r].y);
      acc[r].z = fmaf(a.y, w1.z, acc[r].z);
      acc[r].w = fmaf(a.y, w1.w, acc[r].w);
      acc[r].x = fmaf(a.z, w2.x, acc[r].x);
      acc[r].y = fmaf(a.z, w2.y, acc[r].y);
      acc[r].z = fmaf(a.z, w2.z, acc[r].z);
      acc[r].w = fmaf(a.z, w2.w, acc[r].w);
      acc[r].x = fmaf(a.w, w3.x, acc[r].x);
      acc[r].y = fmaf(a.w, w3.y, acc[r].y);
      acc[r].z = fmaf(a.w, w3.z, acc[r].z);
      acc[r].w = fmaf(a.w, w3.w, acc[r].w);
    }
  }
  float mx[4] = {-1e30f, -1e30f, -1e30f, -1e30f};
  float mn[4] = {1e30f, 1e30f, 1e30f, 1e30f};
  double sv[4] = {0, 0, 0, 0}, qv[4] = {0, 0, 0, 0};
#pragma unroll
  for (int r = 0; r < 16; r++) {
    float h0 = acc[r].x > 0.f ? acc[r].x : 0.f;
    float h1 = acc[r].y > 0.f ? acc[r].y : 0.f;
    float h2 = acc[r].z > 0.f ? acc[r].z : 0.f;
    float h3 = acc[r].w > 0.f ? acc[r].w : 0.f;
    mx[0] = fmaxf(mx[0], h0);
    mn[0] = fminf(mn[0], h0);
    sv[0] += h0;
    qv[0] = fma((double)h0, (double)h0, qv[0]);
    mx[1] = fmaxf(mx[1], h1);
    mn[1] = fminf(mn[1], h1);
    sv[1] += h1;
    qv[1] = fma((double)h1, (double)h1, qv[1]);
    mx[2] = fmaxf(mx[2], h2);
    mn[2] = fminf(mn[2], h2);
    sv[2] += h2;
    qv[2] = fma((double)h2, (double)h2, qv[2]);
    mx[3] = fmaxf(mx[3], h3);
    mn[3] = fminf(mn[3], h3);
    sv[3] += h3;
    qv[3] = fma((double)h3, (double)h3, qv[3]);
  }
  size_t base = (size_t)blk * 1024;
  *(float4*)(partMax + base + col) = make_float4(mx[0], mx[1], mx[2], mx[3]);
  *(float4*)(partMin + base + col) = make_float4(mn[0], mn[1], mn[2], mn[3]);
  *(float4*)(partSum + base + col) =
      make_float4((float)sv[0], (float)sv[1], (float)sv[2], (float)sv[3]);
  *(float4*)(partSq + base + col) =
      make_float4((float)qv[0], (float)qv[1], (float)qv[2], (float)qv[3]);
}

// Reduce 128 per-block partials per (batch, channel).
__global__ void __launch_bounds__(256) final_reduce(const float* __restrict__ partMax,
                                                    const float* __restrict__ partMin,
                                                    const float* __restrict__ partSum,
                                                    const float* __restrict__ partSq,
                                                    float* __restrict__ h5max,
                                                    float* __restrict__ h5min,
                                                    double* __restrict__ bsum,
                                                    double* __restrict__ bsq) {
  int bid = blockIdx.x;
  int b = bid >> 2;
  int ch = ((bid & 3) << 8) + threadIdx.x;
  float mx = -1e30f, mn = 1e30f;
  double s = 0.0, q = 0.0;
  for (int j = 0; j < 128; j++) {
    size_t base = ((size_t)(b * 128 + j) << 10) + ch;
    mx = fmaxf(mx, partMax[base]);
    mn = fminf(mn, partMin[base]);
    s += (double)partSum[base];
    q += (double)partSq[base];
  }
  h5max[(size_t)b * 1024 + ch] = mx;
  h5min[(size_t)b * 1024 + ch] = mn;
  bsum[(size_t)b * 1024 + ch] = s;
  bsq[(size_t)b * 1024 + ch] = q;
}

// Fused final bn_finalize + apply.
__global__ void __launch_bounds__(256) final_apply_fused(const float* __restrict__ h5max,
                                                         const float* __restrict__ h5min,
                                                         const double* __restrict__ bsum,
                                                         const double* __restrict__ bsq,
                                                         const float* __restrict__ g,
                                                         const float* __restrict__ be,
                                                         float* __restrict__ out,
                                                         double invM) {
  int i = blockIdx.x * 256 + threadIdx.x;
  if (i >= B * 1024) return;
  int ch = i & 1023;
  double s = 0.0, q = 0.0;
#pragma unroll
  for (int j = 0; j < 8; j++) {
    s += bsum[(size_t)j * 1024 + ch];
    q += bsq[(size_t)j * 1024 + ch];
  }
  double mean = s * invM;
  double var = q * invM - mean * mean;
  double sc = (double)g[ch] / sqrt(var + 1e-5);
  float scf = (float)sc;
  float shf = (float)((double)be[ch] - mean * sc);
  float v = scf >= 0.f ? h5max[i] : h5min[i];
  out[i] = v * scf + shf;
}

}  // namespace

extern "C" void kernel_launch(void* const* d_in, const int* in_sizes, int n_in,
                              void* d_out, int out_size, void* d_ws, size_t ws_size,
                              hipStream_t stream) {
  const float* x = (const float*)d_in[0];
  const float *Wv[5], *bv[5], *gv[5], *bev[5];
  for (int i = 0; i < 5; i++) {
    Wv[i] = (const float*)d_in[1 + 4 * i];
    bv[i] = (const float*)d_in[2 + 4 * i];
    gv[i] = (const float*)d_in[3 + 4 * i];
    bev[i] = (const float*)d_in[4 + 4 * i];
  }

  char* ws = (char*)d_ws;
  size_t off = 0;
  auto alloc = [&](size_t bytes) {
    size_t r = off;
    off = (off + bytes + 255) & ~(size_t)255;
    return r;
  };
  const int BN = B * N;
  float* feat0 = (float*)(ws + alloc((size_t)BN * 3 * 4));
  int* idx = (int*)(ws + alloc((size_t)BN * KNN * 4));
  float* x1 = (float*)(ws + alloc((size_t)BN * 64 * 4));
  float* x2 = (float*)(ws + alloc((size_t)BN * 64 * 4));
  float* x3 = (float*)(ws + alloc((size_t)BN * 64 * 4));
  float* x4 = (float*)(ws + alloc((size_t)BN * 128 * 4));
  unsigned int* fH = (unsigned int*)(ws + alloc((size_t)BN * 32 * 4));  // fp16 pairs
  float* ub = (float*)(ws + alloc((size_t)BN * 128 * 4));
  float* vb = (float*)(ws + alloc((size_t)BN * 128 * 4));
  float* hmax = (float*)(ws + alloc((size_t)BN * 128 * 4));  // reused as partMax/partMin
  float* hmin = (float*)(ws + alloc((size_t)BN * 128 * 4));  // reused as partSum/partSq
  float* sqf = (float*)(ws + alloc((size_t)BN * 4));
  double* lstats = (double*)(ws + alloc((size_t)4 * 2 * NPART * 128 * 8));
  double* bsum = (double*)(ws + alloc((size_t)B * 1024 * 8));
  double* bsq = (double*)(ws + alloc((size_t)B * 1024 * 8));
  float* h5max = (float*)(ws + alloc((size_t)B * 1024 * 4));
  float* h5min = (float*)(ws + alloc((size_t)B * 1024 * 4));

  double* sumL[4], *sqL[4];
  for (int l = 0; l < 4; l++) {
    sumL[l] = lstats + (size_t)l * 2 * NPART * 128;
    sqL[l] = sumL[l] + (size_t)NPART * 128;
  }

  float* partMax = hmax;
  float* partMin = hmax + 1024 * 1024;
  float* partSum = hmin;
  float* partSq = hmin + 1024 * 1024;

  const double invMk = 1.0 / ((double)BN * KNN);
  dim3 tgrid64(N / 32, B);

  hipMemsetAsync(lstats, 0, (size_t)4 * 2 * NPART * 128 * 8, stream);

  // ---- layer 1: C=3 -> D=64 (x is already [B][3][N]) ----
  transpose_x_norm<<<(BN + 255) / 256, 256, 0, stream>>>(x, feat0, sqf);
  knn_fused<3><<<BN / 8, 256, 0, stream>>>(x, feat0, sqf, idx);
  gemm_uv<3, 64><<<BN / 64, 256, 0, stream>>>(feat0, Wv[0], bv[0], ub, vb);
  combine_max<64><<<BN / 4, 256, 0, stream>>>(ub, vb, idx, hmax, hmin, sumL[0], sqL[0]);
  bn_apply_fused<64><<<256, 256, 0, stream>>>(hmax, hmin, sumL[0], sqL[0], gv[0], bev[0], x1,
                                              BN * 64, invMk);

  // ---- layer 2: C=64 -> D=64 ----
  transpose64h_norm<<<tgrid64, 256, 0, stream>>>(x1, fH, sqf);
  knn_fused64h<<<BN / 16, 256, 0, stream>>>(fH, x1, sqf, idx);
  gemm_uv<64, 64><<<BN / 64, 256, 0, stream>>>(x1, Wv[1], bv[1], ub, vb);
  combine_max<64><<<BN / 4, 256, 0, stream>>>(ub, vb, idx, hmax, hmin, sumL[1], sqL[1]);
  bn_apply_fused<64><<<256, 256, 0, stream>>>(hmax, hmin, sumL[1], sqL[1], gv[1], bev[1], x2,
                                              BN * 64, invMk);

  // ---- layer 3: C=64 -> D=64 ----
  transpose64h_norm<<<tgrid64, 256, 0, stream>>>(x2, fH, sqf);
  knn_fused64h<<<BN / 16, 256, 0, stream>>>(fH, x2, sqf, idx);
  gemm_uv<64, 64><<<BN / 64, 256, 0, stream>>>(x2, Wv[2], bv[2], ub, vb);
  combine_max<64><<<BN / 4, 256, 0, stream>>>(ub, vb, idx, hmax, hmin, sumL[2], sqL[2]);
  bn_apply_fused<64><<<256, 256, 0, stream>>>(hmax, hmin, sumL[2], sqL[2], gv[2], bev[2], x3,
                                              BN * 64, invMk);

  // ---- layer 4: C=64 -> D=128 ----
  transpose64h_norm<<<tgrid64, 256, 0, stream>>>(x3, fH, sqf);
  knn_fused64h<<<BN / 16, 256, 0, stream>>>(fH, x3, sqf, idx);
  gemm_uv<64, 128><<<BN / 64, 256, 0, stream>>>(x3, Wv[3], bv[3], ub, vb);
  combine_max<128><<<BN / 2, 256, 0, stream>>>(ub, vb, idx, hmax, hmin, sumL[3], sqL[3]);
  bn_apply_fused<128><<<256, 256, 0, stream>>>(hmax, hmin, sumL[3], sqL[3], gv[3], bev[3], x4,
                                               BN * 128, invMk);

  // ---- final: [BN,320] @ [320,1024], max over n; atomic-free partials ----
  final_gemm<<<BN / 16, 256, 0, stream>>>(x1, x2, x3, x4, Wv[4], bv[4], partMax, partMin,
                                          partSum, partSq);
  final_reduce<<<32, 256, 0, stream>>>(partMax, partMin, partSum, partSq, h5max, h5min, bsum,
                                       bsq);
  final_apply_fused<<<(B * 1024 + 255) / 256, 256, 0, stream>>>(h5max, h5min, bsum, bsq,
                                                                gv[4], bev[4], (float*)d_out,
                                                                1.0 / (double)BN);
}

// Round 16
// 681.118 us; speedup vs baseline: 3.8422x; 1.0390x over previous
//
#include <hip/hip_runtime.h>
#include <hip/hip_fp16.h>
#include <stdint.h>

namespace {

constexpr int B = 8, N = 2048, KNN = 20;
constexpr int NPART = 64;

typedef _Float16 h2_t __attribute__((ext_vector_type(2)));

__device__ __forceinline__ unsigned int pack_h2(float a, float b) {
  __half2 h = __floats2half2_rn(a, b);
  return *(unsigned int*)&h;
}

__device__ __forceinline__ float dot2f(unsigned int a, unsigned int b, float c) {
#if __has_builtin(__builtin_amdgcn_fdot2)
  h2_t ha, hb;
  *(unsigned int*)&ha = a;
  *(unsigned int*)&hb = b;
  return __builtin_amdgcn_fdot2(ha, hb, c, false);
#else
  __half2 ha = *(__half2*)&a, hb = *(__half2*)&b;
  c = fmaf(__low2float(ha), __low2float(hb), c);
  c = fmaf(__high2float(ha), __high2float(hb), c);
  return c;
#endif
}

// Fused: x [B][3][N] -> feat0 [BN][3] + fp32 sq-norms
__global__ void __launch_bounds__(256) transpose_x_norm(const float* __restrict__ x,
                                                        float* __restrict__ f,
                                                        float* __restrict__ sqf) {
  int i = blockIdx.x * 256 + threadIdx.x;
  if (i >= B * N) return;
  int b = i >> 11, n = i & (N - 1);
  const float* xb = x + (size_t)b * 3 * N;
  float v0 = xb[n], v1 = xb[N + n], v2 = xb[2 * N + n];
  float* fp = f + (size_t)i * 3;
  fp[0] = v0;
  fp[1] = v1;
  fp[2] = v2;
  sqf[i] = fmaf(v0, v0, fmaf(v1, v1, v2 * v2));
}

// Fused: [B][N][64] -> fp16-packed channel-pair layout [B][32][N] (half2 as uint)
// + per-point fp32 sq-norms. Block = 32 points x 64 ch; grid (N/32, B).
__global__ void __launch_bounds__(256) transpose64h_norm(const float* __restrict__ in,
                                                         unsigned int* __restrict__ outH,
                                                         float* __restrict__ sqf) {
  __shared__ float tl[32][65];
  int t = threadIdx.x;
  int n0 = blockIdx.x * 32;
  int b = blockIdx.y;
  const float* ib = in + (size_t)b * N * 64;
  unsigned int* ob = outH + (size_t)b * 32 * N;
  int pt = t >> 3, ch0 = (t & 7) * 8;
  const float4* src = (const float4*)(ib + (size_t)(n0 + pt) * 64 + ch0);
  float4 a0 = src[0], a1 = src[1];
  tl[pt][ch0 + 0] = a0.x;
  tl[pt][ch0 + 1] = a0.y;
  tl[pt][ch0 + 2] = a0.z;
  tl[pt][ch0 + 3] = a0.w;
  tl[pt][ch0 + 4] = a1.x;
  tl[pt][ch0 + 5] = a1.y;
  tl[pt][ch0 + 6] = a1.z;
  tl[pt][ch0 + 7] = a1.w;
  __syncthreads();
  if (t < 32) {
    float s = 0.f;
#pragma unroll 8
    for (int c = 0; c < 64; c++) {
      float v = tl[t][c];
      s = fmaf(v, v, s);
    }
    sqf[(size_t)b * N + n0 + t] = s;
  }
  int p = t >> 3, j0 = (t & 7) * 4;  // pair p, 4 points
  uint4 w;
  w.x = pack_h2(tl[j0 + 0][2 * p], tl[j0 + 0][2 * p + 1]);
  w.y = pack_h2(tl[j0 + 1][2 * p], tl[j0 + 1][2 * p + 1]);
  w.z = pack_h2(tl[j0 + 2][2 * p], tl[j0 + 2][2 * p + 1]);
  w.w = pack_h2(tl[j0 + 3][2 * p], tl[j0 + 3][2 * p + 1]);
  *(uint4*)(ob + (size_t)p * N + n0 + j0) = w;
}

// Pack W5 [320][1024] -> W5h [160][1024] (half2 over K pairs).
__global__ void __launch_bounds__(256) pack_w5(const float* __restrict__ W5,
                                               unsigned int* __restrict__ W5h) {
  int i = blockIdx.x * 256 + threadIdx.x;
  if (i >= 160 * 1024) return;
  int k2 = i >> 10, c = i & 1023;
  W5h[i] = pack_h2(W5[(size_t)(2 * k2) * 1024 + c], W5[(size_t)(2 * k2 + 1) * 1024 + c]);
}

// Cross-lane bitonic sort of one fp32 value per lane (ascending by lane),
// two independent streams interleaved.
__device__ __forceinline__ void lane_sort64x2(float& v0, float& v1, int lane) {
#pragma unroll
  for (int k = 2; k <= 64; k <<= 1) {
#pragma unroll
    for (int j = k >> 1; j > 0; j >>= 1) {
      float o0 = __shfl_xor(v0, j, 64);
      float o1 = __shfl_xor(v1, j, 64);
      bool keepmin = (((lane & k) == 0) == ((lane & j) == 0));
      float mn0 = fminf(v0, o0), mx0 = fmaxf(v0, o0);
      v0 = keepmin ? mn0 : mx0;
      float mn1 = fminf(v1, o1), mx1 = fmaxf(v1, o1);
      v1 = keepmin ? mn1 : mx1;
    }
  }
}

// Ballot-compaction of candidates (A[k] <= T) into buf (cap 64); returns count.
__device__ __forceinline__ int compact_cand(const float (&A)[32], float T, int lane,
                                            int* __restrict__ buf) {
  int base = 0;
#pragma unroll
  for (int k = 0; k < 32; k++) {
    bool p = (A[k] <= T);
    unsigned long long mk = __ballot(p);
    if (p) {
      int pos = base + (int)__popcll(mk & ((1ull << lane) - 1));
      if (pos < 64) buf[pos] = (k >> 2) * 256 + lane * 4 + (k & 3);
    }
    base += (int)__popcll(mk);
  }
  return base;
}

// fp32 candidate selection + fp64 exact refine for TWO queries, interleaved.
// Cheap threshold: T = 24th smallest of 64 per-lane minima.
template <int C>
__device__ __forceinline__ void select_refine2(float (&A0)[32], float (&A1)[32], int lane,
                                               int q0loc, int q1loc,
                                               const float* __restrict__ sqb,
                                               const float* __restrict__ rowB,
                                               const float (*qfeat)[C], int (*candBuf)[64],
                                               int* __restrict__ op0, int* __restrict__ op1) {
  const float4* sq4 = (const float4*)sqb;
#pragma unroll
  for (int j8 = 0; j8 < 8; j8++) {
    float4 sv = sq4[j8 * 64 + lane];
    A0[4 * j8 + 0] = fmaf(-2.f, A0[4 * j8 + 0], sv.x);
    A0[4 * j8 + 1] = fmaf(-2.f, A0[4 * j8 + 1], sv.y);
    A0[4 * j8 + 2] = fmaf(-2.f, A0[4 * j8 + 2], sv.z);
    A0[4 * j8 + 3] = fmaf(-2.f, A0[4 * j8 + 3], sv.w);
    A1[4 * j8 + 0] = fmaf(-2.f, A1[4 * j8 + 0], sv.x);
    A1[4 * j8 + 1] = fmaf(-2.f, A1[4 * j8 + 1], sv.y);
    A1[4 * j8 + 2] = fmaf(-2.f, A1[4 * j8 + 2], sv.z);
    A1[4 * j8 + 3] = fmaf(-2.f, A1[4 * j8 + 3], sv.w);
  }
  float p0 = fminf(A0[0], A0[1]), p1 = fminf(A0[2], A0[3]);
  float r0 = fminf(A1[0], A1[1]), r1 = fminf(A1[2], A1[3]);
#pragma unroll
  for (int k = 4; k < 32; k += 4) {
    p0 = fminf(p0, fminf(A0[k], A0[k + 1]));
    p1 = fminf(p1, fminf(A0[k + 2], A0[k + 3]));
    r0 = fminf(r0, fminf(A1[k], A1[k + 1]));
    r1 = fminf(r1, fminf(A1[k + 2], A1[k + 3]));
  }
  float m0 = fminf(p0, p1), m1 = fminf(r0, r1);
  lane_sort64x2(m0, m1, lane);
  float T0 = __shfl(m0, 23, 64);
  float T1 = __shfl(m1, 23, 64);
  int cnt0 = compact_cand(A0, T0, lane, candBuf[q0loc]);
  int cnt1 = compact_cand(A1, T1, lane, candBuf[q1loc]);
  cnt0 = cnt0 < 64 ? cnt0 : 64;
  cnt1 = cnt1 < 64 ? cnt1 : 64;
  int mc0 = (lane < cnt0) ? candBuf[q0loc][lane] : 0;
  int mc1 = (lane < cnt1) ? candBuf[q1loc][lane] : 0;
  double dd0 = 0.0, dd1 = 0.0;
  if constexpr (C % 4 == 0) {
    const float4* r40 = (const float4*)(rowB + (size_t)mc0 * C);
    const float4* r41 = (const float4*)(rowB + (size_t)mc1 * C);
    const float4* q40 = (const float4*)(&qfeat[q0loc][0]);
    const float4* q41 = (const float4*)(&qfeat[q1loc][0]);
#pragma unroll 4
    for (int k = 0; k < C / 4; k++) {
      float4 rv0 = r40[k], qv0 = q40[k];
      float4 rv1 = r41[k], qv1 = q41[k];
      double e0 = (double)qv0.x - (double)rv0.x;
      dd0 = fma(e0, e0, dd0);
      double e1 = (double)qv0.y - (double)rv0.y;
      dd0 = fma(e1, e1, dd0);
      double e2 = (double)qv0.z - (double)rv0.z;
      dd0 = fma(e2, e2, dd0);
      double e3 = (double)qv0.w - (double)rv0.w;
      dd0 = fma(e3, e3, dd0);
      double f0 = (double)qv1.x - (double)rv1.x;
      dd1 = fma(f0, f0, dd1);
      double f1 = (double)qv1.y - (double)rv1.y;
      dd1 = fma(f1, f1, dd1);
      double f2 = (double)qv1.z - (double)rv1.z;
      dd1 = fma(f2, f2, dd1);
      double f3 = (double)qv1.w - (double)rv1.w;
      dd1 = fma(f3, f3, dd1);
    }
  } else {
    const float* r0p = rowB + (size_t)mc0 * C;
    const float* r1p = rowB + (size_t)mc1 * C;
#pragma unroll
    for (int c = 0; c < C; c++) {
      double e0 = (double)qfeat[q0loc][c] - (double)r0p[c];
      dd0 = fma(e0, e0, dd0);
      double e1 = (double)qfeat[q1loc][c] - (double)r1p[c];
      dd1 = fma(e1, e1, dd1);
    }
  }
  int myi0 = (lane < cnt0) ? mc0 : 0x7fffffff;
  int myi1 = (lane < cnt1) ? mc1 : 0x7fffffff;
  if (lane >= cnt0) dd0 = 1e300;
  if (lane >= cnt1) dd1 = 1e300;
#pragma unroll
  for (int k = 2; k <= 64; k <<= 1) {
#pragma unroll
    for (int j = k >> 1; j > 0; j >>= 1) {
      double od0 = __shfl_xor(dd0, j, 64);
      int oi0 = __shfl_xor(myi0, j, 64);
      double od1 = __shfl_xor(dd1, j, 64);
      int oi1 = __shfl_xor(myi1, j, 64);
      bool up = (lane & k) == 0;
      bool lower = (lane & j) == 0;
      bool dir = (up == lower);
      bool cmp0 = (od0 < dd0) || (od0 == dd0 && oi0 < myi0);
      if (dir ? cmp0 : !cmp0) {
        dd0 = od0;
        myi0 = oi0;
      }
      bool cmp1 = (od1 < dd1) || (od1 == dd1 && oi1 < myi1);
      if (dir ? cmp1 : !cmp1) {
        dd1 = od1;
        myi1 = oi1;
      }
    }
  }
  if (lane < KNN) {
    op0[lane] = myi0;
    op1[lane] = myi1;
  }
}

// C=3: 8 queries per 256-thread block; each wave owns 2 queries; direct global reads.
template <int C>
__global__ void __launch_bounds__(256) knn_fused(const float* __restrict__ fT,
                                                 const float* __restrict__ rowF,
                                                 const float* __restrict__ sqf,
                                                 int* __restrict__ idx20) {
  __shared__ __align__(16) float qfeat[8][C];
  __shared__ int candBuf[8][64];
  int t = threadIdx.x, w = t >> 6, lane = t & 63;
  int q0 = blockIdx.x * 8;
  int b = q0 >> 11;
  for (int i = t; i < 8 * C; i += 256) qfeat[i / C][i % C] = rowF[(size_t)q0 * C + i];
  __syncthreads();
  const float* fTb = fT + (size_t)b * C * N;
  const float* rowB = rowF + (((size_t)b) << 11) * C;
  const float* sqb = sqf + (((size_t)b) << 11);
  int qa = w * 2, qbl = w * 2 + 1;
  float acc0[32], acc1[32];
#pragma unroll
  for (int j = 0; j < 32; j++) {
    acc0[j] = 0.f;
    acc1[j] = 0.f;
  }
  for (int c = 0; c < C; c++) {
    float qc0 = qfeat[qa][c], qc1 = qfeat[qbl][c];
    const float4* r4 = (const float4*)(fTb + (size_t)c * N);
#pragma unroll
    for (int j8 = 0; j8 < 8; j8++) {
      float4 v = r4[j8 * 64 + lane];
      acc0[4 * j8 + 0] = fmaf(v.x, qc0, acc0[4 * j8 + 0]);
      acc0[4 * j8 + 1] = fmaf(v.y, qc0, acc0[4 * j8 + 1]);
      acc0[4 * j8 + 2] = fmaf(v.z, qc0, acc0[4 * j8 + 2]);
      acc0[4 * j8 + 3] = fmaf(v.w, qc0, acc0[4 * j8 + 3]);
      acc1[4 * j8 + 0] = fmaf(v.x, qc1, acc1[4 * j8 + 0]);
      acc1[4 * j8 + 1] = fmaf(v.y, qc1, acc1[4 * j8 + 1]);
      acc1[4 * j8 + 2] = fmaf(v.z, qc1, acc1[4 * j8 + 2]);
      acc1[4 * j8 + 3] = fmaf(v.w, qc1, acc1[4 * j8 + 3]);
    }
  }
  select_refine2<C>(acc0, acc1, lane, qa, qbl, sqb, rowB, qfeat, candBuf,
                    idx20 + (size_t)(q0 + qa) * KNN, idx20 + (size_t)(q0 + qbl) * KNN);
}

// C=64 fp16 dot phase: features packed as channel-pair half2 [B][32][N].
__global__ void __launch_bounds__(256) knn_fused64h(const unsigned int* __restrict__ fH,
                                                    const float* __restrict__ rowF,
                                                    const float* __restrict__ sqf,
                                                    int* __restrict__ idx20) {
  __shared__ __align__(16) unsigned int stage[2][N];  // 16 KB
  __shared__ __align__(16) float qfeat[16][64];       // 4 KB (for fp64 refine)
  __shared__ unsigned int qh[16][32];                 // 2 KB packed query pairs
  __shared__ int candBuf[16][64];                     // 4 KB
  int t = threadIdx.x, w = t >> 6, lane = t & 63;
  int q0 = blockIdx.x * 16;
  int b = q0 >> 11;
  const unsigned int* fHb = fH + (size_t)b * 32 * N;
  const uint4* src4 = (const uint4*)fHb;
  for (int i = t; i < 16 * 64; i += 256) qfeat[i >> 6][i & 63] = rowF[(size_t)q0 * 64 + i];
  for (int i = t; i < 16 * 32; i += 256) {
    int q = i >> 5, p = i & 31;
    const float* qp = rowF + (size_t)(q0 + q) * 64 + 2 * p;
    qh[q][p] = pack_h2(qp[0], qp[1]);
  }

  uint4 st[2];
  st[0] = src4[t];
  st[1] = src4[t + 256];
  {
    uint4* d4 = (uint4*)&stage[0][0];
    d4[t] = st[0];
    d4[t + 256] = st[1];
  }
  __syncthreads();

  int qa = w * 4;
  float acc0[32], acc1[32], acc2[32], acc3[32];
#pragma unroll
  for (int j = 0; j < 32; j++) {
    acc0[j] = 0.f;
    acc1[j] = 0.f;
    acc2[j] = 0.f;
    acc3[j] = 0.f;
  }

  for (int chunk = 0; chunk < 32; chunk++) {
    int cur = chunk & 1;
    if (chunk < 31) {
      st[0] = src4[(chunk + 1) * 512 + t];
      st[1] = src4[(chunk + 1) * 512 + t + 256];
    }
    unsigned int qh0 = qh[qa + 0][chunk], qh1 = qh[qa + 1][chunk];
    unsigned int qh2 = qh[qa + 2][chunk], qh3 = qh[qa + 3][chunk];
    const uint4* r4 = (const uint4*)&stage[cur][0];
#pragma unroll
    for (int j8 = 0; j8 < 8; j8++) {
      uint4 v = r4[j8 * 64 + lane];
      acc0[4 * j8 + 0] = dot2f(v.x, qh0, acc0[4 * j8 + 0]);
      acc0[4 * j8 + 1] = dot2f(v.y, qh0, acc0[4 * j8 + 1]);
      acc0[4 * j8 + 2] = dot2f(v.z, qh0, acc0[4 * j8 + 2]);
      acc0[4 * j8 + 3] = dot2f(v.w, qh0, acc0[4 * j8 + 3]);
      acc1[4 * j8 + 0] = dot2f(v.x, qh1, acc1[4 * j8 + 0]);
      acc1[4 * j8 + 1] = dot2f(v.y, qh1, acc1[4 * j8 + 1]);
      acc1[4 * j8 + 2] = dot2f(v.z, qh1, acc1[4 * j8 + 2]);
      acc1[4 * j8 + 3] = dot2f(v.w, qh1, acc1[4 * j8 + 3]);
      acc2[4 * j8 + 0] = dot2f(v.x, qh2, acc2[4 * j8 + 0]);
      acc2[4 * j8 + 1] = dot2f(v.y, qh2, acc2[4 * j8 + 1]);
      acc2[4 * j8 + 2] = dot2f(v.z, qh2, acc2[4 * j8 + 2]);
      acc2[4 * j8 + 3] = dot2f(v.w, qh2, acc2[4 * j8 + 3]);
      acc3[4 * j8 + 0] = dot2f(v.x, qh3, acc3[4 * j8 + 0]);
      acc3[4 * j8 + 1] = dot2f(v.y, qh3, acc3[4 * j8 + 1]);
      acc3[4 * j8 + 2] = dot2f(v.z, qh3, acc3[4 * j8 + 2]);
      acc3[4 * j8 + 3] = dot2f(v.w, qh3, acc3[4 * j8 + 3]);
    }
    if (chunk < 31) {
      uint4* d4 = (uint4*)&stage[cur ^ 1][0];
      d4[t] = st[0];
      d4[t + 256] = st[1];
    }
    __syncthreads();
  }
  const float* rowB = rowF + (((size_t)b) << 11) * 64;
  const float* sqb = sqf + (((size_t)b) << 11);
  select_refine2<64>(acc0, acc1, lane, qa + 0, qa + 1, sqb, rowB, qfeat, candBuf,
                     idx20 + (size_t)(q0 + qa + 0) * KNN, idx20 + (size_t)(q0 + qa + 1) * KNN);
  select_refine2<64>(acc2, acc3, lane, qa + 2, qa + 3, sqb, rowB, qfeat, candBuf,
                     idx20 + (size_t)(q0 + qa + 2) * KNN, idx20 + (size_t)(q0 + qa + 3) * KNN);
}

// EdgeConv factorization: u' = A*(Wt - Wb) + bias, v = A*Wb.
template <int K, int D>
__global__ void __launch_bounds__(256) gemm_uv(const float* __restrict__ A,
                                               const float* __restrict__ W,
                                               const float* __restrict__ bias,
                                               float* __restrict__ u, float* __restrict__ v) {
  constexpr int RG = 256 / D;
  constexpr int RPT = 64 / RG;
  __shared__ float At[64][K];
  int t = threadIdx.x;
  int n0 = blockIdx.x * 64;
  for (int i = t; i < 64 * K; i += 256) At[i / K][i % K] = A[(size_t)n0 * K + i];
  __syncthreads();
  int col = t & (D - 1), rg = t / D;
  float au[RPT], av[RPT];
  float bb = bias[col];
#pragma unroll
  for (int r = 0; r < RPT; r++) {
    au[r] = bb;
    av[r] = 0.f;
  }
  for (int c = 0; c < K; c++) {
    float wt = W[(size_t)c * D + col];
    float wb = W[(size_t)(K + c) * D + col];
    float wu = wt - wb;
#pragma unroll
    for (int r = 0; r < RPT; r++) {
      float a = At[rg * RPT + r][c];
      au[r] = fmaf(a, wu, au[r]);
      av[r] = fmaf(a, wb, av[r]);
    }
  }
#pragma unroll
  for (int r = 0; r < RPT; r++) {
    u[(size_t)(n0 + rg * RPT + r) * D + col] = au[r];
    v[(size_t)(n0 + rg * RPT + r) * D + col] = av[r];
  }
}

// h[n,j,d] = relu(u'[n,d] + v[idx[n,j],d]); max/min over j + fp64 stats.
template <int D>
__global__ void __launch_bounds__(256) combine_max(const float* __restrict__ u,
                                                   const float* __restrict__ v,
                                                   const int* __restrict__ idx20,
                                                   float* __restrict__ hmax,
                                                   float* __restrict__ hmin,
                                                   double* __restrict__ sumP,
                                                   double* __restrict__ sqP) {
  constexpr int PPB = 256 / D;
  int t = threadIdx.x;
  int p = t / D, d = t & (D - 1);
  int bn = blockIdx.x * PPB + p;
  int b = bn >> 11;
  const int* ip = idx20 + (size_t)bn * KNN;
  float up = u[(size_t)bn * D + d];
  const float* vb = v + ((size_t)b << 11) * D;
  float mx = -1e30f, mn = 1e30f;
  double s = 0.0, q = 0.0;
#pragma unroll 4
  for (int j = 0; j < KNN; j++) {
    int nb = ip[j];
    float hv = up + vb[(size_t)nb * D + d];
    hv = hv > 0.f ? hv : 0.f;
    mx = fmaxf(mx, hv);
    mn = fminf(mn, hv);
    double hd = (double)hv;
    s += hd;
    q = fma(hd, hd, q);
  }
  hmax[(size_t)bn * D + d] = mx;
  hmin[(size_t)bn * D + d] = mn;
  int slot = bn & (NPART - 1);
  atomicAdd(&sumP[(size_t)slot * D + d], s);
  atomicAdd(&sqP[(size_t)slot * D + d], q);
}

// Fused bn_finalize + bn_apply.
template <int D>
__global__ void __launch_bounds__(256) bn_apply_fused(const float* __restrict__ hmax,
                                                      const float* __restrict__ hmin,
                                                      const double* __restrict__ sumP,
                                                      const double* __restrict__ sqP,
                                                      const float* __restrict__ g,
                                                      const float* __restrict__ be,
                                                      float* __restrict__ out, int total,
                                                      double invM) {
  constexpr int NG = 256 / D;
  __shared__ double redsS[256], redqS[256];
  __shared__ float scl[D], shf[D];
  int t = threadIdx.x;
  int d = t & (D - 1), grp = t / D;
  double s = 0.0, q = 0.0;
  for (int i = grp; i < NPART; i += NG) {
    s += sumP[(size_t)i * D + d];
    q += sqP[(size_t)i * D + d];
  }
  redsS[t] = s;
  redqS[t] = q;
  __syncthreads();
  if (t < D) {
#pragma unroll
    for (int i = 1; i < NG; i++) {
      s += redsS[i * D + t];
      q += redqS[i * D + t];
    }
    double mean = s * invM;
    double var = q * invM - mean * mean;
    double sc = (double)g[t] / sqrt(var + 1e-5);
    scl[t] = (float)sc;
    shf[t] = (float)((double)be[t] - mean * sc);
  }
  __syncthreads();
  float sc = scl[d], sh = shf[d];
  for (int i = blockIdx.x * 256 + t; i < total; i += 256 * 256) {
    float v = sc >= 0.f ? hmax[i] : hmin[i];
    out[i] = v * sc + sh;
  }
}

// [16384,320]x[320,1024] via packed fp16 pairs + dot2f (fp32 accumulate).
// Block = 16 rows x 1024 cols; thread = 16 rows x 4 contiguous cols.
__global__ void __launch_bounds__(256) final_gemm(const float* __restrict__ x1,
                                                  const float* __restrict__ x2,
                                                  const float* __restrict__ x3,
                                                  const float* __restrict__ x4,
                                                  const unsigned int* __restrict__ W5h,
                                                  const float* __restrict__ b5,
                                                  float* __restrict__ partMax,
                                                  float* __restrict__ partMin,
                                                  float* __restrict__ partSum,
                                                  float* __restrict__ partSq) {
  __shared__ __align__(16) unsigned int Ath[16][160];  // 10 KB packed K-pairs
  int t = threadIdx.x;
  int blk = blockIdx.x;
  int n0 = blk * 16;
  int col = t * 4;
  for (int i = t; i < 16 * 160; i += 256) {
    int r = i / 160, p = i % 160;
    int n = n0 + r;
    int c = 2 * p;
    float va, vb2;
    if (c < 64) {
      const float* s = x1 + (size_t)n * 64 + c;
      va = s[0];
      vb2 = s[1];
    } else if (c < 128) {
      const float* s = x2 + (size_t)n * 64 + (c - 64);
      va = s[0];
      vb2 = s[1];
    } else if (c < 192) {
      const float* s = x3 + (size_t)n * 64 + (c - 128);
      va = s[0];
      vb2 = s[1];
    } else {
      const float* s = x4 + (size_t)n * 128 + (c - 192);
      va = s[0];
      vb2 = s[1];
    }
    Ath[r][p] = pack_h2(va, vb2);
  }
  __syncthreads();
  float4 acc[16];
  float4 bb = *(const float4*)(b5 + col);
#pragma unroll
  for (int r = 0; r < 16; r++) acc[r] = bb;
  for (int p4 = 0; p4 < 40; p4++) {
    const unsigned int* wbase = W5h + (size_t)p4 * 4 * 1024 + col;
    uint4 w0 = *(const uint4*)(wbase);
    uint4 w1 = *(const uint4*)(wbase + 1024);
    uint4 w2 = *(const uint4*)(wbase + 2048);
    uint4 w3 = *(const uint4*)(wbase + 3072);
#pragma unroll
    for (int r = 0; r < 16; r++) {
      uint4 a = *(const uint4*)(&Ath[r][p4 * 4]);
      acc[r].x = dot2f(a.x, w0.x, acc[r].x);
      acc[r].y = dot2f(a.x, w0.y, acc[r].y);
      acc[r].z = dot2f(a.x, w0.z, acc[r].z);
      acc[r].w = dot2f(a.x, w0.w, acc[r].w);
      acc[r].x = dot2f(a.y, w1.x, acc[r].x);
      acc[r].y = dot2f(a.y, w1.y, acc[r].y);
      acc[r].z = dot2f(a.y, w1.z, acc[r].z);
      acc[r].w = dot2f(a.y, w1.w, acc[r].w);
      acc[r].x = dot2f(a.z, w2.x, acc[r].x);
      acc[r].y = dot2f(a.z, w2.y, acc[r].y);
      acc[r].z = dot2f(a.z, w2.z, acc[r].z);
      acc[r].w = dot2f(a.z, w2.w, acc[r].w);
      acc[r].x = dot2f(a.w, w3.x, acc[r].x);
      acc[r].y = dot2f(a.w, w3.y, acc[r].y);
      acc[r].z = dot2f(a.w, w3.z, acc[r].z);
      acc[r].w = dot2f(a.w, w3.w, acc[r].w);
    }
  }
  float mx[4] = {-1e30f, -1e30f, -1e30f, -1e30f};
  float mn[4] = {1e30f, 1e30f, 1e30f, 1e30f};
  double sv[4] = {0, 0, 0, 0}, qv[4] = {0, 0, 0, 0};
#pragma unroll
  for (int r = 0; r < 16; r++) {
    float h0 = acc[r].x > 0.f ? acc[r].x : 0.f;
    float h1 = acc[r].y > 0.f ? acc[r].y : 0.f;
    float h2 = acc[r].z > 0.f ? acc[r].z : 0.f;
    float h3 = acc[r].w > 0.f ? acc[r].w : 0.f;
    mx[0] = fmaxf(mx[0], h0);
    mn[0] = fminf(mn[0], h0);
    sv[0] += h0;
    qv[0] = fma((double)h0, (double)h0, qv[0]);
    mx[1] = fmaxf(mx[1], h1);
    mn[1] = fminf(mn[1], h1);
    sv[1] += h1;
    qv[1] = fma((double)h1, (double)h1, qv[1]);
    mx[2] = fmaxf(mx[2], h2);
    mn[2] = fminf(mn[2], h2);
    sv[2] += h2;
    qv[2] = fma((double)h2, (double)h2, qv[2]);
    mx[3] = fmaxf(mx[3], h3);
    mn[3] = fminf(mn[3], h3);
    sv[3] += h3;
    qv[3] = fma((double)h3, (double)h3, qv[3]);
  }
  size_t base = (size_t)blk * 1024;
  *(float4*)(partMax + base + col) = make_float4(mx[0], mx[1], mx[2], mx[3]);
  *(float4*)(partMin + base + col) = make_float4(mn[0], mn[1], mn[2], mn[3]);
  *(float4*)(partSum + base + col) =
      make_float4((float)sv[0], (float)sv[1], (float)sv[2], (float)sv[3]);
  *(float4*)(partSq + base + col) =
      make_float4((float)qv[0], (float)qv[1], (float)qv[2], (float)qv[3]);
}

// Reduce 128 per-block partials per (batch, channel).
__global__ void __launch_bounds__(256) final_reduce(const float* __restrict__ partMax,
                                                    const float* __restrict__ partMin,
                                                    const float* __restrict__ partSum,
                                                    const float* __restrict__ partSq,
                                                    float* __restrict__ h5max,
                                                    float* __restrict__ h5min,
                                                    double* __restrict__ bsum,
                                                    double* __restrict__ bsq) {
  int bid = blockIdx.x;
  int b = bid >> 2;
  int ch = ((bid & 3) << 8) + threadIdx.x;
  float mx = -1e30f, mn = 1e30f;
  double s = 0.0, q = 0.0;
  for (int j = 0; j < 128; j++) {
    size_t base = ((size_t)(b * 128 + j) << 10) + ch;
    mx = fmaxf(mx, partMax[base]);
    mn = fminf(mn, partMin[base]);
    s += (double)partSum[base];
    q += (double)partSq[base];
  }
  h5max[(size_t)b * 1024 + ch] = mx;
  h5min[(size_t)b * 1024 + ch] = mn;
  bsum[(size_t)b * 1024 + ch] = s;
  bsq[(size_t)b * 1024 + ch] = q;
}

// Fused final bn_finalize + apply.
__global__ void __launch_bounds__(256) final_apply_fused(const float* __restrict__ h5max,
                                                         const float* __restrict__ h5min,
                                                         const double* __restrict__ bsum,
                                                         const double* __restrict__ bsq,
                                                         const float* __restrict__ g,
                                                         const float* __restrict__ be,
                                                         float* __restrict__ out,
                                                         double invM) {
  int i = blockIdx.x * 256 + threadIdx.x;
  if (i >= B * 1024) return;
  int ch = i & 1023;
  double s = 0.0, q = 0.0;
#pragma unroll
  for (int j = 0; j < 8; j++) {
    s += bsum[(size_t)j * 1024 + ch];
    q += bsq[(size_t)j * 1024 + ch];
  }
  double mean = s * invM;
  double var = q * invM - mean * mean;
  double sc = (double)g[ch] / sqrt(var + 1e-5);
  float scf = (float)sc;
  float shf = (float)((double)be[ch] - mean * sc);
  float v = scf >= 0.f ? h5max[i] : h5min[i];
  out[i] = v * scf + shf;
}

}  // namespace

extern "C" void kernel_launch(void* const* d_in, const int* in_sizes, int n_in,
                              void* d_out, int out_size, void* d_ws, size_t ws_size,
                              hipStream_t stream) {
  const float* x = (const float*)d_in[0];
  const float *Wv[5], *bv[5], *gv[5], *bev[5];
  for (int i = 0; i < 5; i++) {
    Wv[i] = (const float*)d_in[1 + 4 * i];
    bv[i] = (const float*)d_in[2 + 4 * i];
    gv[i] = (const float*)d_in[3 + 4 * i];
    bev[i] = (const float*)d_in[4 + 4 * i];
  }

  char* ws = (char*)d_ws;
  size_t off = 0;
  auto alloc = [&](size_t bytes) {
    size_t r = off;
    off = (off + bytes + 255) & ~(size_t)255;
    return r;
  };
  const int BN = B * N;
  float* feat0 = (float*)(ws + alloc((size_t)BN * 3 * 4));
  int* idx = (int*)(ws + alloc((size_t)BN * KNN * 4));
  float* x1 = (float*)(ws + alloc((size_t)BN * 64 * 4));
  float* x2 = (float*)(ws + alloc((size_t)BN * 64 * 4));
  float* x3 = (float*)(ws + alloc((size_t)BN * 64 * 4));
  float* x4 = (float*)(ws + alloc((size_t)BN * 128 * 4));
  unsigned int* fH = (unsigned int*)(ws + alloc((size_t)BN * 32 * 4));  // fp16 pairs
  unsigned int* W5h = (unsigned int*)(ws + alloc((size_t)160 * 1024 * 4));
  float* ub = (float*)(ws + alloc((size_t)BN * 128 * 4));
  float* vb = (float*)(ws + alloc((size_t)BN * 128 * 4));
  float* hmax = (float*)(ws + alloc((size_t)BN * 128 * 4));  // reused as partMax/partMin
  float* hmin = (float*)(ws + alloc((size_t)BN * 128 * 4));  // reused as partSum/partSq
  float* sqf = (float*)(ws + alloc((size_t)BN * 4));
  double* lstats = (double*)(ws + alloc((size_t)4 * 2 * NPART * 128 * 8));
  double* bsum = (double*)(ws + alloc((size_t)B * 1024 * 8));
  double* bsq = (double*)(ws + alloc((size_t)B * 1024 * 8));
  float* h5max = (float*)(ws + alloc((size_t)B * 1024 * 4));
  float* h5min = (float*)(ws + alloc((size_t)B * 1024 * 4));

  double* sumL[4], *sqL[4];
  for (int l = 0; l < 4; l++) {
    sumL[l] = lstats + (size_t)l * 2 * NPART * 128;
    sqL[l] = sumL[l] + (size_t)NPART * 128;
  }

  float* partMax = hmax;
  float* partMin = hmax + 1024 * 1024;
  float* partSum = hmin;
  float* partSq = hmin + 1024 * 1024;

  const double invMk = 1.0 / ((double)BN * KNN);
  dim3 tgrid64(N / 32, B);

  hipMemsetAsync(lstats, 0, (size_t)4 * 2 * NPART * 128 * 8, stream);
  pack_w5<<<640, 256, 0, stream>>>(Wv[4], W5h);

  // ---- layer 1: C=3 -> D=64 (x is already [B][3][N]) ----
  transpose_x_norm<<<(BN + 255) / 256, 256, 0, stream>>>(x, feat0, sqf);
  knn_fused<3><<<BN / 8, 256, 0, stream>>>(x, feat0, sqf, idx);
  gemm_uv<3, 64><<<BN / 64, 256, 0, stream>>>(feat0, Wv[0], bv[0], ub, vb);
  combine_max<64><<<BN / 4, 256, 0, stream>>>(ub, vb, idx, hmax, hmin, sumL[0], sqL[0]);
  bn_apply_fused<64><<<256, 256, 0, stream>>>(hmax, hmin, sumL[0], sqL[0], gv[0], bev[0], x1,
                                              BN * 64, invMk);

  // ---- layer 2: C=64 -> D=64 ----
  transpose64h_norm<<<tgrid64, 256, 0, stream>>>(x1, fH, sqf);
  knn_fused64h<<<BN / 16, 256, 0, stream>>>(fH, x1, sqf, idx);
  gemm_uv<64, 64><<<BN / 64, 256, 0, stream>>>(x1, Wv[1], bv[1], ub, vb);
  combine_max<64><<<BN / 4, 256, 0, stream>>>(ub, vb, idx, hmax, hmin, sumL[1], sqL[1]);
  bn_apply_fused<64><<<256, 256, 0, stream>>>(hmax, hmin, sumL[1], sqL[1], gv[1], bev[1], x2,
                                              BN * 64, invMk);

  // ---- layer 3: C=64 -> D=64 ----
  transpose64h_norm<<<tgrid64, 256, 0, stream>>>(x2, fH, sqf);
  knn_fused64h<<<BN / 16, 256, 0, stream>>>(fH, x2, sqf, idx);
  gemm_uv<64, 64><<<BN / 64, 256, 0, stream>>>(x2, Wv[2], bv[2], ub, vb);
  combine_max<64><<<BN / 4, 256, 0, stream>>>(ub, vb, idx, hmax, hmin, sumL[2], sqL[2]);
  bn_apply_fused<64><<<256, 256, 0, stream>>>(hmax, hmin, sumL[2], sqL[2], gv[2], bev[2], x3,
                                              BN * 64, invMk);

  // ---- layer 4: C=64 -> D=128 ----
  transpose64h_norm<<<tgrid64, 256, 0, stream>>>(x3, fH, sqf);
  knn_fused64h<<<BN / 16, 256, 0, stream>>>(fH, x3, sqf, idx);
  gemm_uv<64, 128><<<BN / 64, 256, 0, stream>>>(x3, Wv[3], bv[3], ub, vb);
  combine_max<128><<<BN / 2, 256, 0, stream>>>(ub, vb, idx, hmax, hmin, sumL[3], sqL[3]);
  bn_apply_fused<128><<<256, 256, 0, stream>>>(hmax, hmin, sumL[3], sqL[3], gv[3], bev[3], x4,
                                               BN * 128, invMk);

  // ---- final: [BN,320] @ [320,1024] via fp16 dot2f; atomic-free partials ----
  final_gemm<<<BN / 16, 256, 0, stream>>>(x1, x2, x3, x4, W5h, bv[4], partMax, partMin,
                                          partSum, partSq);
  final_reduce<<<32, 256, 0, stream>>>(partMax, partMin, partSum, partSq, h5max, h5min, bsum,
                                       bsq);
  final_apply_fused<<<(B * 1024 + 255) / 256, 256, 0, stream>>>(h5max, h5min, bsum, bsq,
                                                                gv[4], bev[4], (float*)d_out,
                                                                1.0 / (double)BN);
}